// Round 3
// baseline (375.433 us; speedup 1.0000x reference)
//
#include <hip/hip_runtime.h>
#include <cstddef>
#include <cstdint>

#define NB 4
#define CC 256
#define LL 4096
#define NG 32
#define CPG 8
#define NH 4
#define DH 64
#define NSPLIT 4
#define PSPLIT 4194304   // fp16 partial-O elements per split: 16*4096*64

static constexpr float EPSV  = 1e-5f;
static constexpr float SCALE_Q = 0.125f * 1.4426950408889634f; // dh^-0.5 * log2(e)

typedef __attribute__((ext_vector_type(8))) short bf16x8;
typedef __attribute__((ext_vector_type(4))) float f32x4;
typedef _Float16 f16x8 __attribute__((ext_vector_type(8)));
typedef _Float16 f16x4 __attribute__((ext_vector_type(4)));
typedef __fp16  h16x2 __attribute__((ext_vector_type(2)));   // cvt_pkrtz native type

__device__ __forceinline__ short f2bf(float f) {
  unsigned u = __float_as_uint(f);
  unsigned r = (u + 0x7fffu + ((u >> 16) & 1u)) >> 16;
  return (short)r;
}
__device__ __forceinline__ short f2h(float f) {
  union { _Float16 h; short s; } u;
  u.h = (_Float16)f;
  return u.s;
}
// element offset of 16B chunk (8 elems) with XOR swizzle: row stride 64 elems
__device__ __forceinline__ int sw(int row, int chunk) {
  return row * 64 + ((chunk ^ (row & 7)) * 8);
}
// async global->LDS DMA, 16B per lane, LDS dest = wave-uniform base + lane*16
typedef __attribute__((address_space(1))) const unsigned int gu32_t;
typedef __attribute__((address_space(3))) unsigned int lu32_t;
__device__ __forceinline__ void gl_lds16(const void* g, void* l) {
  __builtin_amdgcn_global_load_lds((gu32_t*)g, (lu32_t*)l, 16, 0, 0);
}

// ---------------- weight fp32 -> bf16 (Wq/Wk/Wv) or f16 (Wp) ----------------
__global__ __launch_bounds__(256) void wcvt_kernel(
    const float* __restrict__ Wq, const float* __restrict__ Wk,
    const float* __restrict__ Wv, const float* __restrict__ Wp,
    short* __restrict__ dst) {
  const int which = blockIdx.x >> 5;
  const float* src = (which == 0) ? Wq : (which == 1) ? Wk : (which == 2) ? Wv : Wp;
  const int base = (blockIdx.x & 31) * 2048 + threadIdx.x * 8;
  const float4 v0 = *(const float4*)(src + base);
  const float4 v1 = *(const float4*)(src + base + 4);
  short ob[8] __attribute__((aligned(16)));
  if (which < 3) {
    ob[0] = f2bf(v0.x); ob[1] = f2bf(v0.y); ob[2] = f2bf(v0.z); ob[3] = f2bf(v0.w);
    ob[4] = f2bf(v1.x); ob[5] = f2bf(v1.y); ob[6] = f2bf(v1.z); ob[7] = f2bf(v1.w);
  } else {
    ob[0] = f2h(v0.x); ob[1] = f2h(v0.y); ob[2] = f2h(v0.z); ob[3] = f2h(v0.w);
    ob[4] = f2h(v1.x); ob[5] = f2h(v1.y); ob[6] = f2h(v1.z); ob[7] = f2h(v1.w);
  }
  *(uint4*)(dst + which * 65536 + base) = *(const uint4*)ob;
}

// ---------------- GroupNorm -> xnT [n][l][c] bf16 ----------------
__global__ __launch_bounds__(256) void gn_kernel(
    const float* __restrict__ x, const float* __restrict__ gamma,
    const float* __restrict__ beta, short* __restrict__ xnT) {
  const int blk = blockIdx.x;
  const int n = blk >> 5, g = blk & 31;
  const size_t base = ((size_t)n * CC + (size_t)g * CPG) * LL;
  const float* xp = x + base;
  const int NE = CPG * LL;

  float s = 0.f, ss = 0.f;
  for (int i = threadIdx.x * 4; i < NE; i += 256 * 4) {
    float4 v = *(const float4*)(xp + i);
    s  += v.x + v.y + v.z + v.w;
    ss += v.x * v.x + v.y * v.y + v.z * v.z + v.w * v.w;
  }
  #pragma unroll
  for (int off = 32; off; off >>= 1) {
    s  += __shfl_down(s, off);
    ss += __shfl_down(ss, off);
  }
  __shared__ float r1[4], r2[4], stat[2];
  const int wid = threadIdx.x >> 6, lane = threadIdx.x & 63;
  if (lane == 0) { r1[wid] = s; r2[wid] = ss; }
  __syncthreads();
  if (threadIdx.x == 0) {
    float S = 0.f, SS = 0.f;
    #pragma unroll
    for (int w = 0; w < 4; ++w) { S += r1[w]; SS += r2[w]; }
    float mean = S / NE;
    float var  = SS / NE - mean * mean;
    stat[0] = mean;
    stat[1] = rsqrtf(var + EPSV);
  }
  __syncthreads();
  const float mean = stat[0], rstd = stat[1];
  float scl[8], shf[8];
  #pragma unroll
  for (int cc = 0; cc < 8; ++cc) {
    const float gm = gamma[g * CPG + cc];
    scl[cc] = rstd * gm;
    shf[cc] = beta[g * CPG + cc] - mean * rstd * gm;
  }
  for (int j = 0; j < 4; ++j) {
    const int l = j * 1024 + threadIdx.x * 4;
    float4 vv[8];
    #pragma unroll
    for (int cc = 0; cc < 8; ++cc)
      vv[cc] = *(const float4*)(xp + (size_t)cc * LL + l);
    short ob[4][8] __attribute__((aligned(16)));
    #pragma unroll
    for (int cc = 0; cc < 8; ++cc) {
      ob[0][cc] = f2bf(vv[cc].x * scl[cc] + shf[cc]);
      ob[1][cc] = f2bf(vv[cc].y * scl[cc] + shf[cc]);
      ob[2][cc] = f2bf(vv[cc].z * scl[cc] + shf[cc]);
      ob[3][cc] = f2bf(vv[cc].w * scl[cc] + shf[cc]);
    }
    short* op = xnT + ((size_t)n * LL + l) * CC + g * CPG;
    #pragma unroll
    for (int ii = 0; ii < 4; ++ii)
      *(uint4*)(op + (size_t)ii * CC) = *(const uint4*)ob[ii];
  }
}

// ---------------- QKV MFMA GEMM ----------------
// Qt/Kt bf16 [n,h][l][d] (Q scaled by log2e/8). Vo f16 [n,h][d][l].
__global__ __launch_bounds__(256) void qkv_gemm(
    const short* __restrict__ xnT, const short* __restrict__ Wqb,
    const short* __restrict__ Wkb, const short* __restrict__ Wvb,
    short* __restrict__ Qt, short* __restrict__ Kt, _Float16* __restrict__ Vo) {
  const int lt = blockIdx.x, ot = blockIdx.y;
  const int n = lt >> 6, l0 = (lt & 63) << 6;
  const int wave = threadIdx.x >> 6, lane = threadIdx.x & 63;
  const int lq = lane & 15, quad = lane >> 4;

  const int orow = ot * 64 + wave * 16 + lq;
  const short* wqp = Wqb + orow * CC + quad * 8;
  const short* wkp = Wkb + orow * CC + quad * 8;
  const short* wvp = Wvb + orow * CC + quad * 8;
  const short* xp  = xnT + ((size_t)(n * LL + l0) + lq) * CC + quad * 8;

  const f32x4 z = {0.f, 0.f, 0.f, 0.f};
  f32x4 aq[4] = {z, z, z, z}, ak[4] = {z, z, z, z}, av[4] = {z, z, z, z};

  #pragma unroll
  for (int c0 = 0; c0 < 256; c0 += 32) {
    const bf16x8 fq = *(const bf16x8*)(wqp + c0);
    const bf16x8 fk = *(const bf16x8*)(wkp + c0);
    const bf16x8 fv = *(const bf16x8*)(wvp + c0);
    #pragma unroll
    for (int n0 = 0; n0 < 4; ++n0) {
      const bf16x8 fb = *(const bf16x8*)(xp + (size_t)(n0 * 16) * CC + c0);
      aq[n0] = __builtin_amdgcn_mfma_f32_16x16x32_bf16(fq, fb, aq[n0], 0, 0, 0);
      ak[n0] = __builtin_amdgcn_mfma_f32_16x16x32_bf16(fk, fb, ak[n0], 0, 0, 0);
      av[n0] = __builtin_amdgcn_mfma_f32_16x16x32_bf16(fv, fb, av[n0], 0, 0, 0);
    }
  }

  const size_t hb = (size_t)(n * NH + ot);
  #pragma unroll
  for (int n0 = 0; n0 < 4; ++n0)
    #pragma unroll
    for (int r = 0; r < 4; ++r)
      Vo[(hb * DH + wave * 16 + quad * 4 + r) * LL + l0 + n0 * 16 + lq] =
          (_Float16)av[n0][r];
  __shared__ short qt_lds[64][72], kt_lds[64][72];
  #pragma unroll
  for (int n0 = 0; n0 < 4; ++n0)
    #pragma unroll
    for (int r = 0; r < 4; ++r) {
      qt_lds[n0 * 16 + lq][wave * 16 + quad * 4 + r] = f2bf(aq[n0][r] * SCALE_Q);
      kt_lds[n0 * 16 + lq][wave * 16 + quad * 4 + r] = f2bf(ak[n0][r]);
    }
  __syncthreads();
  #pragma unroll
  for (int i = 0; i < 2; ++i) {
    const int u = threadIdx.x + i * 256;
    const int row = u >> 3, ch = u & 7;
    *(uint4*)(Qt + (hb * LL + l0 + row) * DH + ch * 8) = *(const uint4*)&qt_lds[row][ch * 8];
    *(uint4*)(Kt + (hb * LL + l0 + row) * DH + ch * 8) = *(const uint4*)&kt_lds[row][ch * 8];
  }
}

// ---------------- MFMA flash attention v8: 64 q/wave, 4-way key split, 3 waves/SIMD ----------------
// grid (LL/256, NH*NSPLIT, NB) = 1024 blocks, block 256 (4 waves).
// Register diet vs v7: half-tile P (af 32->16), K via global_load_lds (kpre gone),
// VALU l-sum (ol+ones8 gone). Combined VGPR+AGPR ~156 -> 3 waves/SIMD.
__global__ __launch_bounds__(256, 3) void attn_mfma_kernel(
    const short* __restrict__ Qt, const short* __restrict__ Kt,
    const _Float16* __restrict__ Vb, _Float16* __restrict__ Opart,
    float* __restrict__ lpart) {
  __shared__ __align__(16) short    k_lds[2][64 * 64];   // 8 KB each, swizzled (DMA: linear dest, pre-swizzled src)
  __shared__ __align__(16) _Float16 v_lds[2][64 * 64];   // 8 KB each, swizzled+permuted

  const int t = threadIdx.x;
  const int wave = t >> 6, lane = t & 63;
  const int lq = lane & 15, quad = lane >> 4;
  const int l0 = blockIdx.x * 256;
  const int h = blockIdx.y >> 2, split = blockIdx.y & 3;
  const int n = blockIdx.z;
  const int kbase = split * 1024;
  const int R = n * NH + h;
  const size_t hb = (size_t)R * (size_t)LL * DH;
  const short* const Kp = Kt + hb;      // [key][d] bf16
  const _Float16* const Vp = Vb + hb;   // [d][key] f16

  // Q B-frags: B[n=q][k=d] — wave's 64 q rows
  const int qbase = l0 + wave * 64;
  bf16x8 qb[4][2];
  #pragma unroll
  for (int qf = 0; qf < 4; ++qf)
    #pragma unroll
    for (int c = 0; c < 2; ++c)
      qb[qf][c] = *(const bf16x8*)(Qt + hb + (size_t)(qbase + qf * 16 + lq) * DH + c * 32 + quad * 8);

  const f32x4 z = {0.f, 0.f, 0.f, 0.f};
  f32x4 o[4][4] = {{z, z, z, z}, {z, z, z, z}, {z, z, z, z}, {z, z, z, z}};
  float lsum[4] = {0.f, 0.f, 0.f, 0.f};

  const int srow = t >> 3, sch = t & 7;   // staging: rows 0..31(+32), chunk 0..7
  const int vgo = 32 * (sch >> 2) + 4 * (sch & 3);  // permuted key offset (lo half)
  const int ksw = ((sch ^ (srow & 7)) * 8);         // pre-swizzled K source chunk (elems)

  // stage tile 0: K via DMA (linear dest per wave), V via reg round-trip (swizzled scatter)
  {
    gl_lds16(Kp + (size_t)(kbase + srow) * DH + ksw, &k_lds[0][wave * 512]);
    gl_lds16(Kp + (size_t)(kbase + 32 + srow) * DH + ksw, &k_lds[0][2048 + wave * 512]);
    const _Float16* vg0 = Vp + (size_t)srow * LL + kbase + vgo;
    const _Float16* vg1 = Vp + (size_t)(32 + srow) * LL + kbase + vgo;
    uint2 a = *(const uint2*)vg0, b = *(const uint2*)(vg0 + 16);
    *(uint4*)&v_lds[0][sw(srow, sch)] = make_uint4(a.x, a.y, b.x, b.y);
    a = *(const uint2*)vg1; b = *(const uint2*)(vg1 + 16);
    *(uint4*)&v_lds[0][sw(32 + srow, sch)] = make_uint4(a.x, a.y, b.x, b.y);
  }
  __syncthreads();

  for (int kt = 0; kt < 16; ++kt) {
    const int cur = kt & 1, nxt = cur ^ 1;
    uint2 vpre[4];
    if (kt < 15) {
      const int kpos = kbase + (kt + 1) * 64;
      // K -> other LDS buffer via async DMA (free since last barrier)
      gl_lds16(Kp + (size_t)(kpos + srow) * DH + ksw, &k_lds[nxt][wave * 512]);
      gl_lds16(Kp + (size_t)(kpos + 32 + srow) * DH + ksw, &k_lds[nxt][2048 + wave * 512]);
      const _Float16* vg0 = Vp + (size_t)srow * LL + kpos + vgo;
      const _Float16* vg1 = Vp + (size_t)(32 + srow) * LL + kpos + vgo;
      vpre[0] = *(const uint2*)vg0;
      vpre[1] = *(const uint2*)(vg0 + 16);
      vpre[2] = *(const uint2*)vg1;
      vpre[3] = *(const uint2*)(vg1 + 16);
    }
    const short* kb = k_lds[cur];
    const _Float16* vbuf = v_lds[cur];

    // ---- two 32-key half-tiles: QK^T -> exp2 -> f16 A-frags -> PV ----
    #pragma unroll
    for (int hh = 0; hh < 2; ++hh) {
      union PU { f16x4 h4[2]; f16x8 h8; } af[4];
      #pragma unroll
      for (int mf2 = 0; mf2 < 2; ++mf2) {
        const int mrow = (hh * 2 + mf2) * 16 + lq;
        const bf16x8 ka0 = *(const bf16x8*)&kb[sw(mrow, quad)];
        const bf16x8 ka1 = *(const bf16x8*)&kb[sw(mrow, 4 + quad)];
        #pragma unroll
        for (int qf = 0; qf < 4; ++qf) {
          f32x4 zz = {0.f, 0.f, 0.f, 0.f};
          zz = __builtin_amdgcn_mfma_f32_16x16x32_bf16(ka0, qb[qf][0], zz, 0, 0, 0);
          zz = __builtin_amdgcn_mfma_f32_16x16x32_bf16(ka1, qb[qf][1], zz, 0, 0, 0);
          const float e0 = __builtin_amdgcn_exp2f(zz[0]);
          const float e1 = __builtin_amdgcn_exp2f(zz[1]);
          const float e2 = __builtin_amdgcn_exp2f(zz[2]);
          const float e3 = __builtin_amdgcn_exp2f(zz[3]);
          lsum[qf] += (e0 + e1) + (e2 + e3);
          union { h16x2 h2[2]; f16x4 h4; } u;
          u.h2[0] = __builtin_amdgcn_cvt_pkrtz(e0, e1);
          u.h2[1] = __builtin_amdgcn_cvt_pkrtz(e2, e3);
          af[qf].h4[mf2] = u.h4;
        }
      }
      // PV for this half: V chunks hh*4+quad hold exactly this half's permuted keys
      #pragma unroll
      for (int df = 0; df < 4; ++df) {
        const f16x8 vb8 = *(const f16x8*)&vbuf[sw(df * 16 + lq, hh * 4 + quad)];
        #pragma unroll
        for (int qf = 0; qf < 4; ++qf)
          o[qf][df] = __builtin_amdgcn_mfma_f32_16x16x32_f16(af[qf].h8, vb8, o[qf][df], 0, 0, 0);
      }
    }

    // ---- write prefetched V to other buffer; barrier covers K-DMA too ----
    if (kt < 15) {
      *(uint4*)&v_lds[nxt][sw(srow, sch)]      = make_uint4(vpre[0].x, vpre[0].y, vpre[1].x, vpre[1].y);
      *(uint4*)&v_lds[nxt][sw(32 + srow, sch)] = make_uint4(vpre[2].x, vpre[2].y, vpre[3].x, vpre[3].y);
      __syncthreads();
    }
  }

  // ---- epilogue: cross-quad reduce l, store l + raw fp16 partial O ----
  #pragma unroll
  for (int qf = 0; qf < 4; ++qf) {
    lsum[qf] += __shfl_xor(lsum[qf], 16);
    lsum[qf] += __shfl_xor(lsum[qf], 32);
  }
  if (quad == 0) {
    #pragma unroll
    for (int qf = 0; qf < 4; ++qf)
      lpart[((size_t)split * 16 + R) * LL + qbase + qf * 16 + lq] = lsum[qf];
  }
  const size_t pb = ((size_t)split * 16 + R) * (size_t)LL * DH;
  #pragma unroll
  for (int qf = 0; qf < 4; ++qf)
    #pragma unroll
    for (int df = 0; df < 4; ++df)
      #pragma unroll
      for (int r = 0; r < 4; ++r) {
        const int q = qbase + qf * 16 + quad * 4 + r;
        Opart[pb + (size_t)q * DH + df * 16 + lq] = (_Float16)o[qf][df][r];
      }
}

// ---------------- output projection (f16 MFMA, fused normalize, 2 o-tiles) ----------------
__global__ __launch_bounds__(256) void proj_gemm(
    const _Float16* __restrict__ Opart, const float* __restrict__ lpart,
    const _Float16* __restrict__ Wpf, const float* __restrict__ bp,
    float* __restrict__ out) {
  const int lt = blockIdx.x, ot2 = blockIdx.y;   // ot2 covers 128 output channels
  const int n = lt >> 6, l0 = (lt & 63) << 6;
  const int wave = threadIdx.x >> 6, lane = threadIdx.x & 63;
  const int lq = lane & 15, quad = lane >> 4;

  const _Float16* wpp0 = Wpf + (ot2 * 128 + wave * 16 + lq) * CC + quad * 8;
  const _Float16* wpp1 = wpp0 + 64 * CC;

  // per-(n0,h) 1/l as f16 (l = sum of 4 split partials)
  _Float16 invl[4][4];
  #pragma unroll
  for (int n0 = 0; n0 < 4; ++n0) {
    const int q = l0 + n0 * 16 + lq;
    #pragma unroll
    for (int h = 0; h < 4; ++h) {
      const size_t rr = (size_t)(n * NH + h) * LL + q;
      invl[n0][h] = (_Float16)(1.0f / (lpart[rr] + lpart[rr + 16 * (size_t)LL]
                                     + lpart[rr + 32 * (size_t)LL] + lpart[rr + 48 * (size_t)LL]));
    }
  }

  const f32x4 z = {0.f, 0.f, 0.f, 0.f};
  f32x4 acc[2][4] = {{z, z, z, z}, {z, z, z, z}};
  #pragma unroll
  for (int c0 = 0; c0 < 256; c0 += 32) {
    const int h = c0 >> 6;
    const int d0 = (c0 & 63) + quad * 8;
    const f16x8 fa0 = *(const f16x8*)(wpp0 + c0);
    const f16x8 fa1 = *(const f16x8*)(wpp1 + c0);
    #pragma unroll
    for (int n0 = 0; n0 < 4; ++n0) {
      const int q = l0 + n0 * 16 + lq;
      const size_t e = ((size_t)(n * NH + h) * LL + q) * DH + d0;
      const f16x8 b0 = *(const f16x8*)(Opart + e);
      const f16x8 b1 = *(const f16x8*)(Opart + e + (size_t)PSPLIT);
      const f16x8 b2 = *(const f16x8*)(Opart + e + 2 * (size_t)PSPLIT);
      const f16x8 b3 = *(const f16x8*)(Opart + e + 3 * (size_t)PSPLIT);
      f16x8 sc8;
      #pragma unroll
      for (int i = 0; i < 8; ++i) sc8[i] = invl[n0][h];
      const f16x8 fb = ((b0 + b1) + (b2 + b3)) * sc8;
      acc[0][n0] = __builtin_amdgcn_mfma_f32_16x16x32_f16(fa0, fb, acc[0][n0], 0, 0, 0);
      acc[1][n0] = __builtin_amdgcn_mfma_f32_16x16x32_f16(fa1, fb, acc[1][n0], 0, 0, 0);
    }
  }
  #pragma unroll
  for (int w = 0; w < 2; ++w)
    #pragma unroll
    for (int r = 0; r < 4; ++r) {
      const int oo = ot2 * 128 + w * 64 + wave * 16 + quad * 4 + r;
      const float bias = bp[oo];
      #pragma unroll
      for (int n0 = 0; n0 < 4; ++n0)
        out[((size_t)n * CC + oo) * LL + l0 + n0 * 16 + lq] = acc[w][n0][r] + bias;
    }
}

extern "C" void kernel_launch(void* const* d_in, const int* in_sizes, int n_in,
                              void* d_out, int out_size, void* d_ws, size_t ws_size,
                              hipStream_t stream) {
  const float* x     = (const float*)d_in[0];
  const float* gamma = (const float*)d_in[1];
  const float* beta  = (const float*)d_in[2];
  const float* Wq    = (const float*)d_in[3];
  const float* Wk    = (const float*)d_in[4];
  const float* Wv    = (const float*)d_in[5];
  const float* Wp    = (const float*)d_in[6];
  const float* bp    = (const float*)d_in[7];
  float* out = (float*)d_out;

  const size_t S = (size_t)NB * CC * LL;  // 4,194,304
  short*     xnT = (short*)d_ws;          // bf16 [n][l][c]
  short*     Qt  = xnT + S;               // bf16 [n,h][l][d]
  short*     Kt  = Qt + S;
  _Float16*  Vo  = (_Float16*)(Kt + S);   // f16 [n,h][d][l]
  short*     Wb  = (short*)(Vo + S);      // 4 x 65536 (bf16 x3, f16 x1)
  _Float16*  Opart = (_Float16*)(Wb + 4 * 65536);        // NSPLIT x 8 MB fp16
  float*     lpart = (float*)(Opart + NSPLIT * (size_t)PSPLIT); // NSPLIT x 256KB fp32

  gn_kernel  <<<NB * NG,              256, 0, stream>>>(x, gamma, beta, xnT);
  wcvt_kernel<<<128,                  256, 0, stream>>>(Wq, Wk, Wv, Wp, Wb);
  qkv_gemm   <<<dim3(256, 4),         256, 0, stream>>>(xnT, Wb, Wb + 65536, Wb + 131072, Qt, Kt, Vo);
  attn_mfma_kernel<<<dim3(LL/256, NH*NSPLIT, NB), 256, 0, stream>>>(Qt, Kt, Vo, Opart, lpart);
  proj_gemm  <<<dim3(256, 2),         256, 0, stream>>>(Opart, lpart,
                 (const _Float16*)(Wb + 196608), bp, out);
}

// Round 4
// 326.564 us; speedup vs baseline: 1.1496x; 1.1496x over previous
//
#include <hip/hip_runtime.h>
#include <cstddef>
#include <cstdint>

#define NB 4
#define CC 256
#define LL 4096
#define NG 32
#define CPG 8
#define NH 4
#define DH 64
#define NSPLIT 4
#define PSPLIT 4194304   // fp16 partial-O elements per split: 16*4096*64

static constexpr float EPSV  = 1e-5f;
static constexpr float SCALE_Q = 0.125f * 1.4426950408889634f; // dh^-0.5 * log2(e)

typedef __attribute__((ext_vector_type(8))) short bf16x8;
typedef __attribute__((ext_vector_type(4))) float f32x4;
typedef _Float16 f16x8 __attribute__((ext_vector_type(8)));
typedef _Float16 f16x4 __attribute__((ext_vector_type(4)));
typedef __fp16  h16x2 __attribute__((ext_vector_type(2)));   // cvt_pkrtz native type

__device__ __forceinline__ short f2bf(float f) {
  unsigned u = __float_as_uint(f);
  unsigned r = (u + 0x7fffu + ((u >> 16) & 1u)) >> 16;
  return (short)r;
}
__device__ __forceinline__ short f2h(float f) {
  union { _Float16 h; short s; } u;
  u.h = (_Float16)f;
  return u.s;
}
// element offset of 16B chunk (8 elems) with XOR swizzle: row stride 64 elems
__device__ __forceinline__ int sw(int row, int chunk) {
  return row * 64 + ((chunk ^ (row & 7)) * 8);
}
// async global->LDS DMA, 16B per lane, LDS dest = wave-uniform base + lane*16
typedef __attribute__((address_space(1))) const unsigned int gu32_t;
typedef __attribute__((address_space(3))) unsigned int lu32_t;
__device__ __forceinline__ void gl_lds16(const void* g, void* l) {
  __builtin_amdgcn_global_load_lds((gu32_t*)g, (lu32_t*)l, 16, 0, 0);
}

// ---------------- weight fp32 -> bf16 (Wq/Wk/Wv) or f16 (Wp) ----------------
__global__ __launch_bounds__(256) void wcvt_kernel(
    const float* __restrict__ Wq, const float* __restrict__ Wk,
    const float* __restrict__ Wv, const float* __restrict__ Wp,
    short* __restrict__ dst) {
  const int which = blockIdx.x >> 5;
  const float* src = (which == 0) ? Wq : (which == 1) ? Wk : (which == 2) ? Wv : Wp;
  const int base = (blockIdx.x & 31) * 2048 + threadIdx.x * 8;
  const float4 v0 = *(const float4*)(src + base);
  const float4 v1 = *(const float4*)(src + base + 4);
  short ob[8] __attribute__((aligned(16)));
  if (which < 3) {
    ob[0] = f2bf(v0.x); ob[1] = f2bf(v0.y); ob[2] = f2bf(v0.z); ob[3] = f2bf(v0.w);
    ob[4] = f2bf(v1.x); ob[5] = f2bf(v1.y); ob[6] = f2bf(v1.z); ob[7] = f2bf(v1.w);
  } else {
    ob[0] = f2h(v0.x); ob[1] = f2h(v0.y); ob[2] = f2h(v0.z); ob[3] = f2h(v0.w);
    ob[4] = f2h(v1.x); ob[5] = f2h(v1.y); ob[6] = f2h(v1.z); ob[7] = f2h(v1.w);
  }
  *(uint4*)(dst + which * 65536 + base) = *(const uint4*)ob;
}

// ---------------- GroupNorm -> xnT [n][l][c] bf16 ----------------
__global__ __launch_bounds__(256) void gn_kernel(
    const float* __restrict__ x, const float* __restrict__ gamma,
    const float* __restrict__ beta, short* __restrict__ xnT) {
  const int blk = blockIdx.x;
  const int n = blk >> 5, g = blk & 31;
  const size_t base = ((size_t)n * CC + (size_t)g * CPG) * LL;
  const float* xp = x + base;
  const int NE = CPG * LL;

  float s = 0.f, ss = 0.f;
  for (int i = threadIdx.x * 4; i < NE; i += 256 * 4) {
    float4 v = *(const float4*)(xp + i);
    s  += v.x + v.y + v.z + v.w;
    ss += v.x * v.x + v.y * v.y + v.z * v.z + v.w * v.w;
  }
  #pragma unroll
  for (int off = 32; off; off >>= 1) {
    s  += __shfl_down(s, off);
    ss += __shfl_down(ss, off);
  }
  __shared__ float r1[4], r2[4], stat[2];
  const int wid = threadIdx.x >> 6, lane = threadIdx.x & 63;
  if (lane == 0) { r1[wid] = s; r2[wid] = ss; }
  __syncthreads();
  if (threadIdx.x == 0) {
    float S = 0.f, SS = 0.f;
    #pragma unroll
    for (int w = 0; w < 4; ++w) { S += r1[w]; SS += r2[w]; }
    float mean = S / NE;
    float var  = SS / NE - mean * mean;
    stat[0] = mean;
    stat[1] = rsqrtf(var + EPSV);
  }
  __syncthreads();
  const float mean = stat[0], rstd = stat[1];
  float scl[8], shf[8];
  #pragma unroll
  for (int cc = 0; cc < 8; ++cc) {
    const float gm = gamma[g * CPG + cc];
    scl[cc] = rstd * gm;
    shf[cc] = beta[g * CPG + cc] - mean * rstd * gm;
  }
  for (int j = 0; j < 4; ++j) {
    const int l = j * 1024 + threadIdx.x * 4;
    float4 vv[8];
    #pragma unroll
    for (int cc = 0; cc < 8; ++cc)
      vv[cc] = *(const float4*)(xp + (size_t)cc * LL + l);
    short ob[4][8] __attribute__((aligned(16)));
    #pragma unroll
    for (int cc = 0; cc < 8; ++cc) {
      ob[0][cc] = f2bf(vv[cc].x * scl[cc] + shf[cc]);
      ob[1][cc] = f2bf(vv[cc].y * scl[cc] + shf[cc]);
      ob[2][cc] = f2bf(vv[cc].z * scl[cc] + shf[cc]);
      ob[3][cc] = f2bf(vv[cc].w * scl[cc] + shf[cc]);
    }
    short* op = xnT + ((size_t)n * LL + l) * CC + g * CPG;
    #pragma unroll
    for (int ii = 0; ii < 4; ++ii)
      *(uint4*)(op + (size_t)ii * CC) = *(const uint4*)ob[ii];
  }
}

// ---------------- QKV MFMA GEMM ----------------
// Qt/Kt bf16 [n,h][l][d] (Q scaled by log2e/8).
// Vo f16 [n,h][d][perm(l)]: key dim pre-permuted within each 64-block so the
// attn kernel can stage V via global_load_lds with contiguous 16B per lane.
// perm: pos = 32*(n0>>1) + 8*(lq>>2) + 4*(n0&1) + (lq&3)  (bijective on 64)
__global__ __launch_bounds__(256) void qkv_gemm(
    const short* __restrict__ xnT, const short* __restrict__ Wqb,
    const short* __restrict__ Wkb, const short* __restrict__ Wvb,
    short* __restrict__ Qt, short* __restrict__ Kt, _Float16* __restrict__ Vo) {
  const int lt = blockIdx.x, ot = blockIdx.y;
  const int n = lt >> 6, l0 = (lt & 63) << 6;
  const int wave = threadIdx.x >> 6, lane = threadIdx.x & 63;
  const int lq = lane & 15, quad = lane >> 4;

  const int orow = ot * 64 + wave * 16 + lq;
  const short* wqp = Wqb + orow * CC + quad * 8;
  const short* wkp = Wkb + orow * CC + quad * 8;
  const short* wvp = Wvb + orow * CC + quad * 8;
  const short* xp  = xnT + ((size_t)(n * LL + l0) + lq) * CC + quad * 8;

  const f32x4 z = {0.f, 0.f, 0.f, 0.f};
  f32x4 aq[4] = {z, z, z, z}, ak[4] = {z, z, z, z}, av[4] = {z, z, z, z};

  #pragma unroll
  for (int c0 = 0; c0 < 256; c0 += 32) {
    const bf16x8 fq = *(const bf16x8*)(wqp + c0);
    const bf16x8 fk = *(const bf16x8*)(wkp + c0);
    const bf16x8 fv = *(const bf16x8*)(wvp + c0);
    #pragma unroll
    for (int n0 = 0; n0 < 4; ++n0) {
      const bf16x8 fb = *(const bf16x8*)(xp + (size_t)(n0 * 16) * CC + c0);
      aq[n0] = __builtin_amdgcn_mfma_f32_16x16x32_bf16(fq, fb, aq[n0], 0, 0, 0);
      ak[n0] = __builtin_amdgcn_mfma_f32_16x16x32_bf16(fk, fb, ak[n0], 0, 0, 0);
      av[n0] = __builtin_amdgcn_mfma_f32_16x16x32_bf16(fv, fb, av[n0], 0, 0, 0);
    }
  }

  const size_t hb = (size_t)(n * NH + ot);
  // permuted V write (key dim pre-permuted within 64-block)
  #pragma unroll
  for (int n0 = 0; n0 < 4; ++n0) {
    const int pos = l0 + 32 * (n0 >> 1) + 8 * (lq >> 2) + 4 * (n0 & 1) + (lq & 3);
    #pragma unroll
    for (int r = 0; r < 4; ++r)
      Vo[(hb * DH + wave * 16 + quad * 4 + r) * LL + pos] = (_Float16)av[n0][r];
  }
  __shared__ short qt_lds[64][72], kt_lds[64][72];
  #pragma unroll
  for (int n0 = 0; n0 < 4; ++n0)
    #pragma unroll
    for (int r = 0; r < 4; ++r) {
      qt_lds[n0 * 16 + lq][wave * 16 + quad * 4 + r] = f2bf(aq[n0][r] * SCALE_Q);
      kt_lds[n0 * 16 + lq][wave * 16 + quad * 4 + r] = f2bf(ak[n0][r]);
    }
  __syncthreads();
  #pragma unroll
  for (int i = 0; i < 2; ++i) {
    const int u = threadIdx.x + i * 256;
    const int row = u >> 3, ch = u & 7;
    *(uint4*)(Qt + (hb * LL + l0 + row) * DH + ch * 8) = *(const uint4*)&qt_lds[row][ch * 8];
    *(uint4*)(Kt + (hb * LL + l0 + row) * DH + ch * 8) = *(const uint4*)&kt_lds[row][ch * 8];
  }
}

// ---------------- MFMA flash attention v9: 64 q/wave, 4-way key split ----------------
// grid (LL/256, NH*NSPLIT, NB) = 1024 blocks, block 256 (4 waves).
// ALL staging (K and V) via global_load_lds DMA: linear LDS dest, XOR-pre-swizzled
// global source (V pre-permuted in Vo by qkv_gemm). No staging registers, no
// ds_writes, no gather. Peak live regs ~134 -> __launch_bounds__(256,3) for
// 3 waves/SIMD without spills. LDS image identical to the proven v7 kernel.
__global__ __launch_bounds__(256, 3) void attn_mfma_kernel(
    const short* __restrict__ Qt, const short* __restrict__ Kt,
    const _Float16* __restrict__ Vb, _Float16* __restrict__ Opart,
    float* __restrict__ lpart) {
  __shared__ __align__(16) short    k_lds[2][64 * 64];   // 8 KB each
  __shared__ __align__(16) _Float16 v_lds[2][64 * 64];   // 8 KB each

  const int t = threadIdx.x;
  const int wave = t >> 6, lane = t & 63;
  const int lq = lane & 15, quad = lane >> 4;
  const int l0 = blockIdx.x * 256;
  const int h = blockIdx.y >> 2, split = blockIdx.y & 3;
  const int n = blockIdx.z;
  const int kbase = split * 1024;
  const int R = n * NH + h;
  const size_t hb = (size_t)R * (size_t)LL * DH;
  const short* const Kp = Kt + hb;      // [key][d] bf16
  const _Float16* const Vp = Vb + hb;   // [d][perm(key)] f16

  // Q B-frags: B[n=q][k=d] — wave's 64 q rows
  const int qbase = l0 + wave * 64;
  bf16x8 qb[4][2];
  #pragma unroll
  for (int qf = 0; qf < 4; ++qf)
    #pragma unroll
    for (int c = 0; c < 2; ++c)
      qb[qf][c] = *(const bf16x8*)(Qt + hb + (size_t)(qbase + qf * 16 + lq) * DH + c * 32 + quad * 8);

  const f32x4 z = {0.f, 0.f, 0.f, 0.f};
  f32x4 o[4][4] = {{z, z, z, z}, {z, z, z, z}, {z, z, z, z}, {z, z, z, z}};
  float lsum[4] = {0.f, 0.f, 0.f, 0.f};

  const int srow = t >> 3, sch = t & 7;           // staging: row 0..31 (+32), chunk 0..7
  const int swz8 = ((sch ^ (srow & 7)) * 8);      // pre-swizzled source chunk (elems)
  const short*    const kS0 = Kp + (size_t)srow * DH + swz8;
  const short*    const kS1 = Kp + (size_t)(32 + srow) * DH + swz8;
  const _Float16* const vS0 = Vp + (size_t)srow * LL + swz8;
  const _Float16* const vS1 = Vp + (size_t)(32 + srow) * LL + swz8;

  // stage tile 0 (all DMA)
  gl_lds16(kS0 + (size_t)kbase * DH, &k_lds[0][wave * 512]);
  gl_lds16(kS1 + (size_t)kbase * DH, &k_lds[0][2048 + wave * 512]);
  gl_lds16(vS0 + kbase,              &v_lds[0][wave * 512]);
  gl_lds16(vS1 + kbase,              &v_lds[0][2048 + wave * 512]);
  __syncthreads();

  for (int kt = 0; kt < 16; ++kt) {
    const int cur = kt & 1, nxt = cur ^ 1;
    if (kt < 15) {
      const int kpos = kbase + (kt + 1) * 64;
      gl_lds16(kS0 + (size_t)kpos * DH, &k_lds[nxt][wave * 512]);
      gl_lds16(kS1 + (size_t)kpos * DH, &k_lds[nxt][2048 + wave * 512]);
      gl_lds16(vS0 + kpos,              &v_lds[nxt][wave * 512]);
      gl_lds16(vS1 + kpos,              &v_lds[nxt][2048 + wave * 512]);
    }
    const short* kb = k_lds[cur];
    const _Float16* vbuf = v_lds[cur];

    // ---- two 32-key half-tiles: QK^T -> exp2 -> f16 A-frags -> PV ----
    #pragma unroll
    for (int hh = 0; hh < 2; ++hh) {
      union PU { f16x4 h4[2]; f16x8 h8; } af[4];
      #pragma unroll
      for (int mf2 = 0; mf2 < 2; ++mf2) {
        const int mrow = (hh * 2 + mf2) * 16 + lq;
        const bf16x8 ka0 = *(const bf16x8*)&kb[sw(mrow, quad)];
        const bf16x8 ka1 = *(const bf16x8*)&kb[sw(mrow, 4 + quad)];
        #pragma unroll
        for (int qf = 0; qf < 4; ++qf) {
          f32x4 zz = {0.f, 0.f, 0.f, 0.f};
          zz = __builtin_amdgcn_mfma_f32_16x16x32_bf16(ka0, qb[qf][0], zz, 0, 0, 0);
          zz = __builtin_amdgcn_mfma_f32_16x16x32_bf16(ka1, qb[qf][1], zz, 0, 0, 0);
          const float e0 = __builtin_amdgcn_exp2f(zz[0]);
          const float e1 = __builtin_amdgcn_exp2f(zz[1]);
          const float e2 = __builtin_amdgcn_exp2f(zz[2]);
          const float e3 = __builtin_amdgcn_exp2f(zz[3]);
          lsum[qf] += (e0 + e1) + (e2 + e3);
          union { h16x2 h2[2]; f16x4 h4; } u;
          u.h2[0] = __builtin_amdgcn_cvt_pkrtz(e0, e1);
          u.h2[1] = __builtin_amdgcn_cvt_pkrtz(e2, e3);
          af[qf].h4[mf2] = u.h4;
        }
      }
      // PV for this half: V chunks hh*4+quad hold exactly this half's permuted keys
      #pragma unroll
      for (int df = 0; df < 4; ++df) {
        const f16x8 vb8 = *(const f16x8*)&vbuf[sw(df * 16 + lq, hh * 4 + quad)];
        #pragma unroll
        for (int qf = 0; qf < 4; ++qf)
          o[qf][df] = __builtin_amdgcn_mfma_f32_16x16x32_f16(af[qf].h8, vb8, o[qf][df], 0, 0, 0);
      }
    }

    if (kt < 15) __syncthreads();   // drains DMA (vmcnt) + guards buffer swap
  }

  // ---- epilogue: cross-quad reduce l, store l + raw fp16 partial O ----
  #pragma unroll
  for (int qf = 0; qf < 4; ++qf) {
    lsum[qf] += __shfl_xor(lsum[qf], 16);
    lsum[qf] += __shfl_xor(lsum[qf], 32);
  }
  if (quad == 0) {
    #pragma unroll
    for (int qf = 0; qf < 4; ++qf)
      lpart[((size_t)split * 16 + R) * LL + qbase + qf * 16 + lq] = lsum[qf];
  }
  const size_t pb = ((size_t)split * 16 + R) * (size_t)LL * DH;
  #pragma unroll
  for (int qf = 0; qf < 4; ++qf)
    #pragma unroll
    for (int df = 0; df < 4; ++df)
      #pragma unroll
      for (int r = 0; r < 4; ++r) {
        const int q = qbase + qf * 16 + quad * 4 + r;
        Opart[pb + (size_t)q * DH + df * 16 + lq] = (_Float16)o[qf][df][r];
      }
}

// ---------------- output projection (f16 MFMA, fused normalize, 2 o-tiles) ----------------
__global__ __launch_bounds__(256) void proj_gemm(
    const _Float16* __restrict__ Opart, const float* __restrict__ lpart,
    const _Float16* __restrict__ Wpf, const float* __restrict__ bp,
    float* __restrict__ out) {
  const int lt = blockIdx.x, ot2 = blockIdx.y;   // ot2 covers 128 output channels
  const int n = lt >> 6, l0 = (lt & 63) << 6;
  const int wave = threadIdx.x >> 6, lane = threadIdx.x & 63;
  const int lq = lane & 15, quad = lane >> 4;

  const _Float16* wpp0 = Wpf + (ot2 * 128 + wave * 16 + lq) * CC + quad * 8;
  const _Float16* wpp1 = wpp0 + 64 * CC;

  // per-(n0,h) 1/l as f16 (l = sum of 4 split partials)
  _Float16 invl[4][4];
  #pragma unroll
  for (int n0 = 0; n0 < 4; ++n0) {
    const int q = l0 + n0 * 16 + lq;
    #pragma unroll
    for (int h = 0; h < 4; ++h) {
      const size_t rr = (size_t)(n * NH + h) * LL + q;
      invl[n0][h] = (_Float16)(1.0f / (lpart[rr] + lpart[rr + 16 * (size_t)LL]
                                     + lpart[rr + 32 * (size_t)LL] + lpart[rr + 48 * (size_t)LL]));
    }
  }

  const f32x4 z = {0.f, 0.f, 0.f, 0.f};
  f32x4 acc[2][4] = {{z, z, z, z}, {z, z, z, z}};
  #pragma unroll
  for (int c0 = 0; c0 < 256; c0 += 32) {
    const int h = c0 >> 6;
    const int d0 = (c0 & 63) + quad * 8;
    const f16x8 fa0 = *(const f16x8*)(wpp0 + c0);
    const f16x8 fa1 = *(const f16x8*)(wpp1 + c0);
    #pragma unroll
    for (int n0 = 0; n0 < 4; ++n0) {
      const int q = l0 + n0 * 16 + lq;
      const size_t e = ((size_t)(n * NH + h) * LL + q) * DH + d0;
      const f16x8 b0 = *(const f16x8*)(Opart + e);
      const f16x8 b1 = *(const f16x8*)(Opart + e + (size_t)PSPLIT);
      const f16x8 b2 = *(const f16x8*)(Opart + e + 2 * (size_t)PSPLIT);
      const f16x8 b3 = *(const f16x8*)(Opart + e + 3 * (size_t)PSPLIT);
      f16x8 sc8;
      #pragma unroll
      for (int i = 0; i < 8; ++i) sc8[i] = invl[n0][h];
      const f16x8 fb = ((b0 + b1) + (b2 + b3)) * sc8;
      acc[0][n0] = __builtin_amdgcn_mfma_f32_16x16x32_f16(fa0, fb, acc[0][n0], 0, 0, 0);
      acc[1][n0] = __builtin_amdgcn_mfma_f32_16x16x32_f16(fa1, fb, acc[1][n0], 0, 0, 0);
    }
  }
  #pragma unroll
  for (int w = 0; w < 2; ++w)
    #pragma unroll
    for (int r = 0; r < 4; ++r) {
      const int oo = ot2 * 128 + w * 64 + wave * 16 + quad * 4 + r;
      const float bias = bp[oo];
      #pragma unroll
      for (int n0 = 0; n0 < 4; ++n0)
        out[((size_t)n * CC + oo) * LL + l0 + n0 * 16 + lq] = acc[w][n0][r] + bias;
    }
}

extern "C" void kernel_launch(void* const* d_in, const int* in_sizes, int n_in,
                              void* d_out, int out_size, void* d_ws, size_t ws_size,
                              hipStream_t stream) {
  const float* x     = (const float*)d_in[0];
  const float* gamma = (const float*)d_in[1];
  const float* beta  = (const float*)d_in[2];
  const float* Wq    = (const float*)d_in[3];
  const float* Wk    = (const float*)d_in[4];
  const float* Wv    = (const float*)d_in[5];
  const float* Wp    = (const float*)d_in[6];
  const float* bp    = (const float*)d_in[7];
  float* out = (float*)d_out;

  const size_t S = (size_t)NB * CC * LL;  // 4,194,304
  short*     xnT = (short*)d_ws;          // bf16 [n][l][c]
  short*     Qt  = xnT + S;               // bf16 [n,h][l][d]
  short*     Kt  = Qt + S;
  _Float16*  Vo  = (_Float16*)(Kt + S);   // f16 [n,h][d][perm(l)]
  short*     Wb  = (short*)(Vo + S);      // 4 x 65536 (bf16 x3, f16 x1)
  _Float16*  Opart = (_Float16*)(Wb + 4 * 65536);        // NSPLIT x 8 MB fp16
  float*     lpart = (float*)(Opart + NSPLIT * (size_t)PSPLIT); // NSPLIT x 256KB fp32

  gn_kernel  <<<NB * NG,              256, 0, stream>>>(x, gamma, beta, xnT);
  wcvt_kernel<<<128,                  256, 0, stream>>>(Wq, Wk, Wv, Wp, Wb);
  qkv_gemm   <<<dim3(256, 4),         256, 0, stream>>>(xnT, Wb, Wb + 65536, Wb + 131072, Qt, Kt, Vo);
  attn_mfma_kernel<<<dim3(LL/256, NH*NSPLIT, NB), 256, 0, stream>>>(Qt, Kt, Vo, Opart, lpart);
  proj_gemm  <<<dim3(256, 2),         256, 0, stream>>>(Opart, lpart,
                 (const _Float16*)(Wb + 196608), bp, out);
}

// Round 5
// 245.226 us; speedup vs baseline: 1.5310x; 1.3317x over previous
//
#include <hip/hip_runtime.h>
#include <cstddef>
#include <cstdint>

#define NB 4
#define CC 256
#define LL 4096
#define NG 32
#define CPG 8
#define NH 4
#define DH 64
#define NSPLIT 4
#define PSPLIT 4194304   // fp16 partial-O elements per split: 16*4096*64

static constexpr float EPSV  = 1e-5f;
static constexpr float SCALE_Q = 0.125f * 1.4426950408889634f; // dh^-0.5 * log2(e)

typedef __attribute__((ext_vector_type(8))) short bf16x8;
typedef __attribute__((ext_vector_type(4))) float f32x4;
typedef _Float16 f16x8 __attribute__((ext_vector_type(8)));
typedef _Float16 f16x4 __attribute__((ext_vector_type(4)));
typedef __fp16  h16x2 __attribute__((ext_vector_type(2)));   // cvt_pkrtz native type

__device__ __forceinline__ short f2bf(float f) {
  unsigned u = __float_as_uint(f);
  unsigned r = (u + 0x7fffu + ((u >> 16) & 1u)) >> 16;
  return (short)r;
}
__device__ __forceinline__ short f2h(float f) {
  union { _Float16 h; short s; } u;
  u.h = (_Float16)f;
  return u.s;
}
// element offset of 16B chunk (8 elems) with XOR swizzle: row stride 64 elems
__device__ __forceinline__ int sw(int row, int chunk) {
  return row * 64 + ((chunk ^ (row & 7)) * 8);
}
// async global->LDS DMA, 16B per lane, LDS dest = wave-uniform base + lane*16
typedef __attribute__((address_space(1))) const unsigned int gu32_t;
typedef __attribute__((address_space(3))) unsigned int lu32_t;
__device__ __forceinline__ void gl_lds16(const void* g, void* l) {
  __builtin_amdgcn_global_load_lds((gu32_t*)g, (lu32_t*)l, 16, 0, 0);
}

// ---------------- weight fp32 -> bf16 (Wq/Wk/Wv) or f16 (Wp) ----------------
__global__ __launch_bounds__(256) void wcvt_kernel(
    const float* __restrict__ Wq, const float* __restrict__ Wk,
    const float* __restrict__ Wv, const float* __restrict__ Wp,
    short* __restrict__ dst) {
  const int which = blockIdx.x >> 5;
  const float* src = (which == 0) ? Wq : (which == 1) ? Wk : (which == 2) ? Wv : Wp;
  const int base = (blockIdx.x & 31) * 2048 + threadIdx.x * 8;
  const float4 v0 = *(const float4*)(src + base);
  const float4 v1 = *(const float4*)(src + base + 4);
  short ob[8] __attribute__((aligned(16)));
  if (which < 3) {
    ob[0] = f2bf(v0.x); ob[1] = f2bf(v0.y); ob[2] = f2bf(v0.z); ob[3] = f2bf(v0.w);
    ob[4] = f2bf(v1.x); ob[5] = f2bf(v1.y); ob[6] = f2bf(v1.z); ob[7] = f2bf(v1.w);
  } else {
    ob[0] = f2h(v0.x); ob[1] = f2h(v0.y); ob[2] = f2h(v0.z); ob[3] = f2h(v0.w);
    ob[4] = f2h(v1.x); ob[5] = f2h(v1.y); ob[6] = f2h(v1.z); ob[7] = f2h(v1.w);
  }
  *(uint4*)(dst + which * 65536 + base) = *(const uint4*)ob;
}

// ---------------- GroupNorm -> xnT [n][l][c] bf16 ----------------
__global__ __launch_bounds__(256) void gn_kernel(
    const float* __restrict__ x, const float* __restrict__ gamma,
    const float* __restrict__ beta, short* __restrict__ xnT) {
  const int blk = blockIdx.x;
  const int n = blk >> 5, g = blk & 31;
  const size_t base = ((size_t)n * CC + (size_t)g * CPG) * LL;
  const float* xp = x + base;
  const int NE = CPG * LL;

  float s = 0.f, ss = 0.f;
  for (int i = threadIdx.x * 4; i < NE; i += 256 * 4) {
    float4 v = *(const float4*)(xp + i);
    s  += v.x + v.y + v.z + v.w;
    ss += v.x * v.x + v.y * v.y + v.z * v.z + v.w * v.w;
  }
  #pragma unroll
  for (int off = 32; off; off >>= 1) {
    s  += __shfl_down(s, off);
    ss += __shfl_down(ss, off);
  }
  __shared__ float r1[4], r2[4], stat[2];
  const int wid = threadIdx.x >> 6, lane = threadIdx.x & 63;
  if (lane == 0) { r1[wid] = s; r2[wid] = ss; }
  __syncthreads();
  if (threadIdx.x == 0) {
    float S = 0.f, SS = 0.f;
    #pragma unroll
    for (int w = 0; w < 4; ++w) { S += r1[w]; SS += r2[w]; }
    float mean = S / NE;
    float var  = SS / NE - mean * mean;
    stat[0] = mean;
    stat[1] = rsqrtf(var + EPSV);
  }
  __syncthreads();
  const float mean = stat[0], rstd = stat[1];
  float scl[8], shf[8];
  #pragma unroll
  for (int cc = 0; cc < 8; ++cc) {
    const float gm = gamma[g * CPG + cc];
    scl[cc] = rstd * gm;
    shf[cc] = beta[g * CPG + cc] - mean * rstd * gm;
  }
  for (int j = 0; j < 4; ++j) {
    const int l = j * 1024 + threadIdx.x * 4;
    float4 vv[8];
    #pragma unroll
    for (int cc = 0; cc < 8; ++cc)
      vv[cc] = *(const float4*)(xp + (size_t)cc * LL + l);
    short ob[4][8] __attribute__((aligned(16)));
    #pragma unroll
    for (int cc = 0; cc < 8; ++cc) {
      ob[0][cc] = f2bf(vv[cc].x * scl[cc] + shf[cc]);
      ob[1][cc] = f2bf(vv[cc].y * scl[cc] + shf[cc]);
      ob[2][cc] = f2bf(vv[cc].z * scl[cc] + shf[cc]);
      ob[3][cc] = f2bf(vv[cc].w * scl[cc] + shf[cc]);
    }
    short* op = xnT + ((size_t)n * LL + l) * CC + g * CPG;
    #pragma unroll
    for (int ii = 0; ii < 4; ++ii)
      *(uint4*)(op + (size_t)ii * CC) = *(const uint4*)ob[ii];
  }
}

// ---------------- QKV MFMA GEMM ----------------
// Qt/Kt bf16 [n,h][l][d] (Q scaled by log2e/8).
// Vo f16 [n,h][d][perm(l)]: key dim pre-permuted within each 64-block so the
// attn kernel can stage V via global_load_lds with contiguous 16B per lane.
// perm: pos = 32*(n0>>1) + 8*(lq>>2) + 4*(n0&1) + (lq&3)  (bijective on 64)
__global__ __launch_bounds__(256) void qkv_gemm(
    const short* __restrict__ xnT, const short* __restrict__ Wqb,
    const short* __restrict__ Wkb, const short* __restrict__ Wvb,
    short* __restrict__ Qt, short* __restrict__ Kt, _Float16* __restrict__ Vo) {
  const int lt = blockIdx.x, ot = blockIdx.y;
  const int n = lt >> 6, l0 = (lt & 63) << 6;
  const int wave = threadIdx.x >> 6, lane = threadIdx.x & 63;
  const int lq = lane & 15, quad = lane >> 4;

  const int orow = ot * 64 + wave * 16 + lq;
  const short* wqp = Wqb + orow * CC + quad * 8;
  const short* wkp = Wkb + orow * CC + quad * 8;
  const short* wvp = Wvb + orow * CC + quad * 8;
  const short* xp  = xnT + ((size_t)(n * LL + l0) + lq) * CC + quad * 8;

  const f32x4 z = {0.f, 0.f, 0.f, 0.f};
  f32x4 aq[4] = {z, z, z, z}, ak[4] = {z, z, z, z}, av[4] = {z, z, z, z};

  #pragma unroll
  for (int c0 = 0; c0 < 256; c0 += 32) {
    const bf16x8 fq = *(const bf16x8*)(wqp + c0);
    const bf16x8 fk = *(const bf16x8*)(wkp + c0);
    const bf16x8 fv = *(const bf16x8*)(wvp + c0);
    #pragma unroll
    for (int n0 = 0; n0 < 4; ++n0) {
      const bf16x8 fb = *(const bf16x8*)(xp + (size_t)(n0 * 16) * CC + c0);
      aq[n0] = __builtin_amdgcn_mfma_f32_16x16x32_bf16(fq, fb, aq[n0], 0, 0, 0);
      ak[n0] = __builtin_amdgcn_mfma_f32_16x16x32_bf16(fk, fb, ak[n0], 0, 0, 0);
      av[n0] = __builtin_amdgcn_mfma_f32_16x16x32_bf16(fv, fb, av[n0], 0, 0, 0);
    }
  }

  const size_t hb = (size_t)(n * NH + ot);
  // permuted V write (key dim pre-permuted within 64-block)
  #pragma unroll
  for (int n0 = 0; n0 < 4; ++n0) {
    const int pos = l0 + 32 * (n0 >> 1) + 8 * (lq >> 2) + 4 * (n0 & 1) + (lq & 3);
    #pragma unroll
    for (int r = 0; r < 4; ++r)
      Vo[(hb * DH + wave * 16 + quad * 4 + r) * LL + pos] = (_Float16)av[n0][r];
  }
  __shared__ short qt_lds[64][72], kt_lds[64][72];
  #pragma unroll
  for (int n0 = 0; n0 < 4; ++n0)
    #pragma unroll
    for (int r = 0; r < 4; ++r) {
      qt_lds[n0 * 16 + lq][wave * 16 + quad * 4 + r] = f2bf(aq[n0][r] * SCALE_Q);
      kt_lds[n0 * 16 + lq][wave * 16 + quad * 4 + r] = f2bf(ak[n0][r]);
    }
  __syncthreads();
  #pragma unroll
  for (int i = 0; i < 2; ++i) {
    const int u = threadIdx.x + i * 256;
    const int row = u >> 3, ch = u & 7;
    *(uint4*)(Qt + (hb * LL + l0 + row) * DH + ch * 8) = *(const uint4*)&qt_lds[row][ch * 8];
    *(uint4*)(Kt + (hb * LL + l0 + row) * DH + ch * 8) = *(const uint4*)&kt_lds[row][ch * 8];
  }
}

// ---------------- MFMA flash attention v10: 32 q/wave, 4-way key split ----------------
// grid (LL/128, NH*NSPLIT, NB) = 2048 blocks, block 256 (4 waves).
// Per-wave state halved vs v9: o[2][4]=32 acc, qb[2][2]=16, af[2]=8 -> peak live
// ~90 combined, fits the 128-reg class -> 4 waves/SIMD (4 blocks/CU, 128KB LDS).
// K/V staging via global_load_lds DMA, LDS image identical to proven v9.
__global__ __launch_bounds__(256, 4) void attn_mfma_kernel(
    const short* __restrict__ Qt, const short* __restrict__ Kt,
    const _Float16* __restrict__ Vb, _Float16* __restrict__ Opart,
    float* __restrict__ lpart) {
  __shared__ __align__(16) short    k_lds[2][64 * 64];   // 8 KB each
  __shared__ __align__(16) _Float16 v_lds[2][64 * 64];   // 8 KB each

  const int t = threadIdx.x;
  const int wave = t >> 6, lane = t & 63;
  const int lq = lane & 15, quad = lane >> 4;
  const int l0 = blockIdx.x * 128;
  const int h = blockIdx.y >> 2, split = blockIdx.y & 3;
  const int n = blockIdx.z;
  const int kbase = split * 1024;
  const int R = n * NH + h;
  const size_t hb = (size_t)R * (size_t)LL * DH;
  const short* const Kp = Kt + hb;      // [key][d] bf16
  const _Float16* const Vp = Vb + hb;   // [d][perm(key)] f16

  // Q B-frags: B[n=q][k=d] — wave's 32 q rows
  const int qbase = l0 + wave * 32;
  bf16x8 qb[2][2];
  #pragma unroll
  for (int qf = 0; qf < 2; ++qf)
    #pragma unroll
    for (int c = 0; c < 2; ++c)
      qb[qf][c] = *(const bf16x8*)(Qt + hb + (size_t)(qbase + qf * 16 + lq) * DH + c * 32 + quad * 8);

  const f32x4 z = {0.f, 0.f, 0.f, 0.f};
  f32x4 o[2][4] = {{z, z, z, z}, {z, z, z, z}};
  float lsum[2] = {0.f, 0.f};

  const int srow = t >> 3, sch = t & 7;           // staging: row 0..31 (+32), chunk 0..7
  const int swz8 = ((sch ^ (srow & 7)) * 8);      // pre-swizzled source chunk (elems)
  const short*    const kS0 = Kp + (size_t)srow * DH + swz8;
  const short*    const kS1 = Kp + (size_t)(32 + srow) * DH + swz8;
  const _Float16* const vS0 = Vp + (size_t)srow * LL + swz8;
  const _Float16* const vS1 = Vp + (size_t)(32 + srow) * LL + swz8;

  // stage tile 0 (all DMA)
  gl_lds16(kS0 + (size_t)kbase * DH, &k_lds[0][wave * 512]);
  gl_lds16(kS1 + (size_t)kbase * DH, &k_lds[0][2048 + wave * 512]);
  gl_lds16(vS0 + kbase,              &v_lds[0][wave * 512]);
  gl_lds16(vS1 + kbase,              &v_lds[0][2048 + wave * 512]);
  __syncthreads();

  for (int kt = 0; kt < 16; ++kt) {
    const int cur = kt & 1, nxt = cur ^ 1;
    if (kt < 15) {
      const int kpos = kbase + (kt + 1) * 64;
      gl_lds16(kS0 + (size_t)kpos * DH, &k_lds[nxt][wave * 512]);
      gl_lds16(kS1 + (size_t)kpos * DH, &k_lds[nxt][2048 + wave * 512]);
      gl_lds16(vS0 + kpos,              &v_lds[nxt][wave * 512]);
      gl_lds16(vS1 + kpos,              &v_lds[nxt][2048 + wave * 512]);
    }
    const short* kb = k_lds[cur];
    const _Float16* vbuf = v_lds[cur];

    // ---- two 32-key half-tiles: QK^T -> exp2 -> f16 A-frags -> PV ----
    #pragma unroll
    for (int hh = 0; hh < 2; ++hh) {
      union PU { f16x4 h4[2]; f16x8 h8; } af[2];
      #pragma unroll
      for (int mf2 = 0; mf2 < 2; ++mf2) {
        const int mrow = (hh * 2 + mf2) * 16 + lq;
        const bf16x8 ka0 = *(const bf16x8*)&kb[sw(mrow, quad)];
        const bf16x8 ka1 = *(const bf16x8*)&kb[sw(mrow, 4 + quad)];
        #pragma unroll
        for (int qf = 0; qf < 2; ++qf) {
          f32x4 zz = {0.f, 0.f, 0.f, 0.f};
          zz = __builtin_amdgcn_mfma_f32_16x16x32_bf16(ka0, qb[qf][0], zz, 0, 0, 0);
          zz = __builtin_amdgcn_mfma_f32_16x16x32_bf16(ka1, qb[qf][1], zz, 0, 0, 0);
          const float e0 = __builtin_amdgcn_exp2f(zz[0]);
          const float e1 = __builtin_amdgcn_exp2f(zz[1]);
          const float e2 = __builtin_amdgcn_exp2f(zz[2]);
          const float e3 = __builtin_amdgcn_exp2f(zz[3]);
          lsum[qf] += (e0 + e1) + (e2 + e3);
          union { h16x2 h2[2]; f16x4 h4; } u;
          u.h2[0] = __builtin_amdgcn_cvt_pkrtz(e0, e1);
          u.h2[1] = __builtin_amdgcn_cvt_pkrtz(e2, e3);
          af[qf].h4[mf2] = u.h4;
        }
      }
      // PV for this half: V chunks hh*4+quad hold exactly this half's permuted keys
      #pragma unroll
      for (int df = 0; df < 4; ++df) {
        const f16x8 vb8 = *(const f16x8*)&vbuf[sw(df * 16 + lq, hh * 4 + quad)];
        #pragma unroll
        for (int qf = 0; qf < 2; ++qf)
          o[qf][df] = __builtin_amdgcn_mfma_f32_16x16x32_f16(af[qf].h8, vb8, o[qf][df], 0, 0, 0);
      }
    }

    if (kt < 15) __syncthreads();   // drains DMA (vmcnt) + guards buffer swap
  }

  // ---- epilogue: cross-quad reduce l, store l + raw fp16 partial O ----
  #pragma unroll
  for (int qf = 0; qf < 2; ++qf) {
    lsum[qf] += __shfl_xor(lsum[qf], 16);
    lsum[qf] += __shfl_xor(lsum[qf], 32);
  }
  if (quad == 0) {
    #pragma unroll
    for (int qf = 0; qf < 2; ++qf)
      lpart[((size_t)split * 16 + R) * LL + qbase + qf * 16 + lq] = lsum[qf];
  }
  const size_t pb = ((size_t)split * 16 + R) * (size_t)LL * DH;
  #pragma unroll
  for (int qf = 0; qf < 2; ++qf)
    #pragma unroll
    for (int df = 0; df < 4; ++df)
      #pragma unroll
      for (int r = 0; r < 4; ++r) {
        const int q = qbase + qf * 16 + quad * 4 + r;
        Opart[pb + (size_t)q * DH + df * 16 + lq] = (_Float16)o[qf][df][r];
      }
}

// ---------------- output projection (f16 MFMA, fused normalize, 2 o-tiles) ----------------
__global__ __launch_bounds__(256) void proj_gemm(
    const _Float16* __restrict__ Opart, const float* __restrict__ lpart,
    const _Float16* __restrict__ Wpf, const float* __restrict__ bp,
    float* __restrict__ out) {
  const int lt = blockIdx.x, ot2 = blockIdx.y;   // ot2 covers 128 output channels
  const int n = lt >> 6, l0 = (lt & 63) << 6;
  const int wave = threadIdx.x >> 6, lane = threadIdx.x & 63;
  const int lq = lane & 15, quad = lane >> 4;

  const _Float16* wpp0 = Wpf + (ot2 * 128 + wave * 16 + lq) * CC + quad * 8;
  const _Float16* wpp1 = wpp0 + 64 * CC;

  // per-(n0,h) 1/l as f16 (l = sum of 4 split partials)
  _Float16 invl[4][4];
  #pragma unroll
  for (int n0 = 0; n0 < 4; ++n0) {
    const int q = l0 + n0 * 16 + lq;
    #pragma unroll
    for (int h = 0; h < 4; ++h) {
      const size_t rr = (size_t)(n * NH + h) * LL + q;
      invl[n0][h] = (_Float16)(1.0f / (lpart[rr] + lpart[rr + 16 * (size_t)LL]
                                     + lpart[rr + 32 * (size_t)LL] + lpart[rr + 48 * (size_t)LL]));
    }
  }

  const f32x4 z = {0.f, 0.f, 0.f, 0.f};
  f32x4 acc[2][4] = {{z, z, z, z}, {z, z, z, z}};
  #pragma unroll
  for (int c0 = 0; c0 < 256; c0 += 32) {
    const int h = c0 >> 6;
    const int d0 = (c0 & 63) + quad * 8;
    const f16x8 fa0 = *(const f16x8*)(wpp0 + c0);
    const f16x8 fa1 = *(const f16x8*)(wpp1 + c0);
    #pragma unroll
    for (int n0 = 0; n0 < 4; ++n0) {
      const int q = l0 + n0 * 16 + lq;
      const size_t e = ((size_t)(n * NH + h) * LL + q) * DH + d0;
      const f16x8 b0 = *(const f16x8*)(Opart + e);
      const f16x8 b1 = *(const f16x8*)(Opart + e + (size_t)PSPLIT);
      const f16x8 b2 = *(const f16x8*)(Opart + e + 2 * (size_t)PSPLIT);
      const f16x8 b3 = *(const f16x8*)(Opart + e + 3 * (size_t)PSPLIT);
      f16x8 sc8;
      #pragma unroll
      for (int i = 0; i < 8; ++i) sc8[i] = invl[n0][h];
      const f16x8 fb = ((b0 + b1) + (b2 + b3)) * sc8;
      acc[0][n0] = __builtin_amdgcn_mfma_f32_16x16x32_f16(fa0, fb, acc[0][n0], 0, 0, 0);
      acc[1][n0] = __builtin_amdgcn_mfma_f32_16x16x32_f16(fa1, fb, acc[1][n0], 0, 0, 0);
    }
  }
  #pragma unroll
  for (int w = 0; w < 2; ++w)
    #pragma unroll
    for (int r = 0; r < 4; ++r) {
      const int oo = ot2 * 128 + w * 64 + wave * 16 + quad * 4 + r;
      const float bias = bp[oo];
      #pragma unroll
      for (int n0 = 0; n0 < 4; ++n0)
        out[((size_t)n * CC + oo) * LL + l0 + n0 * 16 + lq] = acc[w][n0][r] + bias;
    }
}

extern "C" void kernel_launch(void* const* d_in, const int* in_sizes, int n_in,
                              void* d_out, int out_size, void* d_ws, size_t ws_size,
                              hipStream_t stream) {
  const float* x     = (const float*)d_in[0];
  const float* gamma = (const float*)d_in[1];
  const float* beta  = (const float*)d_in[2];
  const float* Wq    = (const float*)d_in[3];
  const float* Wk    = (const float*)d_in[4];
  const float* Wv    = (const float*)d_in[5];
  const float* Wp    = (const float*)d_in[6];
  const float* bp    = (const float*)d_in[7];
  float* out = (float*)d_out;

  const size_t S = (size_t)NB * CC * LL;  // 4,194,304
  short*     xnT = (short*)d_ws;          // bf16 [n][l][c]
  short*     Qt  = xnT + S;               // bf16 [n,h][l][d]
  short*     Kt  = Qt + S;
  _Float16*  Vo  = (_Float16*)(Kt + S);   // f16 [n,h][d][perm(l)]
  short*     Wb  = (short*)(Vo + S);      // 4 x 65536 (bf16 x3, f16 x1)
  _Float16*  Opart = (_Float16*)(Wb + 4 * 65536);        // NSPLIT x 8 MB fp16
  float*     lpart = (float*)(Opart + NSPLIT * (size_t)PSPLIT); // NSPLIT x 256KB fp32

  gn_kernel  <<<NB * NG,              256, 0, stream>>>(x, gamma, beta, xnT);
  wcvt_kernel<<<128,                  256, 0, stream>>>(Wq, Wk, Wv, Wp, Wb);
  qkv_gemm   <<<dim3(256, 4),         256, 0, stream>>>(xnT, Wb, Wb + 65536, Wb + 131072, Qt, Kt, Vo);
  attn_mfma_kernel<<<dim3(LL/128, NH*NSPLIT, NB), 256, 0, stream>>>(Qt, Kt, Vo, Opart, lpart);
  proj_gemm  <<<dim3(256, 2),         256, 0, stream>>>(Opart, lpart,
                 (const _Float16*)(Wb + 196608), bp, out);
}

// Round 6
// 218.478 us; speedup vs baseline: 1.7184x; 1.1224x over previous
//
#include <hip/hip_runtime.h>
#include <cstddef>
#include <cstdint>

#define NB 4
#define CC 256
#define LL 4096
#define NG 32
#define CPG 8
#define NH 4
#define DH 64
#define NSPLIT 2
#define PSPLIT 4194304   // fp16 partial-O elements per split: 16*4096*64

static constexpr float EPSV  = 1e-5f;
static constexpr float SCALE_Q = 0.125f * 1.4426950408889634f; // dh^-0.5 * log2(e)

typedef __attribute__((ext_vector_type(8))) short bf16x8;
typedef __attribute__((ext_vector_type(4))) float f32x4;
typedef _Float16 f16x8 __attribute__((ext_vector_type(8)));
typedef _Float16 f16x4 __attribute__((ext_vector_type(4)));
typedef __fp16  h16x2 __attribute__((ext_vector_type(2)));   // cvt_pkrtz native type

__device__ __forceinline__ short f2bf(float f) {
  unsigned u = __float_as_uint(f);
  unsigned r = (u + 0x7fffu + ((u >> 16) & 1u)) >> 16;
  return (short)r;
}
__device__ __forceinline__ short f2h(float f) {
  union { _Float16 h; short s; } u;
  u.h = (_Float16)f;
  return u.s;
}
// element offset of 16B chunk (8 elems) with XOR swizzle: row stride 64 elems
__device__ __forceinline__ int sw(int row, int chunk) {
  return row * 64 + ((chunk ^ (row & 7)) * 8);
}
// async global->LDS DMA, 16B per lane, LDS dest = wave-uniform base + lane*16
typedef __attribute__((address_space(1))) const unsigned int gu32_t;
typedef __attribute__((address_space(3))) unsigned int lu32_t;
__device__ __forceinline__ void gl_lds16(const void* g, void* l) {
  __builtin_amdgcn_global_load_lds((gu32_t*)g, (lu32_t*)l, 16, 0, 0);
}

// ---------------- weight fp32 -> bf16 (Wq/Wk/Wv) or f16 (Wp) ----------------
__global__ __launch_bounds__(256) void wcvt_kernel(
    const float* __restrict__ Wq, const float* __restrict__ Wk,
    const float* __restrict__ Wv, const float* __restrict__ Wp,
    short* __restrict__ dst) {
  const int which = blockIdx.x >> 5;
  const float* src = (which == 0) ? Wq : (which == 1) ? Wk : (which == 2) ? Wv : Wp;
  const int base = (blockIdx.x & 31) * 2048 + threadIdx.x * 8;
  const float4 v0 = *(const float4*)(src + base);
  const float4 v1 = *(const float4*)(src + base + 4);
  short ob[8] __attribute__((aligned(16)));
  if (which < 3) {
    ob[0] = f2bf(v0.x); ob[1] = f2bf(v0.y); ob[2] = f2bf(v0.z); ob[3] = f2bf(v0.w);
    ob[4] = f2bf(v1.x); ob[5] = f2bf(v1.y); ob[6] = f2bf(v1.z); ob[7] = f2bf(v1.w);
  } else {
    ob[0] = f2h(v0.x); ob[1] = f2h(v0.y); ob[2] = f2h(v0.z); ob[3] = f2h(v0.w);
    ob[4] = f2h(v1.x); ob[5] = f2h(v1.y); ob[6] = f2h(v1.z); ob[7] = f2h(v1.w);
  }
  *(uint4*)(dst + which * 65536 + base) = *(const uint4*)ob;
}

// ---------------- GroupNorm -> xnT [n][l][c] bf16 ----------------
__global__ __launch_bounds__(256) void gn_kernel(
    const float* __restrict__ x, const float* __restrict__ gamma,
    const float* __restrict__ beta, short* __restrict__ xnT) {
  const int blk = blockIdx.x;
  const int n = blk >> 5, g = blk & 31;
  const size_t base = ((size_t)n * CC + (size_t)g * CPG) * LL;
  const float* xp = x + base;
  const int NE = CPG * LL;

  float s = 0.f, ss = 0.f;
  for (int i = threadIdx.x * 4; i < NE; i += 256 * 4) {
    float4 v = *(const float4*)(xp + i);
    s  += v.x + v.y + v.z + v.w;
    ss += v.x * v.x + v.y * v.y + v.z * v.z + v.w * v.w;
  }
  #pragma unroll
  for (int off = 32; off; off >>= 1) {
    s  += __shfl_down(s, off);
    ss += __shfl_down(ss, off);
  }
  __shared__ float r1[4], r2[4], stat[2];
  const int wid = threadIdx.x >> 6, lane = threadIdx.x & 63;
  if (lane == 0) { r1[wid] = s; r2[wid] = ss; }
  __syncthreads();
  if (threadIdx.x == 0) {
    float S = 0.f, SS = 0.f;
    #pragma unroll
    for (int w = 0; w < 4; ++w) { S += r1[w]; SS += r2[w]; }
    float mean = S / NE;
    float var  = SS / NE - mean * mean;
    stat[0] = mean;
    stat[1] = rsqrtf(var + EPSV);
  }
  __syncthreads();
  const float mean = stat[0], rstd = stat[1];
  float scl[8], shf[8];
  #pragma unroll
  for (int cc = 0; cc < 8; ++cc) {
    const float gm = gamma[g * CPG + cc];
    scl[cc] = rstd * gm;
    shf[cc] = beta[g * CPG + cc] - mean * rstd * gm;
  }
  for (int j = 0; j < 4; ++j) {
    const int l = j * 1024 + threadIdx.x * 4;
    float4 vv[8];
    #pragma unroll
    for (int cc = 0; cc < 8; ++cc)
      vv[cc] = *(const float4*)(xp + (size_t)cc * LL + l);
    short ob[4][8] __attribute__((aligned(16)));
    #pragma unroll
    for (int cc = 0; cc < 8; ++cc) {
      ob[0][cc] = f2bf(vv[cc].x * scl[cc] + shf[cc]);
      ob[1][cc] = f2bf(vv[cc].y * scl[cc] + shf[cc]);
      ob[2][cc] = f2bf(vv[cc].z * scl[cc] + shf[cc]);
      ob[3][cc] = f2bf(vv[cc].w * scl[cc] + shf[cc]);
    }
    short* op = xnT + ((size_t)n * LL + l) * CC + g * CPG;
    #pragma unroll
    for (int ii = 0; ii < 4; ++ii)
      *(uint4*)(op + (size_t)ii * CC) = *(const uint4*)ob[ii];
  }
}

// ---------------- QKV MFMA GEMM ----------------
// Qt/Kt bf16 [n,h][l][d] (Q scaled by log2e/8).
// Vo f16 [n,h][d][perm(l)]: key dim pre-permuted within each 64-block so the
// attn kernel can stage V via global_load_lds with contiguous 16B per lane.
// perm: pos = 32*(n0>>1) + 8*(lq>>2) + 4*(n0&1) + (lq&3)  (bijective on 64)
__global__ __launch_bounds__(256) void qkv_gemm(
    const short* __restrict__ xnT, const short* __restrict__ Wqb,
    const short* __restrict__ Wkb, const short* __restrict__ Wvb,
    short* __restrict__ Qt, short* __restrict__ Kt, _Float16* __restrict__ Vo) {
  const int lt = blockIdx.x, ot = blockIdx.y;
  const int n = lt >> 6, l0 = (lt & 63) << 6;
  const int wave = threadIdx.x >> 6, lane = threadIdx.x & 63;
  const int lq = lane & 15, quad = lane >> 4;

  const int orow = ot * 64 + wave * 16 + lq;
  const short* wqp = Wqb + orow * CC + quad * 8;
  const short* wkp = Wkb + orow * CC + quad * 8;
  const short* wvp = Wvb + orow * CC + quad * 8;
  const short* xp  = xnT + ((size_t)(n * LL + l0) + lq) * CC + quad * 8;

  const f32x4 z = {0.f, 0.f, 0.f, 0.f};
  f32x4 aq[4] = {z, z, z, z}, ak[4] = {z, z, z, z}, av[4] = {z, z, z, z};

  #pragma unroll
  for (int c0 = 0; c0 < 256; c0 += 32) {
    const bf16x8 fq = *(const bf16x8*)(wqp + c0);
    const bf16x8 fk = *(const bf16x8*)(wkp + c0);
    const bf16x8 fv = *(const bf16x8*)(wvp + c0);
    #pragma unroll
    for (int n0 = 0; n0 < 4; ++n0) {
      const bf16x8 fb = *(const bf16x8*)(xp + (size_t)(n0 * 16) * CC + c0);
      aq[n0] = __builtin_amdgcn_mfma_f32_16x16x32_bf16(fq, fb, aq[n0], 0, 0, 0);
      ak[n0] = __builtin_amdgcn_mfma_f32_16x16x32_bf16(fk, fb, ak[n0], 0, 0, 0);
      av[n0] = __builtin_amdgcn_mfma_f32_16x16x32_bf16(fv, fb, av[n0], 0, 0, 0);
    }
  }

  const size_t hb = (size_t)(n * NH + ot);
  // permuted V write (key dim pre-permuted within 64-block)
  #pragma unroll
  for (int n0 = 0; n0 < 4; ++n0) {
    const int pos = l0 + 32 * (n0 >> 1) + 8 * (lq >> 2) + 4 * (n0 & 1) + (lq & 3);
    #pragma unroll
    for (int r = 0; r < 4; ++r)
      Vo[(hb * DH + wave * 16 + quad * 4 + r) * LL + pos] = (_Float16)av[n0][r];
  }
  __shared__ short qt_lds[64][72], kt_lds[64][72];
  #pragma unroll
  for (int n0 = 0; n0 < 4; ++n0)
    #pragma unroll
    for (int r = 0; r < 4; ++r) {
      qt_lds[n0 * 16 + lq][wave * 16 + quad * 4 + r] = f2bf(aq[n0][r] * SCALE_Q);
      kt_lds[n0 * 16 + lq][wave * 16 + quad * 4 + r] = f2bf(ak[n0][r]);
    }
  __syncthreads();
  #pragma unroll
  for (int i = 0; i < 2; ++i) {
    const int u = threadIdx.x + i * 256;
    const int row = u >> 3, ch = u & 7;
    *(uint4*)(Qt + (hb * LL + l0 + row) * DH + ch * 8) = *(const uint4*)&qt_lds[row][ch * 8];
    *(uint4*)(Kt + (hb * LL + l0 + row) * DH + ch * 8) = *(const uint4*)&kt_lds[row][ch * 8];
  }
}

// ---------------- MFMA flash attention v11: 64 q/wave, 2-way key split ----------------
// grid (LL/256, NH*NSPLIT, NB) = 512 blocks, block 256 (4 waves).
// v9's DMA staging (K and V via global_load_lds: linear LDS dest, pre-swizzled
// global source) at the PROVEN spill-free (256,2) register class. 64 q/wave
// keeps the per-q overhead minimal: 16 b128 LDS reads + ~96 VALU per 64q-tile
// vs 32/164 at 32 q/wave (round 5). MFMA pipe is the binding pipe (~33 us floor).
__global__ __launch_bounds__(256, 2) void attn_mfma_kernel(
    const short* __restrict__ Qt, const short* __restrict__ Kt,
    const _Float16* __restrict__ Vb, _Float16* __restrict__ Opart,
    float* __restrict__ lpart) {
  __shared__ __align__(16) short    k_lds[2][64 * 64];   // 8 KB each
  __shared__ __align__(16) _Float16 v_lds[2][64 * 64];   // 8 KB each

  const int t = threadIdx.x;
  const int wave = t >> 6, lane = t & 63;
  const int lq = lane & 15, quad = lane >> 4;
  const int l0 = blockIdx.x * 256;
  const int h = blockIdx.y >> 1, split = blockIdx.y & 1;
  const int n = blockIdx.z;
  const int kbase = split * 2048;
  const int R = n * NH + h;
  const size_t hb = (size_t)R * (size_t)LL * DH;
  const short* const Kp = Kt + hb;      // [key][d] bf16
  const _Float16* const Vp = Vb + hb;   // [d][perm(key)] f16

  // Q B-frags: B[n=q][k=d] — wave's 64 q rows
  const int qbase = l0 + wave * 64;
  bf16x8 qb[4][2];
  #pragma unroll
  for (int qf = 0; qf < 4; ++qf)
    #pragma unroll
    for (int c = 0; c < 2; ++c)
      qb[qf][c] = *(const bf16x8*)(Qt + hb + (size_t)(qbase + qf * 16 + lq) * DH + c * 32 + quad * 8);

  const f32x4 z = {0.f, 0.f, 0.f, 0.f};
  f32x4 o[4][4] = {{z, z, z, z}, {z, z, z, z}, {z, z, z, z}, {z, z, z, z}};
  float lsum[4] = {0.f, 0.f, 0.f, 0.f};

  const int srow = t >> 3, sch = t & 7;           // staging: row 0..31 (+32), chunk 0..7
  const int swz8 = ((sch ^ (srow & 7)) * 8);      // pre-swizzled source chunk (elems)
  const short*    const kS0 = Kp + (size_t)srow * DH + swz8;
  const short*    const kS1 = Kp + (size_t)(32 + srow) * DH + swz8;
  const _Float16* const vS0 = Vp + (size_t)srow * LL + swz8;
  const _Float16* const vS1 = Vp + (size_t)(32 + srow) * LL + swz8;

  // stage tile 0 (all DMA)
  gl_lds16(kS0 + (size_t)kbase * DH, &k_lds[0][wave * 512]);
  gl_lds16(kS1 + (size_t)kbase * DH, &k_lds[0][2048 + wave * 512]);
  gl_lds16(vS0 + kbase,              &v_lds[0][wave * 512]);
  gl_lds16(vS1 + kbase,              &v_lds[0][2048 + wave * 512]);
  __syncthreads();

  for (int kt = 0; kt < 32; ++kt) {
    const int cur = kt & 1, nxt = cur ^ 1;
    if (kt < 31) {
      const int kpos = kbase + (kt + 1) * 64;
      gl_lds16(kS0 + (size_t)kpos * DH, &k_lds[nxt][wave * 512]);
      gl_lds16(kS1 + (size_t)kpos * DH, &k_lds[nxt][2048 + wave * 512]);
      gl_lds16(vS0 + kpos,              &v_lds[nxt][wave * 512]);
      gl_lds16(vS1 + kpos,              &v_lds[nxt][2048 + wave * 512]);
    }
    const short* kb = k_lds[cur];
    const _Float16* vbuf = v_lds[cur];

    // ---- two 32-key half-tiles: QK^T -> exp2 -> f16 A-frags -> PV ----
    #pragma unroll
    for (int hh = 0; hh < 2; ++hh) {
      union PU { f16x4 h4[2]; f16x8 h8; } af[4];
      #pragma unroll
      for (int mf2 = 0; mf2 < 2; ++mf2) {
        const int mrow = (hh * 2 + mf2) * 16 + lq;
        const bf16x8 ka0 = *(const bf16x8*)&kb[sw(mrow, quad)];
        const bf16x8 ka1 = *(const bf16x8*)&kb[sw(mrow, 4 + quad)];
        #pragma unroll
        for (int qf = 0; qf < 4; ++qf) {
          f32x4 zz = {0.f, 0.f, 0.f, 0.f};
          zz = __builtin_amdgcn_mfma_f32_16x16x32_bf16(ka0, qb[qf][0], zz, 0, 0, 0);
          zz = __builtin_amdgcn_mfma_f32_16x16x32_bf16(ka1, qb[qf][1], zz, 0, 0, 0);
          const float e0 = __builtin_amdgcn_exp2f(zz[0]);
          const float e1 = __builtin_amdgcn_exp2f(zz[1]);
          const float e2 = __builtin_amdgcn_exp2f(zz[2]);
          const float e3 = __builtin_amdgcn_exp2f(zz[3]);
          lsum[qf] += (e0 + e1) + (e2 + e3);
          union { h16x2 h2[2]; f16x4 h4; } u;
          u.h2[0] = __builtin_amdgcn_cvt_pkrtz(e0, e1);
          u.h2[1] = __builtin_amdgcn_cvt_pkrtz(e2, e3);
          af[qf].h4[mf2] = u.h4;
        }
      }
      // PV for this half: V chunks hh*4+quad hold exactly this half's permuted keys
      #pragma unroll
      for (int df = 0; df < 4; ++df) {
        const f16x8 vb8 = *(const f16x8*)&vbuf[sw(df * 16 + lq, hh * 4 + quad)];
        #pragma unroll
        for (int qf = 0; qf < 4; ++qf)
          o[qf][df] = __builtin_amdgcn_mfma_f32_16x16x32_f16(af[qf].h8, vb8, o[qf][df], 0, 0, 0);
      }
    }

    if (kt < 31) __syncthreads();   // drains DMA (vmcnt) + guards buffer swap
  }

  // ---- epilogue: cross-quad reduce l, store l + raw fp16 partial O ----
  #pragma unroll
  for (int qf = 0; qf < 4; ++qf) {
    lsum[qf] += __shfl_xor(lsum[qf], 16);
    lsum[qf] += __shfl_xor(lsum[qf], 32);
  }
  if (quad == 0) {
    #pragma unroll
    for (int qf = 0; qf < 4; ++qf)
      lpart[((size_t)split * 16 + R) * LL + qbase + qf * 16 + lq] = lsum[qf];
  }
  const size_t pb = ((size_t)split * 16 + R) * (size_t)LL * DH;
  #pragma unroll
  for (int qf = 0; qf < 4; ++qf)
    #pragma unroll
    for (int df = 0; df < 4; ++df)
      #pragma unroll
      for (int r = 0; r < 4; ++r) {
        const int q = qbase + qf * 16 + quad * 4 + r;
        Opart[pb + (size_t)q * DH + df * 16 + lq] = (_Float16)o[qf][df][r];
      }
}

// ---------------- output projection (f16 MFMA, fused normalize, 2 o-tiles) ----------------
__global__ __launch_bounds__(256) void proj_gemm(
    const _Float16* __restrict__ Opart, const float* __restrict__ lpart,
    const _Float16* __restrict__ Wpf, const float* __restrict__ bp,
    float* __restrict__ out) {
  const int lt = blockIdx.x, ot2 = blockIdx.y;   // ot2 covers 128 output channels
  const int n = lt >> 6, l0 = (lt & 63) << 6;
  const int wave = threadIdx.x >> 6, lane = threadIdx.x & 63;
  const int lq = lane & 15, quad = lane >> 4;

  const _Float16* wpp0 = Wpf + (ot2 * 128 + wave * 16 + lq) * CC + quad * 8;
  const _Float16* wpp1 = wpp0 + 64 * CC;

  // per-(n0,h) 1/l as f16 (l = lpart split0 + split1)
  _Float16 invl[4][4];
  #pragma unroll
  for (int n0 = 0; n0 < 4; ++n0) {
    const int q = l0 + n0 * 16 + lq;
    #pragma unroll
    for (int h = 0; h < 4; ++h) {
      const size_t rr = (size_t)(n * NH + h) * LL + q;
      invl[n0][h] = (_Float16)(1.0f / (lpart[rr] + lpart[rr + 16 * (size_t)LL]));
    }
  }

  const f32x4 z = {0.f, 0.f, 0.f, 0.f};
  f32x4 acc[2][4] = {{z, z, z, z}, {z, z, z, z}};
  #pragma unroll
  for (int c0 = 0; c0 < 256; c0 += 32) {
    const int h = c0 >> 6;
    const int d0 = (c0 & 63) + quad * 8;
    const f16x8 fa0 = *(const f16x8*)(wpp0 + c0);
    const f16x8 fa1 = *(const f16x8*)(wpp1 + c0);
    #pragma unroll
    for (int n0 = 0; n0 < 4; ++n0) {
      const int q = l0 + n0 * 16 + lq;
      const size_t e = ((size_t)(n * NH + h) * LL + q) * DH + d0;
      const f16x8 b0 = *(const f16x8*)(Opart + e);
      const f16x8 b1 = *(const f16x8*)(Opart + e + (size_t)PSPLIT);
      f16x8 sc8;
      #pragma unroll
      for (int i = 0; i < 8; ++i) sc8[i] = invl[n0][h];
      const f16x8 fb = (b0 + b1) * sc8;
      acc[0][n0] = __builtin_amdgcn_mfma_f32_16x16x32_f16(fa0, fb, acc[0][n0], 0, 0, 0);
      acc[1][n0] = __builtin_amdgcn_mfma_f32_16x16x32_f16(fa1, fb, acc[1][n0], 0, 0, 0);
    }
  }
  #pragma unroll
  for (int w = 0; w < 2; ++w)
    #pragma unroll
    for (int r = 0; r < 4; ++r) {
      const int oo = ot2 * 128 + w * 64 + wave * 16 + quad * 4 + r;
      const float bias = bp[oo];
      #pragma unroll
      for (int n0 = 0; n0 < 4; ++n0)
        out[((size_t)n * CC + oo) * LL + l0 + n0 * 16 + lq] = acc[w][n0][r] + bias;
    }
}

extern "C" void kernel_launch(void* const* d_in, const int* in_sizes, int n_in,
                              void* d_out, int out_size, void* d_ws, size_t ws_size,
                              hipStream_t stream) {
  const float* x     = (const float*)d_in[0];
  const float* gamma = (const float*)d_in[1];
  const float* beta  = (const float*)d_in[2];
  const float* Wq    = (const float*)d_in[3];
  const float* Wk    = (const float*)d_in[4];
  const float* Wv    = (const float*)d_in[5];
  const float* Wp    = (const float*)d_in[6];
  const float* bp    = (const float*)d_in[7];
  float* out = (float*)d_out;

  const size_t S = (size_t)NB * CC * LL;  // 4,194,304
  short*     xnT = (short*)d_ws;          // bf16 [n][l][c]
  short*     Qt  = xnT + S;               // bf16 [n,h][l][d]
  short*     Kt  = Qt + S;
  _Float16*  Vo  = (_Float16*)(Kt + S);   // f16 [n,h][d][perm(l)]
  short*     Wb  = (short*)(Vo + S);      // 4 x 65536 (bf16 x3, f16 x1)
  _Float16*  Opart = (_Float16*)(Wb + 4 * 65536);        // NSPLIT x 8 MB fp16
  float*     lpart = (float*)(Opart + NSPLIT * (size_t)PSPLIT); // NSPLIT x 256KB fp32

  gn_kernel  <<<NB * NG,              256, 0, stream>>>(x, gamma, beta, xnT);
  wcvt_kernel<<<128,                  256, 0, stream>>>(Wq, Wk, Wv, Wp, Wb);
  qkv_gemm   <<<dim3(256, 4),         256, 0, stream>>>(xnT, Wb, Wb + 65536, Wb + 131072, Qt, Kt, Vo);
  attn_mfma_kernel<<<dim3(LL/256, NH*NSPLIT, NB), 256, 0, stream>>>(Qt, Kt, Vo, Opart, lpart);
  proj_gemm  <<<dim3(256, 2),         256, 0, stream>>>(Opart, lpart,
                 (const _Float16*)(Wb + 196608), bp, out);
}

// Round 7
// 205.395 us; speedup vs baseline: 1.8279x; 1.0637x over previous
//
#include <hip/hip_runtime.h>
#include <cstddef>
#include <cstdint>

#define NB 4
#define CC 256
#define LL 4096
#define NG 32
#define CPG 8
#define NH 4
#define DH 64
#define PSPLIT 4194304   // fp16 partial-O elements per split: 16*4096*64

static constexpr float EPSV  = 1e-5f;
static constexpr float SCALE_Q = 0.125f * 1.4426950408889634f; // dh^-0.5 * log2(e)

typedef __attribute__((ext_vector_type(8))) short bf16x8;
typedef __attribute__((ext_vector_type(4))) float f32x4;
typedef _Float16 f16x8 __attribute__((ext_vector_type(8)));
typedef _Float16 f16x4 __attribute__((ext_vector_type(4)));
typedef __fp16  h16x2 __attribute__((ext_vector_type(2)));   // cvt_pkrtz native type

__device__ __forceinline__ short f2bf(float f) {
  unsigned u = __float_as_uint(f);
  unsigned r = (u + 0x7fffu + ((u >> 16) & 1u)) >> 16;
  return (short)r;
}
__device__ __forceinline__ short f2h(float f) {
  union { _Float16 h; short s; } u;
  u.h = (_Float16)f;
  return u.s;
}
// element offset of 16B chunk (8 elems) with XOR swizzle: row stride 64 elems
__device__ __forceinline__ int sw(int row, int chunk) {
  return row * 64 + ((chunk ^ (row & 7)) * 8);
}

// ---------------- weight fp32 -> bf16 (Wq/Wk/Wv) or f16 (Wp) ----------------
__global__ __launch_bounds__(256) void wcvt_kernel(
    const float* __restrict__ Wq, const float* __restrict__ Wk,
    const float* __restrict__ Wv, const float* __restrict__ Wp,
    short* __restrict__ dst) {
  const int which = blockIdx.x >> 5;
  const float* src = (which == 0) ? Wq : (which == 1) ? Wk : (which == 2) ? Wv : Wp;
  const int base = (blockIdx.x & 31) * 2048 + threadIdx.x * 8;
  const float4 v0 = *(const float4*)(src + base);
  const float4 v1 = *(const float4*)(src + base + 4);
  short ob[8] __attribute__((aligned(16)));
  if (which < 3) {
    ob[0] = f2bf(v0.x); ob[1] = f2bf(v0.y); ob[2] = f2bf(v0.z); ob[3] = f2bf(v0.w);
    ob[4] = f2bf(v1.x); ob[5] = f2bf(v1.y); ob[6] = f2bf(v1.z); ob[7] = f2bf(v1.w);
  } else {
    ob[0] = f2h(v0.x); ob[1] = f2h(v0.y); ob[2] = f2h(v0.z); ob[3] = f2h(v0.w);
    ob[4] = f2h(v1.x); ob[5] = f2h(v1.y); ob[6] = f2h(v1.z); ob[7] = f2h(v1.w);
  }
  *(uint4*)(dst + which * 65536 + base) = *(const uint4*)ob;
}

// ---------------- GroupNorm stats: 512 blocks = (n,g) x 4 quarters ----------------
// Each block reduces 8 ch x 1024 l = 32KB -> 2 partial floats.
__global__ __launch_bounds__(256) void gn_stats(
    const float* __restrict__ x, float* __restrict__ pstat) {
  const int blk = blockIdx.x;
  const int grp = blk >> 2, qtr = blk & 3;          // grp = n*32+g
  const float* xp = x + (size_t)grp * CPG * LL + qtr * 1024 + threadIdx.x * 4;

  float s = 0.f, ss = 0.f;
  #pragma unroll
  for (int cc = 0; cc < 8; ++cc) {
    const float4 v = *(const float4*)(xp + (size_t)cc * LL);
    s  += v.x + v.y + v.z + v.w;
    ss += v.x * v.x + v.y * v.y + v.z * v.z + v.w * v.w;
  }
  #pragma unroll
  for (int off = 32; off; off >>= 1) {
    s  += __shfl_down(s, off);
    ss += __shfl_down(ss, off);
  }
  __shared__ float r1[4], r2[4];
  const int wid = threadIdx.x >> 6, lane = threadIdx.x & 63;
  if (lane == 0) { r1[wid] = s; r2[wid] = ss; }
  __syncthreads();
  if (threadIdx.x == 0) {
    float S = 0.f, SS = 0.f;
    #pragma unroll
    for (int w = 0; w < 4; ++w) { S += r1[w]; SS += r2[w]; }
    pstat[blk * 2]     = S;
    pstat[blk * 2 + 1] = SS;
  }
}

// ---------------- GroupNorm apply -> xnT [n][l][c] bf16: 512 blocks ----------------
__global__ __launch_bounds__(256) void gn_apply(
    const float* __restrict__ x, const float* __restrict__ gamma,
    const float* __restrict__ beta, const float* __restrict__ pstat,
    short* __restrict__ xnT) {
  const int blk = blockIdx.x;
  const int grp = blk >> 2, j = blk & 3;            // grp = n*32+g, j = l-chunk
  const int n = grp >> 5, g = grp & 31;
  const float* xp = x + (size_t)grp * CPG * LL;
  const int NE = CPG * LL;

  float S = 0.f, SS = 0.f;
  #pragma unroll
  for (int w = 0; w < 4; ++w) {
    S  += pstat[grp * 8 + w * 2];
    SS += pstat[grp * 8 + w * 2 + 1];
  }
  const float mean = S / NE;
  const float rstd = rsqrtf(SS / NE - mean * mean + EPSV);

  float scl[8], shf[8];
  #pragma unroll
  for (int cc = 0; cc < 8; ++cc) {
    const float gm = gamma[g * CPG + cc];
    scl[cc] = rstd * gm;
    shf[cc] = beta[g * CPG + cc] - mean * rstd * gm;
  }
  const int l = j * 1024 + threadIdx.x * 4;
  float4 vv[8];
  #pragma unroll
  for (int cc = 0; cc < 8; ++cc)
    vv[cc] = *(const float4*)(xp + (size_t)cc * LL + l);
  short ob[4][8] __attribute__((aligned(16)));
  #pragma unroll
  for (int cc = 0; cc < 8; ++cc) {
    ob[0][cc] = f2bf(vv[cc].x * scl[cc] + shf[cc]);
    ob[1][cc] = f2bf(vv[cc].y * scl[cc] + shf[cc]);
    ob[2][cc] = f2bf(vv[cc].z * scl[cc] + shf[cc]);
    ob[3][cc] = f2bf(vv[cc].w * scl[cc] + shf[cc]);
  }
  short* op = xnT + ((size_t)n * LL + l) * CC + g * CPG;
  #pragma unroll
  for (int ii = 0; ii < 4; ++ii)
    *(uint4*)(op + (size_t)ii * CC) = *(const uint4*)ob[ii];
}

// ---------------- QKV MFMA GEMM ----------------
// Qt/Kt bf16 [n,h][l][d] (Q scaled by log2e/8). Vo f16 [n,h][d][l].
__global__ __launch_bounds__(256) void qkv_gemm(
    const short* __restrict__ xnT, const short* __restrict__ Wqb,
    const short* __restrict__ Wkb, const short* __restrict__ Wvb,
    short* __restrict__ Qt, short* __restrict__ Kt, _Float16* __restrict__ Vo) {
  const int lt = blockIdx.x, ot = blockIdx.y;
  const int n = lt >> 6, l0 = (lt & 63) << 6;
  const int wave = threadIdx.x >> 6, lane = threadIdx.x & 63;
  const int lq = lane & 15, quad = lane >> 4;

  const int orow = ot * 64 + wave * 16 + lq;
  const short* wqp = Wqb + orow * CC + quad * 8;
  const short* wkp = Wkb + orow * CC + quad * 8;
  const short* wvp = Wvb + orow * CC + quad * 8;
  const short* xp  = xnT + ((size_t)(n * LL + l0) + lq) * CC + quad * 8;

  const f32x4 z = {0.f, 0.f, 0.f, 0.f};
  f32x4 aq[4] = {z, z, z, z}, ak[4] = {z, z, z, z}, av[4] = {z, z, z, z};

  #pragma unroll
  for (int c0 = 0; c0 < 256; c0 += 32) {
    const bf16x8 fq = *(const bf16x8*)(wqp + c0);
    const bf16x8 fk = *(const bf16x8*)(wkp + c0);
    const bf16x8 fv = *(const bf16x8*)(wvp + c0);
    #pragma unroll
    for (int n0 = 0; n0 < 4; ++n0) {
      const bf16x8 fb = *(const bf16x8*)(xp + (size_t)(n0 * 16) * CC + c0);
      aq[n0] = __builtin_amdgcn_mfma_f32_16x16x32_bf16(fq, fb, aq[n0], 0, 0, 0);
      ak[n0] = __builtin_amdgcn_mfma_f32_16x16x32_bf16(fk, fb, ak[n0], 0, 0, 0);
      av[n0] = __builtin_amdgcn_mfma_f32_16x16x32_bf16(fv, fb, av[n0], 0, 0, 0);
    }
  }

  const size_t hb = (size_t)(n * NH + ot);
  #pragma unroll
  for (int n0 = 0; n0 < 4; ++n0)
    #pragma unroll
    for (int r = 0; r < 4; ++r)
      Vo[(hb * DH + wave * 16 + quad * 4 + r) * LL + l0 + n0 * 16 + lq] =
          (_Float16)av[n0][r];
  __shared__ short qt_lds[64][72], kt_lds[64][72];
  #pragma unroll
  for (int n0 = 0; n0 < 4; ++n0)
    #pragma unroll
    for (int r = 0; r < 4; ++r) {
      qt_lds[n0 * 16 + lq][wave * 16 + quad * 4 + r] = f2bf(aq[n0][r] * SCALE_Q);
      kt_lds[n0 * 16 + lq][wave * 16 + quad * 4 + r] = f2bf(ak[n0][r]);
    }
  __syncthreads();
  #pragma unroll
  for (int i = 0; i < 2; ++i) {
    const int u = threadIdx.x + i * 256;
    const int row = u >> 3, ch = u & 7;
    *(uint4*)(Qt + (hb * LL + l0 + row) * DH + ch * 8) = *(const uint4*)&qt_lds[row][ch * 8];
    *(uint4*)(Kt + (hb * LL + l0 + row) * DH + ch * 8) = *(const uint4*)&kt_lds[row][ch * 8];
  }
}

// ---------------- MFMA flash attention (round-0 proven body): 64 q/wave ----------------
// grid (LL/256, NH*2, NB) = 512 blocks, block 256 (4 waves).
// Reg-staged K/V prefetch (issue-early/write-late hides HBM latency across the
// compute phase), ones-MFMA l-sum. 2 waves/SIMD — measured best (74.4 us);
// all diet/occupancy variants (rounds 1-6) measured worse.
__global__ __launch_bounds__(256, 2) void attn_mfma_kernel(
    const short* __restrict__ Qt, const short* __restrict__ Kt,
    const _Float16* __restrict__ Vb, _Float16* __restrict__ Opart,
    float* __restrict__ lpart) {
  __shared__ __align__(16) short    k_lds[2][64 * 64];   // 8 KB each, swizzled
  __shared__ __align__(16) _Float16 v_lds[2][64 * 64];   // 8 KB each, swizzled+permuted

  const int t = threadIdx.x;
  const int wave = t >> 6, lane = t & 63;
  const int lq = lane & 15, quad = lane >> 4;
  const int l0 = blockIdx.x * 256;
  const int h = blockIdx.y >> 1, split = blockIdx.y & 1;
  const int n = blockIdx.z;
  const int kbase = split * 2048;
  const int R = n * NH + h;
  const size_t hb = (size_t)R * (size_t)LL * DH;
  const short* const Kp = Kt + hb;      // [key][d] bf16
  const _Float16* const Vp = Vb + hb;   // [d][key] f16

  // Q B-frags: B[n=q][k=d] — wave's 64 q rows
  const int qbase = l0 + wave * 64;
  bf16x8 qb[4][2];
  #pragma unroll
  for (int qf = 0; qf < 4; ++qf)
    #pragma unroll
    for (int c = 0; c < 2; ++c)
      qb[qf][c] = *(const bf16x8*)(Qt + hb + (size_t)(qbase + qf * 16 + lq) * DH + c * 32 + quad * 8);

  const f32x4 z = {0.f, 0.f, 0.f, 0.f};
  f32x4 o[4][4] = {{z, z, z, z}, {z, z, z, z}, {z, z, z, z}, {z, z, z, z}};
  f32x4 ol[4] = {z, z, z, z};

  f16x8 ones8;
  #pragma unroll
  for (int i = 0; i < 8; ++i) ones8[i] = (_Float16)1.0f;

  const int srow = t >> 3, sch = t & 7;   // staging: rows 0..31(+32), chunk 0..7
  const int vgo = 32 * (sch >> 2) + 4 * (sch & 3);  // permuted key offset (lo half)

  // stage tile 0
  {
    *(uint4*)&k_lds[0][sw(srow, sch)]      = *(const uint4*)(Kp + (size_t)(kbase + srow) * DH + sch * 8);
    *(uint4*)&k_lds[0][sw(32 + srow, sch)] = *(const uint4*)(Kp + (size_t)(kbase + 32 + srow) * DH + sch * 8);
    const _Float16* vg0 = Vp + (size_t)srow * LL + kbase + vgo;
    const _Float16* vg1 = Vp + (size_t)(32 + srow) * LL + kbase + vgo;
    uint2 a = *(const uint2*)vg0, b = *(const uint2*)(vg0 + 16);
    *(uint4*)&v_lds[0][sw(srow, sch)] = make_uint4(a.x, a.y, b.x, b.y);
    a = *(const uint2*)vg1; b = *(const uint2*)(vg1 + 16);
    *(uint4*)&v_lds[0][sw(32 + srow, sch)] = make_uint4(a.x, a.y, b.x, b.y);
  }
  __syncthreads();

  for (int kt = 0; kt < 32; ++kt) {
    const int cur = kt & 1;
    // prefetch next tile into regs
    uint4 kpre[2]; uint2 vpre[4];
    if (kt < 31) {
      const int kpos = kbase + (kt + 1) * 64;
      kpre[0] = *(const uint4*)(Kp + (size_t)(kpos + srow) * DH + sch * 8);
      kpre[1] = *(const uint4*)(Kp + (size_t)(kpos + 32 + srow) * DH + sch * 8);
      const _Float16* vg0 = Vp + (size_t)srow * LL + kpos + vgo;
      const _Float16* vg1 = Vp + (size_t)(32 + srow) * LL + kpos + vgo;
      vpre[0] = *(const uint2*)vg0;
      vpre[1] = *(const uint2*)(vg0 + 16);
      vpre[2] = *(const uint2*)vg1;
      vpre[3] = *(const uint2*)(vg1 + 16);
    }
    const short* kb = k_lds[cur];
    const _Float16* vbuf = v_lds[cur];

    // ---- S^T = K·Q^T (bf16), p = exp2(s) -> f16 pack directly into A-frags ----
    union PU { f16x4 h4[2]; f16x8 h8; } af[2][4];
    #pragma unroll
    for (int mf = 0; mf < 4; ++mf) {
      const bf16x8 ka0 = *(const bf16x8*)&kb[sw(mf * 16 + lq, quad)];
      const bf16x8 ka1 = *(const bf16x8*)&kb[sw(mf * 16 + lq, 4 + quad)];
      #pragma unroll
      for (int qf = 0; qf < 4; ++qf) {
        f32x4 zz = {0.f, 0.f, 0.f, 0.f};
        zz = __builtin_amdgcn_mfma_f32_16x16x32_bf16(ka0, qb[qf][0], zz, 0, 0, 0);
        zz = __builtin_amdgcn_mfma_f32_16x16x32_bf16(ka1, qb[qf][1], zz, 0, 0, 0);
        union { h16x2 h2[2]; f16x4 h4; } u;
        u.h2[0] = __builtin_amdgcn_cvt_pkrtz(__builtin_amdgcn_exp2f(zz[0]),
                                             __builtin_amdgcn_exp2f(zz[1]));
        u.h2[1] = __builtin_amdgcn_cvt_pkrtz(__builtin_amdgcn_exp2f(zz[2]),
                                             __builtin_amdgcn_exp2f(zz[3]));
        af[mf >> 1][qf].h4[mf & 1] = u.h4;
      }
    }

    // ---- l-sum via ones-MFMA: D rows == o rows, in-lane ----
    #pragma unroll
    for (int qf = 0; qf < 4; ++qf) {
      ol[qf] = __builtin_amdgcn_mfma_f32_16x16x32_f16(af[0][qf].h8, ones8, ol[qf], 0, 0, 0);
      ol[qf] = __builtin_amdgcn_mfma_f32_16x16x32_f16(af[1][qf].h8, ones8, ol[qf], 0, 0, 0);
    }

    // ---- O += P·V: b128 V-frags, 0-conflict pattern ----
    #pragma unroll
    for (int df = 0; df < 4; ++df)
      #pragma unroll
      for (int cc = 0; cc < 2; ++cc) {
        const f16x8 vb8 = *(const f16x8*)&vbuf[sw(df * 16 + lq, cc * 4 + quad)];
        #pragma unroll
        for (int qf = 0; qf < 4; ++qf)
          o[qf][df] = __builtin_amdgcn_mfma_f32_16x16x32_f16(af[cc][qf].h8, vb8, o[qf][df], 0, 0, 0);
      }

    // ---- write prefetched tile to other buffer ----
    if (kt < 31) {
      const int nxt = 1 - cur;
      *(uint4*)&k_lds[nxt][sw(srow, sch)]      = kpre[0];
      *(uint4*)&k_lds[nxt][sw(32 + srow, sch)] = kpre[1];
      *(uint4*)&v_lds[nxt][sw(srow, sch)]      = make_uint4(vpre[0].x, vpre[0].y, vpre[1].x, vpre[1].y);
      *(uint4*)&v_lds[nxt][sw(32 + srow, sch)] = make_uint4(vpre[2].x, vpre[2].y, vpre[3].x, vpre[3].y);
      __syncthreads();
    }
  }

  // ---- epilogue: store partial l (rows match in-lane) + raw fp16 partial O ----
  const size_t pb = ((size_t)split * 16 + R) * (size_t)LL * DH;
  #pragma unroll
  for (int qf = 0; qf < 4; ++qf) {
    if (lq == 0) {
      #pragma unroll
      for (int r = 0; r < 4; ++r)
        lpart[((size_t)split * 16 + R) * LL + qbase + qf * 16 + quad * 4 + r] = ol[qf][r];
    }
    #pragma unroll
    for (int df = 0; df < 4; ++df)
      #pragma unroll
      for (int r = 0; r < 4; ++r) {
        const int q = qbase + qf * 16 + quad * 4 + r;
        Opart[pb + (size_t)q * DH + df * 16 + lq] = (_Float16)o[qf][df][r];
      }
  }
}

// ---------------- output projection (f16 MFMA, fused normalize, 2 o-tiles) ----------------
__global__ __launch_bounds__(256) void proj_gemm(
    const _Float16* __restrict__ Opart, const float* __restrict__ lpart,
    const _Float16* __restrict__ Wpf, const float* __restrict__ bp,
    float* __restrict__ out) {
  const int lt = blockIdx.x, ot2 = blockIdx.y;   // ot2 covers 128 output channels
  const int n = lt >> 6, l0 = (lt & 63) << 6;
  const int wave = threadIdx.x >> 6, lane = threadIdx.x & 63;
  const int lq = lane & 15, quad = lane >> 4;

  const _Float16* wpp0 = Wpf + (ot2 * 128 + wave * 16 + lq) * CC + quad * 8;
  const _Float16* wpp1 = wpp0 + 64 * CC;

  // per-(n0,h) 1/l as f16 (l = lpart split0 + split1)
  _Float16 invl[4][4];
  #pragma unroll
  for (int n0 = 0; n0 < 4; ++n0) {
    const int q = l0 + n0 * 16 + lq;
    #pragma unroll
    for (int h = 0; h < 4; ++h) {
      const size_t rr = (size_t)(n * NH + h) * LL + q;
      invl[n0][h] = (_Float16)(1.0f / (lpart[rr] + lpart[rr + 16 * (size_t)LL]));
    }
  }

  const f32x4 z = {0.f, 0.f, 0.f, 0.f};
  f32x4 acc[2][4] = {{z, z, z, z}, {z, z, z, z}};
  #pragma unroll
  for (int c0 = 0; c0 < 256; c0 += 32) {
    const int h = c0 >> 6;
    const int d0 = (c0 & 63) + quad * 8;
    const f16x8 fa0 = *(const f16x8*)(wpp0 + c0);
    const f16x8 fa1 = *(const f16x8*)(wpp1 + c0);
    #pragma unroll
    for (int n0 = 0; n0 < 4; ++n0) {
      const int q = l0 + n0 * 16 + lq;
      const size_t e = ((size_t)(n * NH + h) * LL + q) * DH + d0;
      const f16x8 b0 = *(const f16x8*)(Opart + e);
      const f16x8 b1 = *(const f16x8*)(Opart + e + (size_t)PSPLIT);
      f16x8 sc8;
      #pragma unroll
      for (int i = 0; i < 8; ++i) sc8[i] = invl[n0][h];
      const f16x8 fb = (b0 + b1) * sc8;
      acc[0][n0] = __builtin_amdgcn_mfma_f32_16x16x32_f16(fa0, fb, acc[0][n0], 0, 0, 0);
      acc[1][n0] = __builtin_amdgcn_mfma_f32_16x16x32_f16(fa1, fb, acc[1][n0], 0, 0, 0);
    }
  }
  #pragma unroll
  for (int w = 0; w < 2; ++w)
    #pragma unroll
    for (int r = 0; r < 4; ++r) {
      const int oo = ot2 * 128 + w * 64 + wave * 16 + quad * 4 + r;
      const float bias = bp[oo];
      #pragma unroll
      for (int n0 = 0; n0 < 4; ++n0)
        out[((size_t)n * CC + oo) * LL + l0 + n0 * 16 + lq] = acc[w][n0][r] + bias;
    }
}

extern "C" void kernel_launch(void* const* d_in, const int* in_sizes, int n_in,
                              void* d_out, int out_size, void* d_ws, size_t ws_size,
                              hipStream_t stream) {
  const float* x     = (const float*)d_in[0];
  const float* gamma = (const float*)d_in[1];
  const float* beta  = (const float*)d_in[2];
  const float* Wq    = (const float*)d_in[3];
  const float* Wk    = (const float*)d_in[4];
  const float* Wv    = (const float*)d_in[5];
  const float* Wp    = (const float*)d_in[6];
  const float* bp    = (const float*)d_in[7];
  float* out = (float*)d_out;

  const size_t S = (size_t)NB * CC * LL;  // 4,194,304
  short*     xnT = (short*)d_ws;          // bf16 [n][l][c]
  short*     Qt  = xnT + S;               // bf16 [n,h][l][d]
  short*     Kt  = Qt + S;
  _Float16*  Vo  = (_Float16*)(Kt + S);   // f16 [n,h][d][l]
  short*     Wb  = (short*)(Vo + S);      // 4 x 65536 (bf16 x3, f16 x1)
  _Float16*  Opart = (_Float16*)(Wb + 4 * 65536);  // 2 x 8 MB fp16
  float*     lpart = (float*)(Opart + 2 * (size_t)PSPLIT); // 2 x 256 KB fp32
  float*     pstat = lpart + 2 * 16 * (size_t)LL;  // 1024 floats GN partials

  gn_stats   <<<512,                  256, 0, stream>>>(x, pstat);
  gn_apply   <<<512,                  256, 0, stream>>>(x, gamma, beta, pstat, xnT);
  wcvt_kernel<<<128,                  256, 0, stream>>>(Wq, Wk, Wv, Wp, Wb);
  qkv_gemm   <<<dim3(256, 4),         256, 0, stream>>>(xnT, Wb, Wb + 65536, Wb + 131072, Qt, Kt, Vo);
  attn_mfma_kernel<<<dim3(LL/256, NH*2, NB), 256, 0, stream>>>(Qt, Kt, Vo, Opart, lpart);
  proj_gemm  <<<dim3(256, 2),         256, 0, stream>>>(Opart, lpart,
                 (const _Float16*)(Wb + 196608), bp, out);
}

// Round 8
// 185.431 us; speedup vs baseline: 2.0247x; 1.1077x over previous
//
#include <hip/hip_runtime.h>
#include <cstddef>
#include <cstdint>

#define NB 4
#define CC 256
#define LL 4096
#define NG 32
#define CPG 8
#define NH 4
#define DH 64
#define PSPLIT 4194304   // fp16 partial-O elements per split: 16*4096*64

static constexpr float EPSV  = 1e-5f;
static constexpr float SCALE_Q = 0.125f * 1.4426950408889634f; // dh^-0.5 * log2(e)

typedef __attribute__((ext_vector_type(8))) short bf16x8;
typedef __attribute__((ext_vector_type(4))) float f32x4;
typedef _Float16 f16x8 __attribute__((ext_vector_type(8)));
typedef _Float16 f16x4 __attribute__((ext_vector_type(4)));
typedef __fp16  h16x2 __attribute__((ext_vector_type(2)));   // cvt_pkrtz native type

__device__ __forceinline__ short f2bf(float f) {
  unsigned u = __float_as_uint(f);
  unsigned r = (u + 0x7fffu + ((u >> 16) & 1u)) >> 16;
  return (short)r;
}
__device__ __forceinline__ short f2h(float f) {
  union { _Float16 h; short s; } u;
  u.h = (_Float16)f;
  return u.s;
}
// element offset of 16B chunk (8 elems) with XOR swizzle: row stride 64 elems
__device__ __forceinline__ int sw(int row, int chunk) {
  return row * 64 + ((chunk ^ (row & 7)) * 8);
}

// ---------------- fused GroupNorm stats (512 blocks) + weight cvt (128 blocks) ----------------
// stats: each block reduces 8 ch x 1024 l = 32KB -> 2 partial floats.
// wcvt: fp32 -> bf16 (Wq/Wk/Wv) or f16 (Wp), independent work overlapped.
__global__ __launch_bounds__(256) void gnstats_wcvt(
    const float* __restrict__ x, float* __restrict__ pstat,
    const float* __restrict__ Wq, const float* __restrict__ Wk,
    const float* __restrict__ Wv, const float* __restrict__ Wp,
    short* __restrict__ wdst) {
  __shared__ float r1[4], r2[4];
  const int blk = blockIdx.x;
  if (blk < 512) {
    const int grp = blk >> 2, qtr = blk & 3;          // grp = n*32+g
    const float* xp = x + (size_t)grp * CPG * LL + qtr * 1024 + threadIdx.x * 4;
    float s = 0.f, ss = 0.f;
    #pragma unroll
    for (int cc = 0; cc < 8; ++cc) {
      const float4 v = *(const float4*)(xp + (size_t)cc * LL);
      s  += v.x + v.y + v.z + v.w;
      ss += v.x * v.x + v.y * v.y + v.z * v.z + v.w * v.w;
    }
    #pragma unroll
    for (int off = 32; off; off >>= 1) {
      s  += __shfl_down(s, off);
      ss += __shfl_down(ss, off);
    }
    const int wid = threadIdx.x >> 6, lane = threadIdx.x & 63;
    if (lane == 0) { r1[wid] = s; r2[wid] = ss; }
    __syncthreads();
    if (threadIdx.x == 0) {
      float S = 0.f, SS = 0.f;
      #pragma unroll
      for (int w = 0; w < 4; ++w) { S += r1[w]; SS += r2[w]; }
      pstat[blk * 2]     = S;
      pstat[blk * 2 + 1] = SS;
    }
  } else {
    const int wblk = blk - 512;
    const int which = wblk >> 5;
    const float* src = (which == 0) ? Wq : (which == 1) ? Wk : (which == 2) ? Wv : Wp;
    const int base = (wblk & 31) * 2048 + threadIdx.x * 8;
    const float4 v0 = *(const float4*)(src + base);
    const float4 v1 = *(const float4*)(src + base + 4);
    short ob[8] __attribute__((aligned(16)));
    if (which < 3) {
      ob[0] = f2bf(v0.x); ob[1] = f2bf(v0.y); ob[2] = f2bf(v0.z); ob[3] = f2bf(v0.w);
      ob[4] = f2bf(v1.x); ob[5] = f2bf(v1.y); ob[6] = f2bf(v1.z); ob[7] = f2bf(v1.w);
    } else {
      ob[0] = f2h(v0.x); ob[1] = f2h(v0.y); ob[2] = f2h(v0.z); ob[3] = f2h(v0.w);
      ob[4] = f2h(v1.x); ob[5] = f2h(v1.y); ob[6] = f2h(v1.z); ob[7] = f2h(v1.w);
    }
    *(uint4*)(wdst + which * 65536 + base) = *(const uint4*)ob;
  }
}

// ---------------- QKV MFMA GEMM with fused GroupNorm staging ----------------
// Each block stages its 64l x 256c x-tile: load fp32 (coalesced along l), apply
// per-group affine from pstat (group == c-chunk), convert bf16, write transposed
// [l][c] into LDS (pad 264 -> ~2-way read conflicts). K-loop reads fb frags from
// LDS. No xnT in HBM at all. LDS reused for Qt/Kt repack after the K-loop.
// Qt/Kt bf16 [n,h][l][d] (Q scaled by log2e/8). Vo f16 [n,h][d][l].
__global__ __launch_bounds__(256) void qkv_gemm(
    const float* __restrict__ x, const float* __restrict__ gamma,
    const float* __restrict__ beta, const float* __restrict__ pstat,
    const short* __restrict__ Wqb, const short* __restrict__ Wkb,
    const short* __restrict__ Wvb,
    short* __restrict__ Qt, short* __restrict__ Kt, _Float16* __restrict__ Vo) {
  __shared__ __align__(16) short smem[64 * 264];   // 33792 B; xn tile, later qt/kt
  const int lt = blockIdx.x, ot = blockIdx.y;
  const int n = lt >> 6, l0 = (lt & 63) << 6;
  const int wave = threadIdx.x >> 6, lane = threadIdx.x & 63;
  const int lq = lane & 15, quad = lane >> 4;

  // ---- stage: normalize + bf16 + transpose into LDS ----
  #pragma unroll
  for (int i = 0; i < 2; ++i) {
    const int u = threadIdx.x + i * 256;
    const int cc = u >> 4, l4 = u & 15;              // cc = c-chunk == group
    const int grp = n * NG + cc;
    float S = 0.f, SS = 0.f;
    #pragma unroll
    for (int w = 0; w < 4; ++w) {
      S  += pstat[(grp * 4 + w) * 2];
      SS += pstat[(grp * 4 + w) * 2 + 1];
    }
    const float mean = S / 32768.f;                  // NE = 8*4096
    const float rstd = rsqrtf(SS / 32768.f - mean * mean + EPSV);
    const float* xp = x + (size_t)(n * CC + cc * CPG) * LL + l0 + l4 * 4;
    short ob[4][8] __attribute__((aligned(16)));
    #pragma unroll
    for (int j = 0; j < 8; ++j) {
      const float scl = rstd * gamma[cc * CPG + j];
      const float shf = beta[cc * CPG + j] - mean * scl;
      const float4 v = *(const float4*)(xp + (size_t)j * LL);
      ob[0][j] = f2bf(v.x * scl + shf);
      ob[1][j] = f2bf(v.y * scl + shf);
      ob[2][j] = f2bf(v.z * scl + shf);
      ob[3][j] = f2bf(v.w * scl + shf);
    }
    short* dst = smem + (l4 * 4) * 264 + cc * 8;
    #pragma unroll
    for (int jj = 0; jj < 4; ++jj)
      *(uint4*)(dst + jj * 264) = *(const uint4*)ob[jj];
  }
  __syncthreads();

  // ---- MFMA K-loop: weights from global, fb frags from LDS ----
  const int orow = ot * 64 + wave * 16 + lq;
  const short* wqp = Wqb + orow * CC + quad * 8;
  const short* wkp = Wkb + orow * CC + quad * 8;
  const short* wvp = Wvb + orow * CC + quad * 8;
  const short* xl  = smem + lq * 264 + quad * 8;

  const f32x4 z = {0.f, 0.f, 0.f, 0.f};
  f32x4 aq[4] = {z, z, z, z}, ak[4] = {z, z, z, z}, av[4] = {z, z, z, z};

  #pragma unroll
  for (int c0 = 0; c0 < 256; c0 += 32) {
    const bf16x8 fq = *(const bf16x8*)(wqp + c0);
    const bf16x8 fk = *(const bf16x8*)(wkp + c0);
    const bf16x8 fv = *(const bf16x8*)(wvp + c0);
    #pragma unroll
    for (int n0 = 0; n0 < 4; ++n0) {
      const bf16x8 fb = *(const bf16x8*)(xl + (n0 * 16) * 264 + c0);
      aq[n0] = __builtin_amdgcn_mfma_f32_16x16x32_bf16(fq, fb, aq[n0], 0, 0, 0);
      ak[n0] = __builtin_amdgcn_mfma_f32_16x16x32_bf16(fk, fb, ak[n0], 0, 0, 0);
      av[n0] = __builtin_amdgcn_mfma_f32_16x16x32_bf16(fv, fb, av[n0], 0, 0, 0);
    }
  }

  const size_t hb = (size_t)(n * NH + ot);
  #pragma unroll
  for (int n0 = 0; n0 < 4; ++n0)
    #pragma unroll
    for (int r = 0; r < 4; ++r)
      Vo[(hb * DH + wave * 16 + quad * 4 + r) * LL + l0 + n0 * 16 + lq] =
          (_Float16)av[n0][r];

  // ---- reuse LDS for Qt/Kt repack ----
  __syncthreads();                                   // all xn reads done
  short* qt_l = smem;                                // [64][72]
  short* kt_l = smem + 64 * 72;                      // [64][72]
  #pragma unroll
  for (int n0 = 0; n0 < 4; ++n0)
    #pragma unroll
    for (int r = 0; r < 4; ++r) {
      qt_l[(n0 * 16 + lq) * 72 + wave * 16 + quad * 4 + r] = f2bf(aq[n0][r] * SCALE_Q);
      kt_l[(n0 * 16 + lq) * 72 + wave * 16 + quad * 4 + r] = f2bf(ak[n0][r]);
    }
  __syncthreads();
  #pragma unroll
  for (int i = 0; i < 2; ++i) {
    const int u = threadIdx.x + i * 256;
    const int row = u >> 3, ch = u & 7;
    *(uint4*)(Qt + (hb * LL + l0 + row) * DH + ch * 8) = *(const uint4*)&qt_l[row * 72 + ch * 8];
    *(uint4*)(Kt + (hb * LL + l0 + row) * DH + ch * 8) = *(const uint4*)&kt_l[row * 72 + ch * 8];
  }
}

// ---------------- MFMA flash attention (round-0 proven body): 64 q/wave ----------------
// grid (LL/256, NH*2, NB) = 512 blocks, block 256 (4 waves).
// Reg-staged K/V prefetch, ones-MFMA l-sum, 2 waves/SIMD — measured best (74.4 us).
__global__ __launch_bounds__(256, 2) void attn_mfma_kernel(
    const short* __restrict__ Qt, const short* __restrict__ Kt,
    const _Float16* __restrict__ Vb, _Float16* __restrict__ Opart,
    float* __restrict__ lpart) {
  __shared__ __align__(16) short    k_lds[2][64 * 64];   // 8 KB each, swizzled
  __shared__ __align__(16) _Float16 v_lds[2][64 * 64];   // 8 KB each, swizzled+permuted

  const int t = threadIdx.x;
  const int wave = t >> 6, lane = t & 63;
  const int lq = lane & 15, quad = lane >> 4;
  const int l0 = blockIdx.x * 256;
  const int h = blockIdx.y >> 1, split = blockIdx.y & 1;
  const int n = blockIdx.z;
  const int kbase = split * 2048;
  const int R = n * NH + h;
  const size_t hb = (size_t)R * (size_t)LL * DH;
  const short* const Kp = Kt + hb;      // [key][d] bf16
  const _Float16* const Vp = Vb + hb;   // [d][key] f16

  // Q B-frags: B[n=q][k=d] — wave's 64 q rows
  const int qbase = l0 + wave * 64;
  bf16x8 qb[4][2];
  #pragma unroll
  for (int qf = 0; qf < 4; ++qf)
    #pragma unroll
    for (int c = 0; c < 2; ++c)
      qb[qf][c] = *(const bf16x8*)(Qt + hb + (size_t)(qbase + qf * 16 + lq) * DH + c * 32 + quad * 8);

  const f32x4 z = {0.f, 0.f, 0.f, 0.f};
  f32x4 o[4][4] = {{z, z, z, z}, {z, z, z, z}, {z, z, z, z}, {z, z, z, z}};
  f32x4 ol[4] = {z, z, z, z};

  f16x8 ones8;
  #pragma unroll
  for (int i = 0; i < 8; ++i) ones8[i] = (_Float16)1.0f;

  const int srow = t >> 3, sch = t & 7;   // staging: rows 0..31(+32), chunk 0..7
  const int vgo = 32 * (sch >> 2) + 4 * (sch & 3);  // permuted key offset (lo half)

  // stage tile 0
  {
    *(uint4*)&k_lds[0][sw(srow, sch)]      = *(const uint4*)(Kp + (size_t)(kbase + srow) * DH + sch * 8);
    *(uint4*)&k_lds[0][sw(32 + srow, sch)] = *(const uint4*)(Kp + (size_t)(kbase + 32 + srow) * DH + sch * 8);
    const _Float16* vg0 = Vp + (size_t)srow * LL + kbase + vgo;
    const _Float16* vg1 = Vp + (size_t)(32 + srow) * LL + kbase + vgo;
    uint2 a = *(const uint2*)vg0, b = *(const uint2*)(vg0 + 16);
    *(uint4*)&v_lds[0][sw(srow, sch)] = make_uint4(a.x, a.y, b.x, b.y);
    a = *(const uint2*)vg1; b = *(const uint2*)(vg1 + 16);
    *(uint4*)&v_lds[0][sw(32 + srow, sch)] = make_uint4(a.x, a.y, b.x, b.y);
  }
  __syncthreads();

  for (int kt = 0; kt < 32; ++kt) {
    const int cur = kt & 1;
    // prefetch next tile into regs
    uint4 kpre[2]; uint2 vpre[4];
    if (kt < 31) {
      const int kpos = kbase + (kt + 1) * 64;
      kpre[0] = *(const uint4*)(Kp + (size_t)(kpos + srow) * DH + sch * 8);
      kpre[1] = *(const uint4*)(Kp + (size_t)(kpos + 32 + srow) * DH + sch * 8);
      const _Float16* vg0 = Vp + (size_t)srow * LL + kpos + vgo;
      const _Float16* vg1 = Vp + (size_t)(32 + srow) * LL + kpos + vgo;
      vpre[0] = *(const uint2*)vg0;
      vpre[1] = *(const uint2*)(vg0 + 16);
      vpre[2] = *(const uint2*)vg1;
      vpre[3] = *(const uint2*)(vg1 + 16);
    }
    const short* kb = k_lds[cur];
    const _Float16* vbuf = v_lds[cur];

    // ---- S^T = K·Q^T (bf16), p = exp2(s) -> f16 pack directly into A-frags ----
    union PU { f16x4 h4[2]; f16x8 h8; } af[2][4];
    #pragma unroll
    for (int mf = 0; mf < 4; ++mf) {
      const bf16x8 ka0 = *(const bf16x8*)&kb[sw(mf * 16 + lq, quad)];
      const bf16x8 ka1 = *(const bf16x8*)&kb[sw(mf * 16 + lq, 4 + quad)];
      #pragma unroll
      for (int qf = 0; qf < 4; ++qf) {
        f32x4 zz = {0.f, 0.f, 0.f, 0.f};
        zz = __builtin_amdgcn_mfma_f32_16x16x32_bf16(ka0, qb[qf][0], zz, 0, 0, 0);
        zz = __builtin_amdgcn_mfma_f32_16x16x32_bf16(ka1, qb[qf][1], zz, 0, 0, 0);
        union { h16x2 h2[2]; f16x4 h4; } u;
        u.h2[0] = __builtin_amdgcn_cvt_pkrtz(__builtin_amdgcn_exp2f(zz[0]),
                                             __builtin_amdgcn_exp2f(zz[1]));
        u.h2[1] = __builtin_amdgcn_cvt_pkrtz(__builtin_amdgcn_exp2f(zz[2]),
                                             __builtin_amdgcn_exp2f(zz[3]));
        af[mf >> 1][qf].h4[mf & 1] = u.h4;
      }
    }

    // ---- l-sum via ones-MFMA: D rows == o rows, in-lane ----
    #pragma unroll
    for (int qf = 0; qf < 4; ++qf) {
      ol[qf] = __builtin_amdgcn_mfma_f32_16x16x32_f16(af[0][qf].h8, ones8, ol[qf], 0, 0, 0);
      ol[qf] = __builtin_amdgcn_mfma_f32_16x16x32_f16(af[1][qf].h8, ones8, ol[qf], 0, 0, 0);
    }

    // ---- O += P·V: b128 V-frags, 0-conflict pattern ----
    #pragma unroll
    for (int df = 0; df < 4; ++df)
      #pragma unroll
      for (int cc = 0; cc < 2; ++cc) {
        const f16x8 vb8 = *(const f16x8*)&vbuf[sw(df * 16 + lq, cc * 4 + quad)];
        #pragma unroll
        for (int qf = 0; qf < 4; ++qf)
          o[qf][df] = __builtin_amdgcn_mfma_f32_16x16x32_f16(af[cc][qf].h8, vb8, o[qf][df], 0, 0, 0);
      }

    // ---- write prefetched tile to other buffer ----
    if (kt < 31) {
      const int nxt = 1 - cur;
      *(uint4*)&k_lds[nxt][sw(srow, sch)]      = kpre[0];
      *(uint4*)&k_lds[nxt][sw(32 + srow, sch)] = kpre[1];
      *(uint4*)&v_lds[nxt][sw(srow, sch)]      = make_uint4(vpre[0].x, vpre[0].y, vpre[1].x, vpre[1].y);
      *(uint4*)&v_lds[nxt][sw(32 + srow, sch)] = make_uint4(vpre[2].x, vpre[2].y, vpre[3].x, vpre[3].y);
      __syncthreads();
    }
  }

  // ---- epilogue: store partial l (rows match in-lane) + raw fp16 partial O ----
  const size_t pb = ((size_t)split * 16 + R) * (size_t)LL * DH;
  #pragma unroll
  for (int qf = 0; qf < 4; ++qf) {
    if (lq == 0) {
      #pragma unroll
      for (int r = 0; r < 4; ++r)
        lpart[((size_t)split * 16 + R) * LL + qbase + qf * 16 + quad * 4 + r] = ol[qf][r];
    }
    #pragma unroll
    for (int df = 0; df < 4; ++df)
      #pragma unroll
      for (int r = 0; r < 4; ++r) {
        const int q = qbase + qf * 16 + quad * 4 + r;
        Opart[pb + (size_t)q * DH + df * 16 + lq] = (_Float16)o[qf][df][r];
      }
  }
}

// ---------------- output projection (f16 MFMA, fused normalize, 2 o-tiles) ----------------
__global__ __launch_bounds__(256) void proj_gemm(
    const _Float16* __restrict__ Opart, const float* __restrict__ lpart,
    const _Float16* __restrict__ Wpf, const float* __restrict__ bp,
    float* __restrict__ out) {
  const int lt = blockIdx.x, ot2 = blockIdx.y;   // ot2 covers 128 output channels
  const int n = lt >> 6, l0 = (lt & 63) << 6;
  const int wave = threadIdx.x >> 6, lane = threadIdx.x & 63;
  const int lq = lane & 15, quad = lane >> 4;

  const _Float16* wpp0 = Wpf + (ot2 * 128 + wave * 16 + lq) * CC + quad * 8;
  const _Float16* wpp1 = wpp0 + 64 * CC;

  // per-(n0,h) 1/l as f16 (l = lpart split0 + split1)
  _Float16 invl[4][4];
  #pragma unroll
  for (int n0 = 0; n0 < 4; ++n0) {
    const int q = l0 + n0 * 16 + lq;
    #pragma unroll
    for (int h = 0; h < 4; ++h) {
      const size_t rr = (size_t)(n * NH + h) * LL + q;
      invl[n0][h] = (_Float16)(1.0f / (lpart[rr] + lpart[rr + 16 * (size_t)LL]));
    }
  }

  const f32x4 z = {0.f, 0.f, 0.f, 0.f};
  f32x4 acc[2][4] = {{z, z, z, z}, {z, z, z, z}};
  #pragma unroll
  for (int c0 = 0; c0 < 256; c0 += 32) {
    const int h = c0 >> 6;
    const int d0 = (c0 & 63) + quad * 8;
    const f16x8 fa0 = *(const f16x8*)(wpp0 + c0);
    const f16x8 fa1 = *(const f16x8*)(wpp1 + c0);
    #pragma unroll
    for (int n0 = 0; n0 < 4; ++n0) {
      const int q = l0 + n0 * 16 + lq;
      const size_t e = ((size_t)(n * NH + h) * LL + q) * DH + d0;
      const f16x8 b0 = *(const f16x8*)(Opart + e);
      const f16x8 b1 = *(const f16x8*)(Opart + e + (size_t)PSPLIT);
      f16x8 sc8;
      #pragma unroll
      for (int i = 0; i < 8; ++i) sc8[i] = invl[n0][h];
      const f16x8 fb = (b0 + b1) * sc8;
      acc[0][n0] = __builtin_amdgcn_mfma_f32_16x16x32_f16(fa0, fb, acc[0][n0], 0, 0, 0);
      acc[1][n0] = __builtin_amdgcn_mfma_f32_16x16x32_f16(fa1, fb, acc[1][n0], 0, 0, 0);
    }
  }
  #pragma unroll
  for (int w = 0; w < 2; ++w)
    #pragma unroll
    for (int r = 0; r < 4; ++r) {
      const int oo = ot2 * 128 + w * 64 + wave * 16 + quad * 4 + r;
      const float bias = bp[oo];
      #pragma unroll
      for (int n0 = 0; n0 < 4; ++n0)
        out[((size_t)n * CC + oo) * LL + l0 + n0 * 16 + lq] = acc[w][n0][r] + bias;
    }
}

extern "C" void kernel_launch(void* const* d_in, const int* in_sizes, int n_in,
                              void* d_out, int out_size, void* d_ws, size_t ws_size,
                              hipStream_t stream) {
  const float* x     = (const float*)d_in[0];
  const float* gamma = (const float*)d_in[1];
  const float* beta  = (const float*)d_in[2];
  const float* Wq    = (const float*)d_in[3];
  const float* Wk    = (const float*)d_in[4];
  const float* Wv    = (const float*)d_in[5];
  const float* Wp    = (const float*)d_in[6];
  const float* bp    = (const float*)d_in[7];
  float* out = (float*)d_out;

  const size_t S = (size_t)NB * CC * LL;  // 4,194,304
  short*     Qt  = (short*)d_ws;          // bf16 [n,h][l][d]
  short*     Kt  = Qt + S;
  _Float16*  Vo  = (_Float16*)(Kt + S);   // f16 [n,h][d][l]
  short*     Wb  = (short*)(Vo + S);      // 4 x 65536 (bf16 x3, f16 x1)
  _Float16*  Opart = (_Float16*)(Wb + 4 * 65536);  // 2 x 8 MB fp16
  float*     lpart = (float*)(Opart + 2 * (size_t)PSPLIT); // 2 x 256 KB fp32
  float*     pstat = lpart + 2 * 16 * (size_t)LL;  // 1024 floats GN partials

  gnstats_wcvt<<<640,                 256, 0, stream>>>(x, pstat, Wq, Wk, Wv, Wp, Wb);
  qkv_gemm   <<<dim3(256, 4),         256, 0, stream>>>(x, gamma, beta, pstat,
                 Wb, Wb + 65536, Wb + 131072, Qt, Kt, Vo);
  attn_mfma_kernel<<<dim3(LL/256, NH*2, NB), 256, 0, stream>>>(Qt, Kt, Vo, Opart, lpart);
  proj_gemm  <<<dim3(256, 2),         256, 0, stream>>>(Opart, lpart,
                 (const _Float16*)(Wb + 196608), bp, out);
}

// Round 9
// 185.211 us; speedup vs baseline: 2.0270x; 1.0012x over previous
//
#include <hip/hip_runtime.h>
#include <cstddef>
#include <cstdint>

#define NB 4
#define CC 256
#define LL 4096
#define NG 32
#define CPG 8
#define NH 4
#define DH 64
#define PSPLIT 4194304   // fp16 partial-O elements per split: 16*4096*64

static constexpr float EPSV  = 1e-5f;
static constexpr float SCALE_Q = 0.125f * 1.4426950408889634f; // dh^-0.5 * log2(e)

typedef __attribute__((ext_vector_type(8))) short bf16x8;
typedef __attribute__((ext_vector_type(4))) float f32x4;
typedef _Float16 f16x8 __attribute__((ext_vector_type(8)));
typedef _Float16 f16x4 __attribute__((ext_vector_type(4)));
typedef __fp16  h16x2 __attribute__((ext_vector_type(2)));   // cvt_pkrtz native type

__device__ __forceinline__ short f2bf(float f) {
  unsigned u = __float_as_uint(f);
  unsigned r = (u + 0x7fffu + ((u >> 16) & 1u)) >> 16;
  return (short)r;
}
__device__ __forceinline__ short f2h(float f) {
  union { _Float16 h; short s; } u;
  u.h = (_Float16)f;
  return u.s;
}
// element offset of 16B chunk (8 elems) with XOR swizzle: row stride 64 elems
__device__ __forceinline__ int sw(int row, int chunk) {
  return row * 64 + ((chunk ^ (row & 7)) * 8);
}

// ---------------- fused GroupNorm stats (512 blocks) + weight cvt (128 blocks) ----------------
__global__ __launch_bounds__(256) void gnstats_wcvt(
    const float* __restrict__ x, float* __restrict__ pstat,
    const float* __restrict__ Wq, const float* __restrict__ Wk,
    const float* __restrict__ Wv, const float* __restrict__ Wp,
    short* __restrict__ wdst) {
  __shared__ float r1[4], r2[4];
  const int blk = blockIdx.x;
  if (blk < 512) {
    const int grp = blk >> 2, qtr = blk & 3;          // grp = n*32+g
    const float* xp = x + (size_t)grp * CPG * LL + qtr * 1024 + threadIdx.x * 4;
    float s = 0.f, ss = 0.f;
    #pragma unroll
    for (int cc = 0; cc < 8; ++cc) {
      const float4 v = *(const float4*)(xp + (size_t)cc * LL);
      s  += v.x + v.y + v.z + v.w;
      ss += v.x * v.x + v.y * v.y + v.z * v.z + v.w * v.w;
    }
    #pragma unroll
    for (int off = 32; off; off >>= 1) {
      s  += __shfl_down(s, off);
      ss += __shfl_down(ss, off);
    }
    const int wid = threadIdx.x >> 6, lane = threadIdx.x & 63;
    if (lane == 0) { r1[wid] = s; r2[wid] = ss; }
    __syncthreads();
    if (threadIdx.x == 0) {
      float S = 0.f, SS = 0.f;
      #pragma unroll
      for (int w = 0; w < 4; ++w) { S += r1[w]; SS += r2[w]; }
      pstat[blk * 2]     = S;
      pstat[blk * 2 + 1] = SS;
    }
  } else {
    const int wblk = blk - 512;
    const int which = wblk >> 5;
    const float* src = (which == 0) ? Wq : (which == 1) ? Wk : (which == 2) ? Wv : Wp;
    const int base = (wblk & 31) * 2048 + threadIdx.x * 8;
    const float4 v0 = *(const float4*)(src + base);
    const float4 v1 = *(const float4*)(src + base + 4);
    short ob[8] __attribute__((aligned(16)));
    if (which < 3) {
      ob[0] = f2bf(v0.x); ob[1] = f2bf(v0.y); ob[2] = f2bf(v0.z); ob[3] = f2bf(v0.w);
      ob[4] = f2bf(v1.x); ob[5] = f2bf(v1.y); ob[6] = f2bf(v1.z); ob[7] = f2bf(v1.w);
    } else {
      ob[0] = f2h(v0.x); ob[1] = f2h(v0.y); ob[2] = f2h(v0.z); ob[3] = f2h(v0.w);
      ob[4] = f2h(v1.x); ob[5] = f2h(v1.y); ob[6] = f2h(v1.z); ob[7] = f2h(v1.w);
    }
    *(uint4*)(wdst + which * 65536 + base) = *(const uint4*)ob;
  }
}

// ---------------- QKV MFMA GEMM v2: fused GN staging, 128 outputs/block ----------------
// grid (256, 2): each block stages its 64l x 256c x-tile ONCE (normalize from
// pstat, bf16, transpose to LDS) and computes 128 output channels (two 64-chunks)
// -> staging redundancy halved vs grid (256,4). acc = 3x2x4 f32x4 = 96 regs.
// Qt/Kt bf16 [n,h][l][d] (Q scaled by log2e/8). Vo f16 [n,h][d][l].
__global__ __launch_bounds__(256) void qkv_gemm(
    const float* __restrict__ x, const float* __restrict__ gamma,
    const float* __restrict__ beta, const float* __restrict__ pstat,
    const short* __restrict__ Wqb, const short* __restrict__ Wkb,
    const short* __restrict__ Wvb,
    short* __restrict__ Qt, short* __restrict__ Kt, _Float16* __restrict__ Vo) {
  __shared__ __align__(16) short smem[64 * 272];   // 34816 B; xn tile (stride 264), later qt/kt (stride 136)
  const int lt = blockIdx.x, ot2 = blockIdx.y;     // ot2 covers 128 output channels
  const int n = lt >> 6, l0 = (lt & 63) << 6;
  const int wave = threadIdx.x >> 6, lane = threadIdx.x & 63;
  const int lq = lane & 15, quad = lane >> 4;

  // ---- stage: normalize + bf16 + transpose into LDS (once per block) ----
  #pragma unroll
  for (int i = 0; i < 2; ++i) {
    const int u = threadIdx.x + i * 256;
    const int cc = u >> 4, l4 = u & 15;              // cc = c-chunk == group
    const int grp = n * NG + cc;
    float S = 0.f, SS = 0.f;
    #pragma unroll
    for (int w = 0; w < 4; ++w) {
      S  += pstat[(grp * 4 + w) * 2];
      SS += pstat[(grp * 4 + w) * 2 + 1];
    }
    const float mean = S / 32768.f;                  // NE = 8*4096
    const float rstd = rsqrtf(SS / 32768.f - mean * mean + EPSV);
    const float* xp = x + (size_t)(n * CC + cc * CPG) * LL + l0 + l4 * 4;
    short ob[4][8] __attribute__((aligned(16)));
    #pragma unroll
    for (int j = 0; j < 8; ++j) {
      const float scl = rstd * gamma[cc * CPG + j];
      const float shf = beta[cc * CPG + j] - mean * scl;
      const float4 v = *(const float4*)(xp + (size_t)j * LL);
      ob[0][j] = f2bf(v.x * scl + shf);
      ob[1][j] = f2bf(v.y * scl + shf);
      ob[2][j] = f2bf(v.z * scl + shf);
      ob[3][j] = f2bf(v.w * scl + shf);
    }
    short* dst = smem + (l4 * 4) * 264 + cc * 8;
    #pragma unroll
    for (int jj = 0; jj < 4; ++jj)
      *(uint4*)(dst + jj * 264) = *(const uint4*)ob[jj];
  }
  __syncthreads();

  // ---- MFMA K-loop: weights from global (2 output sub-tiles), fb frags from LDS ----
  const int orow = ot2 * 128 + wave * 16 + lq;       // first 64-chunk row
  const short* wqp = Wqb + orow * CC + quad * 8;
  const short* wkp = Wkb + orow * CC + quad * 8;
  const short* wvp = Wvb + orow * CC + quad * 8;
  const short* xl  = smem + lq * 264 + quad * 8;

  const f32x4 z = {0.f, 0.f, 0.f, 0.f};
  f32x4 aq[2][4] = {{z, z, z, z}, {z, z, z, z}};
  f32x4 ak[2][4] = {{z, z, z, z}, {z, z, z, z}};
  f32x4 av[2][4] = {{z, z, z, z}, {z, z, z, z}};

  #pragma unroll
  for (int c0 = 0; c0 < 256; c0 += 32) {
    const bf16x8 fq0 = *(const bf16x8*)(wqp + c0);
    const bf16x8 fq1 = *(const bf16x8*)(wqp + 64 * CC + c0);
    const bf16x8 fk0 = *(const bf16x8*)(wkp + c0);
    const bf16x8 fk1 = *(const bf16x8*)(wkp + 64 * CC + c0);
    const bf16x8 fv0 = *(const bf16x8*)(wvp + c0);
    const bf16x8 fv1 = *(const bf16x8*)(wvp + 64 * CC + c0);
    #pragma unroll
    for (int n0 = 0; n0 < 4; ++n0) {
      const bf16x8 fb = *(const bf16x8*)(xl + (n0 * 16) * 264 + c0);
      aq[0][n0] = __builtin_amdgcn_mfma_f32_16x16x32_bf16(fq0, fb, aq[0][n0], 0, 0, 0);
      aq[1][n0] = __builtin_amdgcn_mfma_f32_16x16x32_bf16(fq1, fb, aq[1][n0], 0, 0, 0);
      ak[0][n0] = __builtin_amdgcn_mfma_f32_16x16x32_bf16(fk0, fb, ak[0][n0], 0, 0, 0);
      ak[1][n0] = __builtin_amdgcn_mfma_f32_16x16x32_bf16(fk1, fb, ak[1][n0], 0, 0, 0);
      av[0][n0] = __builtin_amdgcn_mfma_f32_16x16x32_bf16(fv0, fb, av[0][n0], 0, 0, 0);
      av[1][n0] = __builtin_amdgcn_mfma_f32_16x16x32_bf16(fv1, fb, av[1][n0], 0, 0, 0);
    }
  }

  // ---- V write: channel = ot2*128 + w*64 + wave*16 + quad*4 + r -> (h, d) ----
  #pragma unroll
  for (int w = 0; w < 2; ++w) {
    const size_t hb = (size_t)(n * NH + ot2 * 2 + w);
    #pragma unroll
    for (int n0 = 0; n0 < 4; ++n0)
      #pragma unroll
      for (int r = 0; r < 4; ++r)
        Vo[(hb * DH + wave * 16 + quad * 4 + r) * LL + l0 + n0 * 16 + lq] =
            (_Float16)av[w][n0][r];
  }

  // ---- reuse LDS for Qt/Kt repack: [64 l][136] per tensor (16B-aligned rows) ----
  __syncthreads();                                   // all xn reads done
  short* qt_l = smem;                                // [64][136]
  short* kt_l = smem + 64 * 136;                     // [64][136]
  #pragma unroll
  for (int w = 0; w < 2; ++w)
    #pragma unroll
    for (int n0 = 0; n0 < 4; ++n0)
      #pragma unroll
      for (int r = 0; r < 4; ++r) {
        const int row = n0 * 16 + lq;
        const int col = w * 64 + wave * 16 + quad * 4 + r;
        qt_l[row * 136 + col] = f2bf(aq[w][n0][r] * SCALE_Q);
        kt_l[row * 136 + col] = f2bf(ak[w][n0][r]);
      }
  __syncthreads();
  #pragma unroll
  for (int i = 0; i < 4; ++i) {
    const int u = threadIdx.x + i * 256;
    const int row = u >> 4, ch16 = u & 15;           // 64 rows x 16 chunks of 8 ch
    const int h = ot2 * 2 + (ch16 >> 3);
    const int d0 = (ch16 & 7) * 8;
    const size_t hb = (size_t)(n * NH + h);
    *(uint4*)(Qt + (hb * LL + l0 + row) * DH + d0) = *(const uint4*)&qt_l[row * 136 + ch16 * 8];
    *(uint4*)(Kt + (hb * LL + l0 + row) * DH + d0) = *(const uint4*)&kt_l[row * 136 + ch16 * 8];
  }
}

// ---------------- MFMA flash attention (round-0 proven body): 64 q/wave ----------------
// grid (LL/256, NH*2, NB) = 512 blocks, block 256 (4 waves).
// Reg-staged K/V prefetch, ones-MFMA l-sum, 2 waves/SIMD — measured best (74.4 us).
__global__ __launch_bounds__(256, 2) void attn_mfma_kernel(
    const short* __restrict__ Qt, const short* __restrict__ Kt,
    const _Float16* __restrict__ Vb, _Float16* __restrict__ Opart,
    float* __restrict__ lpart) {
  __shared__ __align__(16) short    k_lds[2][64 * 64];   // 8 KB each, swizzled
  __shared__ __align__(16) _Float16 v_lds[2][64 * 64];   // 8 KB each, swizzled+permuted

  const int t = threadIdx.x;
  const int wave = t >> 6, lane = t & 63;
  const int lq = lane & 15, quad = lane >> 4;
  const int l0 = blockIdx.x * 256;
  const int h = blockIdx.y >> 1, split = blockIdx.y & 1;
  const int n = blockIdx.z;
  const int kbase = split * 2048;
  const int R = n * NH + h;
  const size_t hb = (size_t)R * (size_t)LL * DH;
  const short* const Kp = Kt + hb;      // [key][d] bf16
  const _Float16* const Vp = Vb + hb;   // [d][key] f16

  // Q B-frags: B[n=q][k=d] — wave's 64 q rows
  const int qbase = l0 + wave * 64;
  bf16x8 qb[4][2];
  #pragma unroll
  for (int qf = 0; qf < 4; ++qf)
    #pragma unroll
    for (int c = 0; c < 2; ++c)
      qb[qf][c] = *(const bf16x8*)(Qt + hb + (size_t)(qbase + qf * 16 + lq) * DH + c * 32 + quad * 8);

  const f32x4 z = {0.f, 0.f, 0.f, 0.f};
  f32x4 o[4][4] = {{z, z, z, z}, {z, z, z, z}, {z, z, z, z}, {z, z, z, z}};
  f32x4 ol[4] = {z, z, z, z};

  f16x8 ones8;
  #pragma unroll
  for (int i = 0; i < 8; ++i) ones8[i] = (_Float16)1.0f;

  const int srow = t >> 3, sch = t & 7;   // staging: rows 0..31(+32), chunk 0..7
  const int vgo = 32 * (sch >> 2) + 4 * (sch & 3);  // permuted key offset (lo half)

  // stage tile 0
  {
    *(uint4*)&k_lds[0][sw(srow, sch)]      = *(const uint4*)(Kp + (size_t)(kbase + srow) * DH + sch * 8);
    *(uint4*)&k_lds[0][sw(32 + srow, sch)] = *(const uint4*)(Kp + (size_t)(kbase + 32 + srow) * DH + sch * 8);
    const _Float16* vg0 = Vp + (size_t)srow * LL + kbase + vgo;
    const _Float16* vg1 = Vp + (size_t)(32 + srow) * LL + kbase + vgo;
    uint2 a = *(const uint2*)vg0, b = *(const uint2*)(vg0 + 16);
    *(uint4*)&v_lds[0][sw(srow, sch)] = make_uint4(a.x, a.y, b.x, b.y);
    a = *(const uint2*)vg1; b = *(const uint2*)(vg1 + 16);
    *(uint4*)&v_lds[0][sw(32 + srow, sch)] = make_uint4(a.x, a.y, b.x, b.y);
  }
  __syncthreads();

  for (int kt = 0; kt < 32; ++kt) {
    const int cur = kt & 1;
    // prefetch next tile into regs
    uint4 kpre[2]; uint2 vpre[4];
    if (kt < 31) {
      const int kpos = kbase + (kt + 1) * 64;
      kpre[0] = *(const uint4*)(Kp + (size_t)(kpos + srow) * DH + sch * 8);
      kpre[1] = *(const uint4*)(Kp + (size_t)(kpos + 32 + srow) * DH + sch * 8);
      const _Float16* vg0 = Vp + (size_t)srow * LL + kpos + vgo;
      const _Float16* vg1 = Vp + (size_t)(32 + srow) * LL + kpos + vgo;
      vpre[0] = *(const uint2*)vg0;
      vpre[1] = *(const uint2*)(vg0 + 16);
      vpre[2] = *(const uint2*)vg1;
      vpre[3] = *(const uint2*)(vg1 + 16);
    }
    const short* kb = k_lds[cur];
    const _Float16* vbuf = v_lds[cur];

    // ---- S^T = K·Q^T (bf16), p = exp2(s) -> f16 pack directly into A-frags ----
    union PU { f16x4 h4[2]; f16x8 h8; } af[2][4];
    #pragma unroll
    for (int mf = 0; mf < 4; ++mf) {
      const bf16x8 ka0 = *(const bf16x8*)&kb[sw(mf * 16 + lq, quad)];
      const bf16x8 ka1 = *(const bf16x8*)&kb[sw(mf * 16 + lq, 4 + quad)];
      #pragma unroll
      for (int qf = 0; qf < 4; ++qf) {
        f32x4 zz = {0.f, 0.f, 0.f, 0.f};
        zz = __builtin_amdgcn_mfma_f32_16x16x32_bf16(ka0, qb[qf][0], zz, 0, 0, 0);
        zz = __builtin_amdgcn_mfma_f32_16x16x32_bf16(ka1, qb[qf][1], zz, 0, 0, 0);
        union { h16x2 h2[2]; f16x4 h4; } u;
        u.h2[0] = __builtin_amdgcn_cvt_pkrtz(__builtin_amdgcn_exp2f(zz[0]),
                                             __builtin_amdgcn_exp2f(zz[1]));
        u.h2[1] = __builtin_amdgcn_cvt_pkrtz(__builtin_amdgcn_exp2f(zz[2]),
                                             __builtin_amdgcn_exp2f(zz[3]));
        af[mf >> 1][qf].h4[mf & 1] = u.h4;
      }
    }

    // ---- l-sum via ones-MFMA: D rows == o rows, in-lane ----
    #pragma unroll
    for (int qf = 0; qf < 4; ++qf) {
      ol[qf] = __builtin_amdgcn_mfma_f32_16x16x32_f16(af[0][qf].h8, ones8, ol[qf], 0, 0, 0);
      ol[qf] = __builtin_amdgcn_mfma_f32_16x16x32_f16(af[1][qf].h8, ones8, ol[qf], 0, 0, 0);
    }

    // ---- O += P·V: b128 V-frags, 0-conflict pattern ----
    #pragma unroll
    for (int df = 0; df < 4; ++df)
      #pragma unroll
      for (int cc = 0; cc < 2; ++cc) {
        const f16x8 vb8 = *(const f16x8*)&vbuf[sw(df * 16 + lq, cc * 4 + quad)];
        #pragma unroll
        for (int qf = 0; qf < 4; ++qf)
          o[qf][df] = __builtin_amdgcn_mfma_f32_16x16x32_f16(af[cc][qf].h8, vb8, o[qf][df], 0, 0, 0);
      }

    // ---- write prefetched tile to other buffer ----
    if (kt < 31) {
      const int nxt = 1 - cur;
      *(uint4*)&k_lds[nxt][sw(srow, sch)]      = kpre[0];
      *(uint4*)&k_lds[nxt][sw(32 + srow, sch)] = kpre[1];
      *(uint4*)&v_lds[nxt][sw(srow, sch)]      = make_uint4(vpre[0].x, vpre[0].y, vpre[1].x, vpre[1].y);
      *(uint4*)&v_lds[nxt][sw(32 + srow, sch)] = make_uint4(vpre[2].x, vpre[2].y, vpre[3].x, vpre[3].y);
      __syncthreads();
    }
  }

  // ---- epilogue: store partial l (rows match in-lane) + raw fp16 partial O ----
  const size_t pb = ((size_t)split * 16 + R) * (size_t)LL * DH;
  #pragma unroll
  for (int qf = 0; qf < 4; ++qf) {
    if (lq == 0) {
      #pragma unroll
      for (int r = 0; r < 4; ++r)
        lpart[((size_t)split * 16 + R) * LL + qbase + qf * 16 + quad * 4 + r] = ol[qf][r];
    }
    #pragma unroll
    for (int df = 0; df < 4; ++df)
      #pragma unroll
      for (int r = 0; r < 4; ++r) {
        const int q = qbase + qf * 16 + quad * 4 + r;
        Opart[pb + (size_t)q * DH + df * 16 + lq] = (_Float16)o[qf][df][r];
      }
  }
}

// ---------------- output projection (f16 MFMA, fused normalize, 2 o-tiles) ----------------
__global__ __launch_bounds__(256) void proj_gemm(
    const _Float16* __restrict__ Opart, const float* __restrict__ lpart,
    const _Float16* __restrict__ Wpf, const float* __restrict__ bp,
    float* __restrict__ out) {
  const int lt = blockIdx.x, ot2 = blockIdx.y;   // ot2 covers 128 output channels
  const int n = lt >> 6, l0 = (lt & 63) << 6;
  const int wave = threadIdx.x >> 6, lane = threadIdx.x & 63;
  const int lq = lane & 15, quad = lane >> 4;

  const _Float16* wpp0 = Wpf + (ot2 * 128 + wave * 16 + lq) * CC + quad * 8;
  const _Float16* wpp1 = wpp0 + 64 * CC;

  // per-(n0,h) 1/l as f16 (l = lpart split0 + split1)
  _Float16 invl[4][4];
  #pragma unroll
  for (int n0 = 0; n0 < 4; ++n0) {
    const int q = l0 + n0 * 16 + lq;
    #pragma unroll
    for (int h = 0; h < 4; ++h) {
      const size_t rr = (size_t)(n * NH + h) * LL + q;
      invl[n0][h] = (_Float16)(1.0f / (lpart[rr] + lpart[rr + 16 * (size_t)LL]));
    }
  }

  const f32x4 z = {0.f, 0.f, 0.f, 0.f};
  f32x4 acc[2][4] = {{z, z, z, z}, {z, z, z, z}};
  #pragma unroll
  for (int c0 = 0; c0 < 256; c0 += 32) {
    const int h = c0 >> 6;
    const int d0 = (c0 & 63) + quad * 8;
    const f16x8 fa0 = *(const f16x8*)(wpp0 + c0);
    const f16x8 fa1 = *(const f16x8*)(wpp1 + c0);
    #pragma unroll
    for (int n0 = 0; n0 < 4; ++n0) {
      const int q = l0 + n0 * 16 + lq;
      const size_t e = ((size_t)(n * NH + h) * LL + q) * DH + d0;
      const f16x8 b0 = *(const f16x8*)(Opart + e);
      const f16x8 b1 = *(const f16x8*)(Opart + e + (size_t)PSPLIT);
      f16x8 sc8;
      #pragma unroll
      for (int i = 0; i < 8; ++i) sc8[i] = invl[n0][h];
      const f16x8 fb = (b0 + b1) * sc8;
      acc[0][n0] = __builtin_amdgcn_mfma_f32_16x16x32_f16(fa0, fb, acc[0][n0], 0, 0, 0);
      acc[1][n0] = __builtin_amdgcn_mfma_f32_16x16x32_f16(fa1, fb, acc[1][n0], 0, 0, 0);
    }
  }
  #pragma unroll
  for (int w = 0; w < 2; ++w)
    #pragma unroll
    for (int r = 0; r < 4; ++r) {
      const int oo = ot2 * 128 + w * 64 + wave * 16 + quad * 4 + r;
      const float bias = bp[oo];
      #pragma unroll
      for (int n0 = 0; n0 < 4; ++n0)
        out[((size_t)n * CC + oo) * LL + l0 + n0 * 16 + lq] = acc[w][n0][r] + bias;
    }
}

extern "C" void kernel_launch(void* const* d_in, const int* in_sizes, int n_in,
                              void* d_out, int out_size, void* d_ws, size_t ws_size,
                              hipStream_t stream) {
  const float* x     = (const float*)d_in[0];
  const float* gamma = (const float*)d_in[1];
  const float* beta  = (const float*)d_in[2];
  const float* Wq    = (const float*)d_in[3];
  const float* Wk    = (const float*)d_in[4];
  const float* Wv    = (const float*)d_in[5];
  const float* Wp    = (const float*)d_in[6];
  const float* bp    = (const float*)d_in[7];
  float* out = (float*)d_out;

  const size_t S = (size_t)NB * CC * LL;  // 4,194,304
  short*     Qt  = (short*)d_ws;          // bf16 [n,h][l][d]
  short*     Kt  = Qt + S;
  _Float16*  Vo  = (_Float16*)(Kt + S);   // f16 [n,h][d][l]
  short*     Wb  = (short*)(Vo + S);      // 4 x 65536 (bf16 x3, f16 x1)
  _Float16*  Opart = (_Float16*)(Wb + 4 * 65536);  // 2 x 8 MB fp16
  float*     lpart = (float*)(Opart + 2 * (size_t)PSPLIT); // 2 x 256 KB fp32
  float*     pstat = lpart + 2 * 16 * (size_t)LL;  // 1024 floats GN partials

  gnstats_wcvt<<<640,                 256, 0, stream>>>(x, pstat, Wq, Wk, Wv, Wp, Wb);
  qkv_gemm   <<<dim3(256, 2),         256, 0, stream>>>(x, gamma, beta, pstat,
                 Wb, Wb + 65536, Wb + 131072, Qt, Kt, Vo);
  attn_mfma_kernel<<<dim3(LL/256, NH*2, NB), 256, 0, stream>>>(Qt, Kt, Vo, Opart, lpart);
  proj_gemm  <<<dim3(256, 2),         256, 0, stream>>>(Opart, lpart,
                 (const _Float16*)(Wb + 196608), bp, out);
}

// Round 10
// 181.489 us; speedup vs baseline: 2.0686x; 1.0205x over previous
//
#include <hip/hip_runtime.h>
#include <cstddef>
#include <cstdint>

#define NB 4
#define CC 256
#define LL 4096
#define NG 32
#define CPG 8
#define NH 4
#define DH 64
#define PSPLIT 4194304   // fp16 partial-O elements per split: 16*4096*64

static constexpr float EPSV  = 1e-5f;
static constexpr float SCALE_Q = 0.125f * 1.4426950408889634f; // dh^-0.5 * log2(e)

typedef __attribute__((ext_vector_type(8))) short bf16x8;
typedef __attribute__((ext_vector_type(4))) float f32x4;
typedef _Float16 f16x8 __attribute__((ext_vector_type(8)));
typedef _Float16 f16x4 __attribute__((ext_vector_type(4)));
typedef __fp16  h16x2 __attribute__((ext_vector_type(2)));   // cvt_pkrtz native type

__device__ __forceinline__ short f2bf(float f) {
  unsigned u = __float_as_uint(f);
  unsigned r = (u + 0x7fffu + ((u >> 16) & 1u)) >> 16;
  return (short)r;
}
__device__ __forceinline__ short f2h(float f) {
  union { _Float16 h; short s; } u;
  u.h = (_Float16)f;
  return u.s;
}
// element offset of 16B chunk (8 elems) with XOR swizzle: row stride 64 elems
__device__ __forceinline__ int sw(int row, int chunk) {
  return row * 64 + ((chunk ^ (row & 7)) * 8);
}

// ---------------- fused GroupNorm stats (512 blocks) + weight cvt (128 blocks) ----------------
// wcvt emits FRAGMENT-MAJOR layout: for 16-out x 32-c tile (t = o/16, c5 = c/32),
// element at ((t*8+c5)*64 + quad*16 + row)*8 + e  (quad = (c>>3)&3, row = o&15).
// A wave's MFMA A-frag load is then ONE contiguous 1KB transaction:
//   W + (t*8+c5)*512 + lane*8   (lane = quad*16+lq).
__global__ __launch_bounds__(256) void gnstats_wcvt(
    const float* __restrict__ x, float* __restrict__ pstat,
    const float* __restrict__ Wq, const float* __restrict__ Wk,
    const float* __restrict__ Wv, const float* __restrict__ Wp,
    short* __restrict__ wdst) {
  __shared__ float r1[4], r2[4];
  const int blk = blockIdx.x;
  if (blk < 512) {
    const int grp = blk >> 2, qtr = blk & 3;          // grp = n*32+g
    const float* xp = x + (size_t)grp * CPG * LL + qtr * 1024 + threadIdx.x * 4;
    float s = 0.f, ss = 0.f;
    #pragma unroll
    for (int cc = 0; cc < 8; ++cc) {
      const float4 v = *(const float4*)(xp + (size_t)cc * LL);
      s  += v.x + v.y + v.z + v.w;
      ss += v.x * v.x + v.y * v.y + v.z * v.z + v.w * v.w;
    }
    #pragma unroll
    for (int off = 32; off; off >>= 1) {
      s  += __shfl_down(s, off);
      ss += __shfl_down(ss, off);
    }
    const int wid = threadIdx.x >> 6, lane = threadIdx.x & 63;
    if (lane == 0) { r1[wid] = s; r2[wid] = ss; }
    __syncthreads();
    if (threadIdx.x == 0) {
      float S = 0.f, SS = 0.f;
      #pragma unroll
      for (int w = 0; w < 4; ++w) { S += r1[w]; SS += r2[w]; }
      pstat[blk * 2]     = S;
      pstat[blk * 2 + 1] = SS;
    }
  } else {
    const int wblk = blk - 512;
    const int which = wblk >> 5;
    const float* src = (which == 0) ? Wq : (which == 1) ? Wk : (which == 2) ? Wv : Wp;
    const int base = (wblk & 31) * 2048 + threadIdx.x * 8;
    const float4 v0 = *(const float4*)(src + base);
    const float4 v1 = *(const float4*)(src + base + 4);
    short ob[8] __attribute__((aligned(16)));
    if (which < 3) {
      ob[0] = f2bf(v0.x); ob[1] = f2bf(v0.y); ob[2] = f2bf(v0.z); ob[3] = f2bf(v0.w);
      ob[4] = f2bf(v1.x); ob[5] = f2bf(v1.y); ob[6] = f2bf(v1.z); ob[7] = f2bf(v1.w);
    } else {
      ob[0] = f2h(v0.x); ob[1] = f2h(v0.y); ob[2] = f2h(v0.z); ob[3] = f2h(v0.w);
      ob[4] = f2h(v1.x); ob[5] = f2h(v1.y); ob[6] = f2h(v1.z); ob[7] = f2h(v1.w);
    }
    const int o = base >> 8, c = base & 255;
    const int dst = (((o >> 4) * 8 + (c >> 5)) * 64 + ((c >> 3) & 3) * 16 + (o & 15)) * 8;
    *(uint4*)(wdst + which * 65536 + dst) = *(const uint4*)ob;
  }
}

// ---------------- QKV MFMA GEMM v3: fused GN staging, frag-major weights ----------------
// grid (256, 2): block stages its 64l x 256c x-tile once, computes 128 outputs.
// Weight A-frags now load as ONE coalesced 1KB/wave transaction per fragment.
// Qt/Kt bf16 [n,h][l][d] (Q scaled by log2e/8). Vo f16 [n,h][d][l].
__global__ __launch_bounds__(256) void qkv_gemm(
    const float* __restrict__ x, const float* __restrict__ gamma,
    const float* __restrict__ beta, const float* __restrict__ pstat,
    const short* __restrict__ Wqb, const short* __restrict__ Wkb,
    const short* __restrict__ Wvb,
    short* __restrict__ Qt, short* __restrict__ Kt, _Float16* __restrict__ Vo) {
  __shared__ __align__(16) short smem[64 * 272];   // 34816 B; xn tile (stride 264), later qt/kt (stride 136)
  const int lt = blockIdx.x, ot2 = blockIdx.y;     // ot2 covers 128 output channels
  const int n = lt >> 6, l0 = (lt & 63) << 6;
  const int wave = threadIdx.x >> 6, lane = threadIdx.x & 63;
  const int lq = lane & 15, quad = lane >> 4;

  // ---- stage: normalize + bf16 + transpose into LDS (once per block) ----
  #pragma unroll
  for (int i = 0; i < 2; ++i) {
    const int u = threadIdx.x + i * 256;
    const int cc = u >> 4, l4 = u & 15;              // cc = c-chunk == group
    const int grp = n * NG + cc;
    float S = 0.f, SS = 0.f;
    #pragma unroll
    for (int w = 0; w < 4; ++w) {
      S  += pstat[(grp * 4 + w) * 2];
      SS += pstat[(grp * 4 + w) * 2 + 1];
    }
    const float mean = S / 32768.f;                  // NE = 8*4096
    const float rstd = rsqrtf(SS / 32768.f - mean * mean + EPSV);
    const float* xp = x + (size_t)(n * CC + cc * CPG) * LL + l0 + l4 * 4;
    short ob[4][8] __attribute__((aligned(16)));
    #pragma unroll
    for (int j = 0; j < 8; ++j) {
      const float scl = rstd * gamma[cc * CPG + j];
      const float shf = beta[cc * CPG + j] - mean * scl;
      const float4 v = *(const float4*)(xp + (size_t)j * LL);
      ob[0][j] = f2bf(v.x * scl + shf);
      ob[1][j] = f2bf(v.y * scl + shf);
      ob[2][j] = f2bf(v.z * scl + shf);
      ob[3][j] = f2bf(v.w * scl + shf);
    }
    short* dst = smem + (l4 * 4) * 264 + cc * 8;
    #pragma unroll
    for (int jj = 0; jj < 4; ++jj)
      *(uint4*)(dst + jj * 264) = *(const uint4*)ob[jj];
  }
  __syncthreads();

  // ---- MFMA K-loop: frag-major weights (coalesced), fb frags from LDS ----
  const int tb   = (ot2 * 8 + wave) * 8;             // tile base for w=0 (x512 elems)
  const int loff = lane * 8;
  const short* xl = smem + lq * 264 + quad * 8;

  const f32x4 z = {0.f, 0.f, 0.f, 0.f};
  f32x4 aq[2][4] = {{z, z, z, z}, {z, z, z, z}};
  f32x4 ak[2][4] = {{z, z, z, z}, {z, z, z, z}};
  f32x4 av[2][4] = {{z, z, z, z}, {z, z, z, z}};

  #pragma unroll
  for (int c5 = 0; c5 < 8; ++c5) {
    const int c0 = c5 * 32;
    const bf16x8 fq0 = *(const bf16x8*)(Wqb + (tb + c5) * 512 + loff);
    const bf16x8 fq1 = *(const bf16x8*)(Wqb + (tb + 32 + c5) * 512 + loff);
    const bf16x8 fk0 = *(const bf16x8*)(Wkb + (tb + c5) * 512 + loff);
    const bf16x8 fk1 = *(const bf16x8*)(Wkb + (tb + 32 + c5) * 512 + loff);
    const bf16x8 fv0 = *(const bf16x8*)(Wvb + (tb + c5) * 512 + loff);
    const bf16x8 fv1 = *(const bf16x8*)(Wvb + (tb + 32 + c5) * 512 + loff);
    #pragma unroll
    for (int n0 = 0; n0 < 4; ++n0) {
      const bf16x8 fb = *(const bf16x8*)(xl + (n0 * 16) * 264 + c0);
      aq[0][n0] = __builtin_amdgcn_mfma_f32_16x16x32_bf16(fq0, fb, aq[0][n0], 0, 0, 0);
      aq[1][n0] = __builtin_amdgcn_mfma_f32_16x16x32_bf16(fq1, fb, aq[1][n0], 0, 0, 0);
      ak[0][n0] = __builtin_amdgcn_mfma_f32_16x16x32_bf16(fk0, fb, ak[0][n0], 0, 0, 0);
      ak[1][n0] = __builtin_amdgcn_mfma_f32_16x16x32_bf16(fk1, fb, ak[1][n0], 0, 0, 0);
      av[0][n0] = __builtin_amdgcn_mfma_f32_16x16x32_bf16(fv0, fb, av[0][n0], 0, 0, 0);
      av[1][n0] = __builtin_amdgcn_mfma_f32_16x16x32_bf16(fv1, fb, av[1][n0], 0, 0, 0);
    }
  }

  // ---- V write: channel = ot2*128 + w*64 + wave*16 + quad*4 + r -> (h, d) ----
  #pragma unroll
  for (int w = 0; w < 2; ++w) {
    const size_t hb = (size_t)(n * NH + ot2 * 2 + w);
    #pragma unroll
    for (int n0 = 0; n0 < 4; ++n0)
      #pragma unroll
      for (int r = 0; r < 4; ++r)
        Vo[(hb * DH + wave * 16 + quad * 4 + r) * LL + l0 + n0 * 16 + lq] =
            (_Float16)av[w][n0][r];
  }

  // ---- reuse LDS for Qt/Kt repack: [64 l][136] per tensor (16B-aligned rows) ----
  __syncthreads();                                   // all xn reads done
  short* qt_l = smem;                                // [64][136]
  short* kt_l = smem + 64 * 136;                     // [64][136]
  #pragma unroll
  for (int w = 0; w < 2; ++w)
    #pragma unroll
    for (int n0 = 0; n0 < 4; ++n0)
      #pragma unroll
      for (int r = 0; r < 4; ++r) {
        const int row = n0 * 16 + lq;
        const int col = w * 64 + wave * 16 + quad * 4 + r;
        qt_l[row * 136 + col] = f2bf(aq[w][n0][r] * SCALE_Q);
        kt_l[row * 136 + col] = f2bf(ak[w][n0][r]);
      }
  __syncthreads();
  #pragma unroll
  for (int i = 0; i < 4; ++i) {
    const int u = threadIdx.x + i * 256;
    const int row = u >> 4, ch16 = u & 15;           // 64 rows x 16 chunks of 8 ch
    const int h = ot2 * 2 + (ch16 >> 3);
    const int d0 = (ch16 & 7) * 8;
    const size_t hb = (size_t)(n * NH + h);
    *(uint4*)(Qt + (hb * LL + l0 + row) * DH + d0) = *(const uint4*)&qt_l[row * 136 + ch16 * 8];
    *(uint4*)(Kt + (hb * LL + l0 + row) * DH + d0) = *(const uint4*)&kt_l[row * 136 + ch16 * 8];
  }
}

// ---------------- MFMA flash attention (round-0 proven body): 64 q/wave ----------------
// grid (LL/256, NH*2, NB) = 512 blocks, block 256 (4 waves).
// Reg-staged K/V prefetch, ones-MFMA l-sum, 2 waves/SIMD — measured best (74.4 us).
__global__ __launch_bounds__(256, 2) void attn_mfma_kernel(
    const short* __restrict__ Qt, const short* __restrict__ Kt,
    const _Float16* __restrict__ Vb, _Float16* __restrict__ Opart,
    float* __restrict__ lpart) {
  __shared__ __align__(16) short    k_lds[2][64 * 64];   // 8 KB each, swizzled
  __shared__ __align__(16) _Float16 v_lds[2][64 * 64];   // 8 KB each, swizzled+permuted

  const int t = threadIdx.x;
  const int wave = t >> 6, lane = t & 63;
  const int lq = lane & 15, quad = lane >> 4;
  const int l0 = blockIdx.x * 256;
  const int h = blockIdx.y >> 1, split = blockIdx.y & 1;
  const int n = blockIdx.z;
  const int kbase = split * 2048;
  const int R = n * NH + h;
  const size_t hb = (size_t)R * (size_t)LL * DH;
  const short* const Kp = Kt + hb;      // [key][d] bf16
  const _Float16* const Vp = Vb + hb;   // [d][key] f16

  // Q B-frags: B[n=q][k=d] — wave's 64 q rows
  const int qbase = l0 + wave * 64;
  bf16x8 qb[4][2];
  #pragma unroll
  for (int qf = 0; qf < 4; ++qf)
    #pragma unroll
    for (int c = 0; c < 2; ++c)
      qb[qf][c] = *(const bf16x8*)(Qt + hb + (size_t)(qbase + qf * 16 + lq) * DH + c * 32 + quad * 8);

  const f32x4 z = {0.f, 0.f, 0.f, 0.f};
  f32x4 o[4][4] = {{z, z, z, z}, {z, z, z, z}, {z, z, z, z}, {z, z, z, z}};
  f32x4 ol[4] = {z, z, z, z};

  f16x8 ones8;
  #pragma unroll
  for (int i = 0; i < 8; ++i) ones8[i] = (_Float16)1.0f;

  const int srow = t >> 3, sch = t & 7;   // staging: rows 0..31(+32), chunk 0..7
  const int vgo = 32 * (sch >> 2) + 4 * (sch & 3);  // permuted key offset (lo half)

  // stage tile 0
  {
    *(uint4*)&k_lds[0][sw(srow, sch)]      = *(const uint4*)(Kp + (size_t)(kbase + srow) * DH + sch * 8);
    *(uint4*)&k_lds[0][sw(32 + srow, sch)] = *(const uint4*)(Kp + (size_t)(kbase + 32 + srow) * DH + sch * 8);
    const _Float16* vg0 = Vp + (size_t)srow * LL + kbase + vgo;
    const _Float16* vg1 = Vp + (size_t)(32 + srow) * LL + kbase + vgo;
    uint2 a = *(const uint2*)vg0, b = *(const uint2*)(vg0 + 16);
    *(uint4*)&v_lds[0][sw(srow, sch)] = make_uint4(a.x, a.y, b.x, b.y);
    a = *(const uint2*)vg1; b = *(const uint2*)(vg1 + 16);
    *(uint4*)&v_lds[0][sw(32 + srow, sch)] = make_uint4(a.x, a.y, b.x, b.y);
  }
  __syncthreads();

  for (int kt = 0; kt < 32; ++kt) {
    const int cur = kt & 1;
    // prefetch next tile into regs
    uint4 kpre[2]; uint2 vpre[4];
    if (kt < 31) {
      const int kpos = kbase + (kt + 1) * 64;
      kpre[0] = *(const uint4*)(Kp + (size_t)(kpos + srow) * DH + sch * 8);
      kpre[1] = *(const uint4*)(Kp + (size_t)(kpos + 32 + srow) * DH + sch * 8);
      const _Float16* vg0 = Vp + (size_t)srow * LL + kpos + vgo;
      const _Float16* vg1 = Vp + (size_t)(32 + srow) * LL + kpos + vgo;
      vpre[0] = *(const uint2*)vg0;
      vpre[1] = *(const uint2*)(vg0 + 16);
      vpre[2] = *(const uint2*)vg1;
      vpre[3] = *(const uint2*)(vg1 + 16);
    }
    const short* kb = k_lds[cur];
    const _Float16* vbuf = v_lds[cur];

    // ---- S^T = K·Q^T (bf16), p = exp2(s) -> f16 pack directly into A-frags ----
    union PU { f16x4 h4[2]; f16x8 h8; } af[2][4];
    #pragma unroll
    for (int mf = 0; mf < 4; ++mf) {
      const bf16x8 ka0 = *(const bf16x8*)&kb[sw(mf * 16 + lq, quad)];
      const bf16x8 ka1 = *(const bf16x8*)&kb[sw(mf * 16 + lq, 4 + quad)];
      #pragma unroll
      for (int qf = 0; qf < 4; ++qf) {
        f32x4 zz = {0.f, 0.f, 0.f, 0.f};
        zz = __builtin_amdgcn_mfma_f32_16x16x32_bf16(ka0, qb[qf][0], zz, 0, 0, 0);
        zz = __builtin_amdgcn_mfma_f32_16x16x32_bf16(ka1, qb[qf][1], zz, 0, 0, 0);
        union { h16x2 h2[2]; f16x4 h4; } u;
        u.h2[0] = __builtin_amdgcn_cvt_pkrtz(__builtin_amdgcn_exp2f(zz[0]),
                                             __builtin_amdgcn_exp2f(zz[1]));
        u.h2[1] = __builtin_amdgcn_cvt_pkrtz(__builtin_amdgcn_exp2f(zz[2]),
                                             __builtin_amdgcn_exp2f(zz[3]));
        af[mf >> 1][qf].h4[mf & 1] = u.h4;
      }
    }

    // ---- l-sum via ones-MFMA: D rows == o rows, in-lane ----
    #pragma unroll
    for (int qf = 0; qf < 4; ++qf) {
      ol[qf] = __builtin_amdgcn_mfma_f32_16x16x32_f16(af[0][qf].h8, ones8, ol[qf], 0, 0, 0);
      ol[qf] = __builtin_amdgcn_mfma_f32_16x16x32_f16(af[1][qf].h8, ones8, ol[qf], 0, 0, 0);
    }

    // ---- O += P·V: b128 V-frags, 0-conflict pattern ----
    #pragma unroll
    for (int df = 0; df < 4; ++df)
      #pragma unroll
      for (int cc = 0; cc < 2; ++cc) {
        const f16x8 vb8 = *(const f16x8*)&vbuf[sw(df * 16 + lq, cc * 4 + quad)];
        #pragma unroll
        for (int qf = 0; qf < 4; ++qf)
          o[qf][df] = __builtin_amdgcn_mfma_f32_16x16x32_f16(af[cc][qf].h8, vb8, o[qf][df], 0, 0, 0);
      }

    // ---- write prefetched tile to other buffer ----
    if (kt < 31) {
      const int nxt = 1 - cur;
      *(uint4*)&k_lds[nxt][sw(srow, sch)]      = kpre[0];
      *(uint4*)&k_lds[nxt][sw(32 + srow, sch)] = kpre[1];
      *(uint4*)&v_lds[nxt][sw(srow, sch)]      = make_uint4(vpre[0].x, vpre[0].y, vpre[1].x, vpre[1].y);
      *(uint4*)&v_lds[nxt][sw(32 + srow, sch)] = make_uint4(vpre[2].x, vpre[2].y, vpre[3].x, vpre[3].y);
      __syncthreads();
    }
  }

  // ---- epilogue: store partial l (rows match in-lane) + raw fp16 partial O ----
  const size_t pb = ((size_t)split * 16 + R) * (size_t)LL * DH;
  #pragma unroll
  for (int qf = 0; qf < 4; ++qf) {
    if (lq == 0) {
      #pragma unroll
      for (int r = 0; r < 4; ++r)
        lpart[((size_t)split * 16 + R) * LL + qbase + qf * 16 + quad * 4 + r] = ol[qf][r];
    }
    #pragma unroll
    for (int df = 0; df < 4; ++df)
      #pragma unroll
      for (int r = 0; r < 4; ++r) {
        const int q = qbase + qf * 16 + quad * 4 + r;
        Opart[pb + (size_t)q * DH + df * 16 + lq] = (_Float16)o[qf][df][r];
      }
  }
}

// ---------------- output projection (f16 MFMA, frag-major weights) ----------------
__global__ __launch_bounds__(256) void proj_gemm(
    const _Float16* __restrict__ Opart, const float* __restrict__ lpart,
    const _Float16* __restrict__ Wpf, const float* __restrict__ bp,
    float* __restrict__ out) {
  const int lt = blockIdx.x, ot2 = blockIdx.y;   // ot2 covers 128 output channels
  const int n = lt >> 6, l0 = (lt & 63) << 6;
  const int wave = threadIdx.x >> 6, lane = threadIdx.x & 63;
  const int lq = lane & 15, quad = lane >> 4;

  const int tb   = (ot2 * 8 + wave) * 8;         // frag tile base for w=0
  const int loff = lane * 8;

  // per-(n0,h) 1/l as f16 (l = lpart split0 + split1)
  _Float16 invl[4][4];
  #pragma unroll
  for (int n0 = 0; n0 < 4; ++n0) {
    const int q = l0 + n0 * 16 + lq;
    #pragma unroll
    for (int h = 0; h < 4; ++h) {
      const size_t rr = (size_t)(n * NH + h) * LL + q;
      invl[n0][h] = (_Float16)(1.0f / (lpart[rr] + lpart[rr + 16 * (size_t)LL]));
    }
  }

  const f32x4 z = {0.f, 0.f, 0.f, 0.f};
  f32x4 acc[2][4] = {{z, z, z, z}, {z, z, z, z}};
  #pragma unroll
  for (int c5 = 0; c5 < 8; ++c5) {
    const int c0 = c5 * 32;
    const int h = c0 >> 6;
    const int d0 = (c0 & 63) + quad * 8;
    const f16x8 fa0 = *(const f16x8*)(Wpf + (tb + c5) * 512 + loff);
    const f16x8 fa1 = *(const f16x8*)(Wpf + (tb + 32 + c5) * 512 + loff);
    #pragma unroll
    for (int n0 = 0; n0 < 4; ++n0) {
      const int q = l0 + n0 * 16 + lq;
      const size_t e = ((size_t)(n * NH + h) * LL + q) * DH + d0;
      const f16x8 b0 = *(const f16x8*)(Opart + e);
      const f16x8 b1 = *(const f16x8*)(Opart + e + (size_t)PSPLIT);
      f16x8 sc8;
      #pragma unroll
      for (int i = 0; i < 8; ++i) sc8[i] = invl[n0][h];
      const f16x8 fb = (b0 + b1) * sc8;
      acc[0][n0] = __builtin_amdgcn_mfma_f32_16x16x32_f16(fa0, fb, acc[0][n0], 0, 0, 0);
      acc[1][n0] = __builtin_amdgcn_mfma_f32_16x16x32_f16(fa1, fb, acc[1][n0], 0, 0, 0);
    }
  }
  #pragma unroll
  for (int w = 0; w < 2; ++w)
    #pragma unroll
    for (int r = 0; r < 4; ++r) {
      const int oo = ot2 * 128 + w * 64 + wave * 16 + quad * 4 + r;
      const float bias = bp[oo];
      #pragma unroll
      for (int n0 = 0; n0 < 4; ++n0)
        out[((size_t)n * CC + oo) * LL + l0 + n0 * 16 + lq] = acc[w][n0][r] + bias;
    }
}

extern "C" void kernel_launch(void* const* d_in, const int* in_sizes, int n_in,
                              void* d_out, int out_size, void* d_ws, size_t ws_size,
                              hipStream_t stream) {
  const float* x     = (const float*)d_in[0];
  const float* gamma = (const float*)d_in[1];
  const float* beta  = (const float*)d_in[2];
  const float* Wq    = (const float*)d_in[3];
  const float* Wk    = (const float*)d_in[4];
  const float* Wv    = (const float*)d_in[5];
  const float* Wp    = (const float*)d_in[6];
  const float* bp    = (const float*)d_in[7];
  float* out = (float*)d_out;

  const size_t S = (size_t)NB * CC * LL;  // 4,194,304
  short*     Qt  = (short*)d_ws;          // bf16 [n,h][l][d]
  short*     Kt  = Qt + S;
  _Float16*  Vo  = (_Float16*)(Kt + S);   // f16 [n,h][d][l]
  short*     Wb  = (short*)(Vo + S);      // 4 x 65536 (bf16 x3, f16 x1), frag-major
  _Float16*  Opart = (_Float16*)(Wb + 4 * 65536);  // 2 x 8 MB fp16
  float*     lpart = (float*)(Opart + 2 * (size_t)PSPLIT); // 2 x 256 KB fp32
  float*     pstat = lpart + 2 * 16 * (size_t)LL;  // 1024 floats GN partials

  gnstats_wcvt<<<640,                 256, 0, stream>>>(x, pstat, Wq, Wk, Wv, Wp, Wb);
  qkv_gemm   <<<dim3(256, 2),         256, 0, stream>>>(x, gamma, beta, pstat,
                 Wb, Wb + 65536, Wb + 131072, Qt, Kt, Vo);
  attn_mfma_kernel<<<dim3(LL/256, NH*2, NB), 256, 0, stream>>>(Qt, Kt, Vo, Opart, lpart);
  proj_gemm  <<<dim3(256, 2),         256, 0, stream>>>(Opart, lpart,
                 (const _Float16*)(Wb + 196608), bp, out);
}

// Round 11
// 171.517 us; speedup vs baseline: 2.1889x; 1.0581x over previous
//
#include <hip/hip_runtime.h>
#include <cstddef>
#include <cstdint>

#define NB 4
#define CC 256
#define LL 4096
#define NG 32
#define CPG 8
#define NH 4
#define DH 64
#define PSPLIT 4194304   // fp16 partial-O elements per split: 16*4096*64

static constexpr float EPSV  = 1e-5f;
static constexpr float SCALE_Q = 0.125f * 1.4426950408889634f; // dh^-0.5 * log2(e)

typedef __attribute__((ext_vector_type(8))) short bf16x8;
typedef __attribute__((ext_vector_type(4))) float f32x4;
typedef _Float16 f16x8 __attribute__((ext_vector_type(8)));
typedef _Float16 f16x4 __attribute__((ext_vector_type(4)));
typedef __fp16  h16x2 __attribute__((ext_vector_type(2)));   // cvt_pkrtz native type

__device__ __forceinline__ short f2bf(float f) {
  unsigned u = __float_as_uint(f);
  unsigned r = (u + 0x7fffu + ((u >> 16) & 1u)) >> 16;
  return (short)r;
}
__device__ __forceinline__ short f2h(float f) {
  union { _Float16 h; short s; } u;
  u.h = (_Float16)f;
  return u.s;
}
// element offset of 16B chunk (8 elems) with XOR swizzle: row stride 64 elems
__device__ __forceinline__ int sw(int row, int chunk) {
  return row * 64 + ((chunk ^ (row & 7)) * 8);
}

// ---------------- fused GroupNorm stats (512 blocks) + weight cvt (128 blocks) ----------------
// wcvt emits FRAGMENT-MAJOR layout: tile t = o/16, c5 = c/32; element at
// ((t*8+c5)*64 + quad*16 + row)*8 + e. A-frag load = one 1KB wave transaction.
__global__ __launch_bounds__(256) void gnstats_wcvt(
    const float* __restrict__ x, float* __restrict__ pstat,
    const float* __restrict__ Wq, const float* __restrict__ Wk,
    const float* __restrict__ Wv, const float* __restrict__ Wp,
    short* __restrict__ wdst) {
  __shared__ float r1[4], r2[4];
  const int blk = blockIdx.x;
  if (blk < 512) {
    const int grp = blk >> 2, qtr = blk & 3;          // grp = n*32+g
    const float* xp = x + (size_t)grp * CPG * LL + qtr * 1024 + threadIdx.x * 4;
    float s = 0.f, ss = 0.f;
    #pragma unroll
    for (int cc = 0; cc < 8; ++cc) {
      const float4 v = *(const float4*)(xp + (size_t)cc * LL);
      s  += v.x + v.y + v.z + v.w;
      ss += v.x * v.x + v.y * v.y + v.z * v.z + v.w * v.w;
    }
    #pragma unroll
    for (int off = 32; off; off >>= 1) {
      s  += __shfl_down(s, off);
      ss += __shfl_down(ss, off);
    }
    const int wid = threadIdx.x >> 6, lane = threadIdx.x & 63;
    if (lane == 0) { r1[wid] = s; r2[wid] = ss; }
    __syncthreads();
    if (threadIdx.x == 0) {
      float S = 0.f, SS = 0.f;
      #pragma unroll
      for (int w = 0; w < 4; ++w) { S += r1[w]; SS += r2[w]; }
      pstat[blk * 2]     = S;
      pstat[blk * 2 + 1] = SS;
    }
  } else {
    const int wblk = blk - 512;
    const int which = wblk >> 5;
    const float* src = (which == 0) ? Wq : (which == 1) ? Wk : (which == 2) ? Wv : Wp;
    const int base = (wblk & 31) * 2048 + threadIdx.x * 8;
    const float4 v0 = *(const float4*)(src + base);
    const float4 v1 = *(const float4*)(src + base + 4);
    short ob[8] __attribute__((aligned(16)));
    if (which < 3) {
      ob[0] = f2bf(v0.x); ob[1] = f2bf(v0.y); ob[2] = f2bf(v0.z); ob[3] = f2bf(v0.w);
      ob[4] = f2bf(v1.x); ob[5] = f2bf(v1.y); ob[6] = f2bf(v1.z); ob[7] = f2bf(v1.w);
    } else {
      ob[0] = f2h(v0.x); ob[1] = f2h(v0.y); ob[2] = f2h(v0.z); ob[3] = f2h(v0.w);
      ob[4] = f2h(v1.x); ob[5] = f2h(v1.y); ob[6] = f2h(v1.z); ob[7] = f2h(v1.w);
    }
    const int o = base >> 8, c = base & 255;
    const int dst = (((o >> 4) * 8 + (c >> 5)) * 64 + ((c >> 3) & 3) * 16 + (o & 15)) * 8;
    *(uint4*)(wdst + which * 65536 + dst) = *(const uint4*)ob;
  }
}

// ---------------- QKV MFMA GEMM v3b: fused GN staging, frag-major weights ----------------
// grid (2, 256) ot-major: consecutive blocks share the x-tile -> L2-hit staging.
__global__ __launch_bounds__(256) void qkv_gemm(
    const float* __restrict__ x, const float* __restrict__ gamma,
    const float* __restrict__ beta, const float* __restrict__ pstat,
    const short* __restrict__ Wqb, const short* __restrict__ Wkb,
    const short* __restrict__ Wvb,
    short* __restrict__ Qt, short* __restrict__ Kt, _Float16* __restrict__ Vo) {
  __shared__ __align__(16) short smem[64 * 272];   // xn tile (stride 264), later qt/kt (stride 136)
  const int lt = blockIdx.y, ot2 = blockIdx.x;     // ot2 covers 128 output channels
  const int n = lt >> 6, l0 = (lt & 63) << 6;
  const int wave = threadIdx.x >> 6, lane = threadIdx.x & 63;
  const int lq = lane & 15, quad = lane >> 4;

  // ---- stage: normalize + bf16 + transpose into LDS (once per block) ----
  #pragma unroll
  for (int i = 0; i < 2; ++i) {
    const int u = threadIdx.x + i * 256;
    const int cc = u >> 4, l4 = u & 15;              // cc = c-chunk == group
    const int grp = n * NG + cc;
    float S = 0.f, SS = 0.f;
    #pragma unroll
    for (int w = 0; w < 4; ++w) {
      S  += pstat[(grp * 4 + w) * 2];
      SS += pstat[(grp * 4 + w) * 2 + 1];
    }
    const float mean = S / 32768.f;                  // NE = 8*4096
    const float rstd = rsqrtf(SS / 32768.f - mean * mean + EPSV);
    const float* xp = x + (size_t)(n * CC + cc * CPG) * LL + l0 + l4 * 4;
    short ob[4][8] __attribute__((aligned(16)));
    #pragma unroll
    for (int j = 0; j < 8; ++j) {
      const float scl = rstd * gamma[cc * CPG + j];
      const float shf = beta[cc * CPG + j] - mean * scl;
      const float4 v = *(const float4*)(xp + (size_t)j * LL);
      ob[0][j] = f2bf(v.x * scl + shf);
      ob[1][j] = f2bf(v.y * scl + shf);
      ob[2][j] = f2bf(v.z * scl + shf);
      ob[3][j] = f2bf(v.w * scl + shf);
    }
    short* dst = smem + (l4 * 4) * 264 + cc * 8;
    #pragma unroll
    for (int jj = 0; jj < 4; ++jj)
      *(uint4*)(dst + jj * 264) = *(const uint4*)ob[jj];
  }
  __syncthreads();

  // ---- MFMA K-loop: frag-major weights (coalesced), fb frags from LDS ----
  const int tb   = (ot2 * 8 + wave) * 8;             // tile base for w=0 (x512 elems)
  const int loff = lane * 8;
  const short* xl = smem + lq * 264 + quad * 8;

  const f32x4 z = {0.f, 0.f, 0.f, 0.f};
  f32x4 aq[2][4] = {{z, z, z, z}, {z, z, z, z}};
  f32x4 ak[2][4] = {{z, z, z, z}, {z, z, z, z}};
  f32x4 av[2][4] = {{z, z, z, z}, {z, z, z, z}};

  #pragma unroll
  for (int c5 = 0; c5 < 8; ++c5) {
    const int c0 = c5 * 32;
    const bf16x8 fq0 = *(const bf16x8*)(Wqb + (tb + c5) * 512 + loff);
    const bf16x8 fq1 = *(const bf16x8*)(Wqb + (tb + 32 + c5) * 512 + loff);
    const bf16x8 fk0 = *(const bf16x8*)(Wkb + (tb + c5) * 512 + loff);
    const bf16x8 fk1 = *(const bf16x8*)(Wkb + (tb + 32 + c5) * 512 + loff);
    const bf16x8 fv0 = *(const bf16x8*)(Wvb + (tb + c5) * 512 + loff);
    const bf16x8 fv1 = *(const bf16x8*)(Wvb + (tb + 32 + c5) * 512 + loff);
    #pragma unroll
    for (int n0 = 0; n0 < 4; ++n0) {
      const bf16x8 fb = *(const bf16x8*)(xl + (n0 * 16) * 264 + c0);
      aq[0][n0] = __builtin_amdgcn_mfma_f32_16x16x32_bf16(fq0, fb, aq[0][n0], 0, 0, 0);
      aq[1][n0] = __builtin_amdgcn_mfma_f32_16x16x32_bf16(fq1, fb, aq[1][n0], 0, 0, 0);
      ak[0][n0] = __builtin_amdgcn_mfma_f32_16x16x32_bf16(fk0, fb, ak[0][n0], 0, 0, 0);
      ak[1][n0] = __builtin_amdgcn_mfma_f32_16x16x32_bf16(fk1, fb, ak[1][n0], 0, 0, 0);
      av[0][n0] = __builtin_amdgcn_mfma_f32_16x16x32_bf16(fv0, fb, av[0][n0], 0, 0, 0);
      av[1][n0] = __builtin_amdgcn_mfma_f32_16x16x32_bf16(fv1, fb, av[1][n0], 0, 0, 0);
    }
  }

  // ---- V write: channel = ot2*128 + w*64 + wave*16 + quad*4 + r -> (h, d) ----
  #pragma unroll
  for (int w = 0; w < 2; ++w) {
    const size_t hb = (size_t)(n * NH + ot2 * 2 + w);
    #pragma unroll
    for (int n0 = 0; n0 < 4; ++n0)
      #pragma unroll
      for (int r = 0; r < 4; ++r)
        Vo[(hb * DH + wave * 16 + quad * 4 + r) * LL + l0 + n0 * 16 + lq] =
            (_Float16)av[w][n0][r];
  }

  // ---- reuse LDS for Qt/Kt repack: [64 l][136] per tensor (16B-aligned rows) ----
  __syncthreads();                                   // all xn reads done
  short* qt_l = smem;                                // [64][136]
  short* kt_l = smem + 64 * 136;                     // [64][136]
  #pragma unroll
  for (int w = 0; w < 2; ++w)
    #pragma unroll
    for (int n0 = 0; n0 < 4; ++n0)
      #pragma unroll
      for (int r = 0; r < 4; ++r) {
        const int row = n0 * 16 + lq;
        const int col = w * 64 + wave * 16 + quad * 4 + r;
        qt_l[row * 136 + col] = f2bf(aq[w][n0][r] * SCALE_Q);
        kt_l[row * 136 + col] = f2bf(ak[w][n0][r]);
      }
  __syncthreads();
  #pragma unroll
  for (int i = 0; i < 4; ++i) {
    const int u = threadIdx.x + i * 256;
    const int row = u >> 4, ch16 = u & 15;           // 64 rows x 16 chunks of 8 ch
    const int h = ot2 * 2 + (ch16 >> 3);
    const int d0 = (ch16 & 7) * 8;
    const size_t hb = (size_t)(n * NH + h);
    *(uint4*)(Qt + (hb * LL + l0 + row) * DH + d0) = *(const uint4*)&qt_l[row * 136 + ch16 * 8];
    *(uint4*)(Kt + (hb * LL + l0 + row) * DH + d0) = *(const uint4*)&kt_l[row * 136 + ch16 * 8];
  }
}

// ---------------- MFMA flash attention (round-0 proven body): 64 q/wave ----------------
__global__ __launch_bounds__(256, 2) void attn_mfma_kernel(
    const short* __restrict__ Qt, const short* __restrict__ Kt,
    const _Float16* __restrict__ Vb, _Float16* __restrict__ Opart,
    float* __restrict__ lpart) {
  __shared__ __align__(16) short    k_lds[2][64 * 64];   // 8 KB each, swizzled
  __shared__ __align__(16) _Float16 v_lds[2][64 * 64];   // 8 KB each, swizzled+permuted

  const int t = threadIdx.x;
  const int wave = t >> 6, lane = t & 63;
  const int lq = lane & 15, quad = lane >> 4;
  const int l0 = blockIdx.x * 256;
  const int h = blockIdx.y >> 1, split = blockIdx.y & 1;
  const int n = blockIdx.z;
  const int kbase = split * 2048;
  const int R = n * NH + h;
  const size_t hb = (size_t)R * (size_t)LL * DH;
  const short* const Kp = Kt + hb;      // [key][d] bf16
  const _Float16* const Vp = Vb + hb;   // [d][key] f16

  const int qbase = l0 + wave * 64;
  bf16x8 qb[4][2];
  #pragma unroll
  for (int qf = 0; qf < 4; ++qf)
    #pragma unroll
    for (int c = 0; c < 2; ++c)
      qb[qf][c] = *(const bf16x8*)(Qt + hb + (size_t)(qbase + qf * 16 + lq) * DH + c * 32 + quad * 8);

  const f32x4 z = {0.f, 0.f, 0.f, 0.f};
  f32x4 o[4][4] = {{z, z, z, z}, {z, z, z, z}, {z, z, z, z}, {z, z, z, z}};
  f32x4 ol[4] = {z, z, z, z};

  f16x8 ones8;
  #pragma unroll
  for (int i = 0; i < 8; ++i) ones8[i] = (_Float16)1.0f;

  const int srow = t >> 3, sch = t & 7;   // staging: rows 0..31(+32), chunk 0..7
  const int vgo = 32 * (sch >> 2) + 4 * (sch & 3);  // permuted key offset (lo half)

  // stage tile 0
  {
    *(uint4*)&k_lds[0][sw(srow, sch)]      = *(const uint4*)(Kp + (size_t)(kbase + srow) * DH + sch * 8);
    *(uint4*)&k_lds[0][sw(32 + srow, sch)] = *(const uint4*)(Kp + (size_t)(kbase + 32 + srow) * DH + sch * 8);
    const _Float16* vg0 = Vp + (size_t)srow * LL + kbase + vgo;
    const _Float16* vg1 = Vp + (size_t)(32 + srow) * LL + kbase + vgo;
    uint2 a = *(const uint2*)vg0, b = *(const uint2*)(vg0 + 16);
    *(uint4*)&v_lds[0][sw(srow, sch)] = make_uint4(a.x, a.y, b.x, b.y);
    a = *(const uint2*)vg1; b = *(const uint2*)(vg1 + 16);
    *(uint4*)&v_lds[0][sw(32 + srow, sch)] = make_uint4(a.x, a.y, b.x, b.y);
  }
  __syncthreads();

  for (int kt = 0; kt < 32; ++kt) {
    const int cur = kt & 1;
    uint4 kpre[2]; uint2 vpre[4];
    if (kt < 31) {
      const int kpos = kbase + (kt + 1) * 64;
      kpre[0] = *(const uint4*)(Kp + (size_t)(kpos + srow) * DH + sch * 8);
      kpre[1] = *(const uint4*)(Kp + (size_t)(kpos + 32 + srow) * DH + sch * 8);
      const _Float16* vg0 = Vp + (size_t)srow * LL + kpos + vgo;
      const _Float16* vg1 = Vp + (size_t)(32 + srow) * LL + kpos + vgo;
      vpre[0] = *(const uint2*)vg0;
      vpre[1] = *(const uint2*)(vg0 + 16);
      vpre[2] = *(const uint2*)vg1;
      vpre[3] = *(const uint2*)(vg1 + 16);
    }
    const short* kb = k_lds[cur];
    const _Float16* vbuf = v_lds[cur];

    union PU { f16x4 h4[2]; f16x8 h8; } af[2][4];
    #pragma unroll
    for (int mf = 0; mf < 4; ++mf) {
      const bf16x8 ka0 = *(const bf16x8*)&kb[sw(mf * 16 + lq, quad)];
      const bf16x8 ka1 = *(const bf16x8*)&kb[sw(mf * 16 + lq, 4 + quad)];
      #pragma unroll
      for (int qf = 0; qf < 4; ++qf) {
        f32x4 zz = {0.f, 0.f, 0.f, 0.f};
        zz = __builtin_amdgcn_mfma_f32_16x16x32_bf16(ka0, qb[qf][0], zz, 0, 0, 0);
        zz = __builtin_amdgcn_mfma_f32_16x16x32_bf16(ka1, qb[qf][1], zz, 0, 0, 0);
        union { h16x2 h2[2]; f16x4 h4; } u;
        u.h2[0] = __builtin_amdgcn_cvt_pkrtz(__builtin_amdgcn_exp2f(zz[0]),
                                             __builtin_amdgcn_exp2f(zz[1]));
        u.h2[1] = __builtin_amdgcn_cvt_pkrtz(__builtin_amdgcn_exp2f(zz[2]),
                                             __builtin_amdgcn_exp2f(zz[3]));
        af[mf >> 1][qf].h4[mf & 1] = u.h4;
      }
    }

    #pragma unroll
    for (int qf = 0; qf < 4; ++qf) {
      ol[qf] = __builtin_amdgcn_mfma_f32_16x16x32_f16(af[0][qf].h8, ones8, ol[qf], 0, 0, 0);
      ol[qf] = __builtin_amdgcn_mfma_f32_16x16x32_f16(af[1][qf].h8, ones8, ol[qf], 0, 0, 0);
    }

    #pragma unroll
    for (int df = 0; df < 4; ++df)
      #pragma unroll
      for (int cc = 0; cc < 2; ++cc) {
        const f16x8 vb8 = *(const f16x8*)&vbuf[sw(df * 16 + lq, cc * 4 + quad)];
        #pragma unroll
        for (int qf = 0; qf < 4; ++qf)
          o[qf][df] = __builtin_amdgcn_mfma_f32_16x16x32_f16(af[cc][qf].h8, vb8, o[qf][df], 0, 0, 0);
      }

    if (kt < 31) {
      const int nxt = 1 - cur;
      *(uint4*)&k_lds[nxt][sw(srow, sch)]      = kpre[0];
      *(uint4*)&k_lds[nxt][sw(32 + srow, sch)] = kpre[1];
      *(uint4*)&v_lds[nxt][sw(srow, sch)]      = make_uint4(vpre[0].x, vpre[0].y, vpre[1].x, vpre[1].y);
      *(uint4*)&v_lds[nxt][sw(32 + srow, sch)] = make_uint4(vpre[2].x, vpre[2].y, vpre[3].x, vpre[3].y);
      __syncthreads();
    }
  }

  const size_t pb = ((size_t)split * 16 + R) * (size_t)LL * DH;
  #pragma unroll
  for (int qf = 0; qf < 4; ++qf) {
    if (lq == 0) {
      #pragma unroll
      for (int r = 0; r < 4; ++r)
        lpart[((size_t)split * 16 + R) * LL + qbase + qf * 16 + quad * 4 + r] = ol[qf][r];
    }
    #pragma unroll
    for (int df = 0; df < 4; ++df)
      #pragma unroll
      for (int r = 0; r < 4; ++r) {
        const int q = qbase + qf * 16 + quad * 4 + r;
        Opart[pb + (size_t)q * DH + df * 16 + lq] = (_Float16)o[qf][df][r];
      }
  }
}

// ---------------- output projection v2: LDS-staged shared B-operand ----------------
// grid (2, 256) ot-major. fb (normalized O) is IDENTICAL for all 4 waves -> stage
// it once per block per head into LDS (coalesced 1KB/wave loads, sw() swizzle),
// double-buffered across the 4 heads (load->compute->write->barrier, T14 order).
__global__ __launch_bounds__(256) void proj_gemm(
    const _Float16* __restrict__ Opart, const float* __restrict__ lpart,
    const _Float16* __restrict__ Wpf, const float* __restrict__ bp,
    float* __restrict__ out) {
  __shared__ __align__(16) _Float16 fb_lds[2][64 * 64];  // 8 KB each, sw()-swizzled
  const int lt = blockIdx.y, ot2 = blockIdx.x;   // ot2 covers 128 output channels
  const int n = lt >> 6, l0 = (lt & 63) << 6;
  const int wave = threadIdx.x >> 6, lane = threadIdx.x & 63;
  const int lq = lane & 15, quad = lane >> 4;
  const int t = threadIdx.x;
  const int qr = t >> 3, ch = t & 7;             // staging: q-row 0..31(+32), d-chunk 0..7

  const int tb   = (ot2 * 8 + wave) * 8;         // frag tile base for w=0
  const int loff = lane * 8;

  // stage head h into buf: fb = (b0 + b1) * (f16)(1/l)  [numerics identical to v1]
  auto stage = [&](int buf, int h) {
    const _Float16* Op = Opart + ((size_t)(n * NH + h) * LL + l0) * DH;
    #pragma unroll
    for (int half = 0; half < 2; ++half) {
      const int q = half * 32 + qr;
      const size_t rr = (size_t)(n * NH + h) * LL + l0 + q;
      const _Float16 il = (_Float16)(1.0f / (lpart[rr] + lpart[rr + 16 * (size_t)LL]));
      const size_t e = (size_t)q * DH + ch * 8;
      const f16x8 b0 = *(const f16x8*)(Op + e);
      const f16x8 b1 = *(const f16x8*)(Op + e + (size_t)PSPLIT);
      f16x8 sc8;
      #pragma unroll
      for (int i = 0; i < 8; ++i) sc8[i] = il;
      const f16x8 fbn = (b0 + b1) * sc8;
      *(f16x8*)&fb_lds[buf][sw(q, ch)] = fbn;
    }
  };

  stage(0, 0);
  __syncthreads();

  const f32x4 z = {0.f, 0.f, 0.f, 0.f};
  f32x4 acc[2][4] = {{z, z, z, z}, {z, z, z, z}};
  for (int h = 0; h < NH; ++h) {
    const int cur = h & 1;
    // prefetch next head into regs (issue-early), write-late after compute
    f16x8 pre[2];
    if (h < NH - 1) {
      const _Float16* Op = Opart + ((size_t)(n * NH + h + 1) * LL + l0) * DH;
      #pragma unroll
      for (int half = 0; half < 2; ++half) {
        const int q = half * 32 + qr;
        const size_t rr = (size_t)(n * NH + h + 1) * LL + l0 + q;
        const _Float16 il = (_Float16)(1.0f / (lpart[rr] + lpart[rr + 16 * (size_t)LL]));
        const size_t e = (size_t)q * DH + ch * 8;
        const f16x8 b0 = *(const f16x8*)(Op + e);
        const f16x8 b1 = *(const f16x8*)(Op + e + (size_t)PSPLIT);
        f16x8 sc8;
        #pragma unroll
        for (int i = 0; i < 8; ++i) sc8[i] = il;
        pre[half] = (b0 + b1) * sc8;
      }
    }
    // compute the two c5 slices of this head from LDS
    #pragma unroll
    for (int cw = 0; cw < 2; ++cw) {
      const int c5 = 2 * h + cw;
      const int c_idx = cw * 4 + quad;
      const f16x8 fa0 = *(const f16x8*)(Wpf + (tb + c5) * 512 + loff);
      const f16x8 fa1 = *(const f16x8*)(Wpf + (tb + 32 + c5) * 512 + loff);
      #pragma unroll
      for (int n0 = 0; n0 < 4; ++n0) {
        const f16x8 fb = *(const f16x8*)&fb_lds[cur][sw(n0 * 16 + lq, c_idx)];
        acc[0][n0] = __builtin_amdgcn_mfma_f32_16x16x32_f16(fa0, fb, acc[0][n0], 0, 0, 0);
        acc[1][n0] = __builtin_amdgcn_mfma_f32_16x16x32_f16(fa1, fb, acc[1][n0], 0, 0, 0);
      }
    }
    if (h < NH - 1) {
      #pragma unroll
      for (int half = 0; half < 2; ++half)
        *(f16x8*)&fb_lds[cur ^ 1][sw(half * 32 + qr, ch)] = pre[half];
      __syncthreads();
    }
  }

  #pragma unroll
  for (int w = 0; w < 2; ++w)
    #pragma unroll
    for (int r = 0; r < 4; ++r) {
      const int oo = ot2 * 128 + w * 64 + wave * 16 + quad * 4 + r;
      const float bias = bp[oo];
      #pragma unroll
      for (int n0 = 0; n0 < 4; ++n0)
        out[((size_t)n * CC + oo) * LL + l0 + n0 * 16 + lq] = acc[w][n0][r] + bias;
    }
}

extern "C" void kernel_launch(void* const* d_in, const int* in_sizes, int n_in,
                              void* d_out, int out_size, void* d_ws, size_t ws_size,
                              hipStream_t stream) {
  const float* x     = (const float*)d_in[0];
  const float* gamma = (const float*)d_in[1];
  const float* beta  = (const float*)d_in[2];
  const float* Wq    = (const float*)d_in[3];
  const float* Wk    = (const float*)d_in[4];
  const float* Wv    = (const float*)d_in[5];
  const float* Wp    = (const float*)d_in[6];
  const float* bp    = (const float*)d_in[7];
  float* out = (float*)d_out;

  const size_t S = (size_t)NB * CC * LL;  // 4,194,304
  short*     Qt  = (short*)d_ws;          // bf16 [n,h][l][d]
  short*     Kt  = Qt + S;
  _Float16*  Vo  = (_Float16*)(Kt + S);   // f16 [n,h][d][l]
  short*     Wb  = (short*)(Vo + S);      // 4 x 65536 (bf16 x3, f16 x1), frag-major
  _Float16*  Opart = (_Float16*)(Wb + 4 * 65536);  // 2 x 8 MB fp16
  float*     lpart = (float*)(Opart + 2 * (size_t)PSPLIT); // 2 x 256 KB fp32
  float*     pstat = lpart + 2 * 16 * (size_t)LL;  // 1024 floats GN partials

  gnstats_wcvt<<<640,                 256, 0, stream>>>(x, pstat, Wq, Wk, Wv, Wp, Wb);
  qkv_gemm   <<<dim3(2, 256),         256, 0, stream>>>(x, gamma, beta, pstat,
                 Wb, Wb + 65536, Wb + 131072, Qt, Kt, Vo);
  attn_mfma_kernel<<<dim3(LL/256, NH*2, NB), 256, 0, stream>>>(Qt, Kt, Vo, Opart, lpart);
  proj_gemm  <<<dim3(2, 256),         256, 0, stream>>>(Opart, lpart,
                 (const _Float16*)(Wb + 196608), bp, out);
}